// Round 15
// baseline (2578.963 us; speedup 1.0000x reference)
//
#include <hip/hip_runtime.h>
#include <stdint.h>

typedef __attribute__((ext_vector_type(4))) float f32x4;
typedef __attribute__((ext_vector_type(8))) short short8;
typedef __attribute__((ext_vector_type(8))) _Float16 half8;

#define DMODEL 512
#define SEQ 513
#define BATCH 128
#define NROWS (BATCH*SEQ)   // 65664 = 513 * 128
#define DHID 682
#define DHID2 1364
#define HP 768
#define QKVS 1536
#define KVB 64
#define NKT 9
#define QSF 0.1803368801111244f   // 0.125 * log2(e)

__device__ __forceinline__ float h2f(ushort u){ return (float)__builtin_bit_cast(_Float16, u); }
__device__ __forceinline__ ushort f2h(float f){ return __builtin_bit_cast(ushort, (_Float16)f); }
__device__ __forceinline__ uint pk2h(float a, float b){
  return __builtin_bit_cast(uint, __builtin_amdgcn_cvt_pkrtz(a, b));
}
__device__ __forceinline__ void gload16(const void* g, void* lds){
  __builtin_amdgcn_global_load_lds((const __attribute__((address_space(1))) void*)g,
                                   (__attribute__((address_space(3))) void*)lds, 16, 0, 0);
}
// bijective XCD-chunked flat-grid swizzle (m204)
__device__ __forceinline__ int xcd_wg(int orig, int nwg){
  const int q = nwg >> 3, r = nwg & 7;
  const int xcd = orig & 7, idx = orig >> 3;
  return (xcd < r) ? (xcd*(q+1) + idx) : (r*(q+1) + (xcd-r)*q + idx);
}

// ---------------------------------------------------------------------------
// GEMM: C[N x O] = A[N x K] @ W[O x K]^T (+bias). fp16 in, fp32 accum.
// 128x128 tile, BK=64, 4 waves, 32KB LDS, 3 blocks/CU, chunk-XOR swizzle.
// EPI=0: write fp16 Cb. EPI=1: Cf[idx] += acc + bias.
// ---------------------------------------------------------------------------
template<int EPI>
__global__ __launch_bounds__(256,3) void gemm_bt(
    const ushort* __restrict__ A, const ushort* __restrict__ W,
    const float* __restrict__ bias, ushort* __restrict__ Cb, float* __restrict__ Cf,
    int K, int ldc, int gx, int nwg)
{
  __shared__ char lds[32768];       // As @0, Ws @16384
  const int t = threadIdx.x, lane = t & 63, w = t >> 6;
  const int fr = lane & 15, g = lane >> 4;
  const int l7 = lane & 7, l8 = lane >> 3;
  const int wg = xcd_wg(blockIdx.x, nwg);
  const int row0 = (wg / gx) << 7;
  const int col0 = (wg % gx) << 7;
  const int wr = (w >> 1) << 6, wc = (w & 1) << 6;

  const int chunkoff = (l7 ^ l8) << 3;
  const ushort* Ag = A + (size_t)(row0 + w*8 + l8) * K + chunkoff;
  const ushort* Wg = W + (size_t)(col0 + w*8 + l8) * K + chunkoff;

  f32x4 acc[4][4] = {};

  for (int k0 = 0; k0 < K; k0 += 64) {
    __syncthreads();
#pragma unroll
    for (int p = 0; p < 4; ++p) {
      gload16(Ag + (size_t)(p*32)*K + k0, lds + p*4096 + w*1024);
      gload16(Wg + (size_t)(p*32)*K + k0, lds + 16384 + p*4096 + w*1024);
    }
    __syncthreads();
#pragma unroll
    for (int ks = 0; ks < 2; ++ks) {
      half8 af[4], wf[4];
#pragma unroll
      for (int m = 0; m < 4; ++m) {
        const int row = wr + m*16 + fr;
        af[m] = *(const half8*)(lds + row*128 + (((g + ks*4) ^ (fr & 7)) << 4));
      }
#pragma unroll
      for (int n = 0; n < 4; ++n) {
        const int row = wc + n*16 + fr;
        wf[n] = *(const half8*)(lds + 16384 + row*128 + (((g + ks*4) ^ (fr & 7)) << 4));
      }
#pragma unroll
      for (int m = 0; m < 4; ++m)
#pragma unroll
        for (int n = 0; n < 4; ++n)
          acc[m][n] = __builtin_amdgcn_mfma_f32_16x16x32_f16(af[m], wf[n], acc[m][n], 0, 0, 0);
    }
  }

  const int r0 = (lane >> 4) << 2;
#pragma unroll
  for (int m = 0; m < 4; ++m) {
    const int rg = row0 + wr + m*16 + r0;
#pragma unroll
    for (int n = 0; n < 4; ++n) {
      const int cg = col0 + wc + n*16 + fr;
      const float bi = bias[cg];
      if (EPI == 0) {
#pragma unroll
        for (int r = 0; r < 4; ++r)
          Cb[(size_t)(rg + r)*ldc + cg] = f2h(acc[m][n][r] + bi);
      } else {
#pragma unroll
        for (int r = 0; r < 4; ++r) {
          const size_t ix = (size_t)(rg + r)*ldc + cg;
          Cf[ix] += acc[m][n][r] + bi;
        }
      }
    }
  }
}

// ---------------------------------------------------------------------------
// Fused residual GEMM + LayerNorm, vectorized epilogue v4 (round-14 proven).
// ---------------------------------------------------------------------------
__global__ __launch_bounds__(256,2) void gemm_res_ln(
    const ushort* __restrict__ A, const ushort* __restrict__ W,
    const float* __restrict__ bias, float* __restrict__ x,
    const float* __restrict__ gamma, const float* __restrict__ beta,
    ushort* __restrict__ xb, int K)
{
  __shared__ char lds[73728];        // K-loop: A [64][128B] @0, W [512][128B] @8192
                                     // epilogue: fb16 @0, redrow @66560, gb @67072
  const int t = threadIdx.x, lane = t & 63, w = t >> 6;
  const int fr = lane & 15, g = lane >> 4;
  const int l7 = lane & 7, l8 = lane >> 3;
  const int row0 = blockIdx.x << 6;

  const int chunkoff = (l7 ^ l8) << 3;
  const ushort* Ag = A + (size_t)(row0 + w*8 + l8) * K + chunkoff;
  const ushort* Wg = W + (size_t)(w*8 + l8) * K + chunkoff;

  f32x4 acc[4][8] = {};

  for (int k0 = 0; k0 < K; k0 += 64) {
    __syncthreads();
    gload16(Ag + k0,                 lds + w*1024);
    gload16(Ag + (size_t)32*K + k0,  lds + 4096 + w*1024);
#pragma unroll
    for (int p = 0; p < 16; ++p)
      gload16(Wg + (size_t)(p*32)*K + k0, lds + 8192 + p*4096 + w*1024);
    __syncthreads();
#pragma unroll
    for (int ks = 0; ks < 2; ++ks) {
      half8 af[4], wf[8];
#pragma unroll
      for (int m = 0; m < 4; ++m) {
        const int row = m*16 + fr;
        af[m] = *(const half8*)(lds + row*128 + (((g + ks*4) ^ (fr & 7)) << 4));
      }
#pragma unroll
      for (int n = 0; n < 8; ++n) {
        const int row = (w << 7) + n*16 + fr;
        wf[n] = *(const half8*)(lds + 8192 + row*128 + (((g + ks*4) ^ (fr & 7)) << 4));
      }
#pragma unroll
      for (int m = 0; m < 4; ++m)
#pragma unroll
        for (int n = 0; n < 8; ++n)
          acc[m][n] = __builtin_amdgcn_mfma_f32_16x16x32_f16(af[m], wf[n], acc[m][n], 0, 0, 0);
    }
  }

  // ---------------- epilogue v4 ----------------
  ushort* fb16   = (ushort*)lds;              // [64][520]
  float2* redrow = (float2*)(lds + 66560);    // [64]
  float*  gb     = (float*)(lds + 67072);     // gamma[512] | beta[512]

  __syncthreads();
#pragma unroll
  for (int n = 0; n < 8; ++n) {
    const int cg = (w << 7) + n*16 + fr;
    const float bi = bias[cg];
#pragma unroll
    for (int m = 0; m < 4; ++m)
#pragma unroll
      for (int r = 0; r < 4; ++r)
        fb16[(m*16 + g*4 + r)*520 + cg] = f2h(acc[m][n][r] + bi);
  }
  if (t < 128) *(f32x4*)&gb[t*4]            = *(const f32x4*)&gamma[t*4];
  else         *(f32x4*)&gb[512 + (t-128)*4] = *(const f32x4*)&beta[(t-128)*4];
  __syncthreads();

  const int q = t & 15;
  const int rbase = t >> 4;
#pragma unroll
  for (int rr = 0; rr < 4; ++rr) {
    const int row = rr*16 + rbase;
    const size_t xrow = (size_t)(row0 + row)*DMODEL;
    float ps = 0.f, pss = 0.f;
#pragma unroll
    for (int j = 0; j < 8; ++j) {
      const int c = q*4 + j*64;
      const uint2 pk = *(const uint2*)&fb16[row*520 + c];
      f32x4 v;
      v[0] = h2f((ushort)(pk.x & 0xffffu)); v[1] = h2f((ushort)(pk.x >> 16));
      v[2] = h2f((ushort)(pk.y & 0xffffu)); v[3] = h2f((ushort)(pk.y >> 16));
      const f32x4 xo = *(const f32x4*)&x[xrow + c];
      v += xo;
      *(f32x4*)&x[xrow + c] = v;
      uint2 opk; opk.x = pk2h(v[0], v[1]); opk.y = pk2h(v[2], v[3]);
      *(uint2*)&fb16[row*520 + c] = opk;
      ps  += v[0]+v[1]+v[2]+v[3];
      pss += v[0]*v[0]+v[1]*v[1]+v[2]*v[2]+v[3]*v[3];
    }
#pragma unroll
    for (int mask = 1; mask <= 8; mask <<= 1) {
      ps  += __shfl_xor(ps,  mask);
      pss += __shfl_xor(pss, mask);
    }
    if (q == 0) redrow[row] = float2{ps, pss};
  }
  __syncthreads();
#pragma unroll
  for (int rr = 0; rr < 4; ++rr) {
    const int row = rr*16 + rbase;
    const float2 sr = redrow[row];
    const float mu = sr.x * (1.f/512.f);
    const float rstd = rsqrtf(sr.y*(1.f/512.f) - mu*mu + 1e-5f);
    const size_t xbrow = (size_t)(row0 + row)*DMODEL;
#pragma unroll
    for (int j = 0; j < 8; ++j) {
      const int c = q*4 + j*64;
      const uint2 pk = *(const uint2*)&fb16[row*520 + c];
      f32x4 v;
      v[0] = h2f((ushort)(pk.x & 0xffffu)); v[1] = h2f((ushort)(pk.x >> 16));
      v[2] = h2f((ushort)(pk.y & 0xffffu)); v[3] = h2f((ushort)(pk.y >> 16));
      const f32x4 ga = *(const f32x4*)&gb[c];
      const f32x4 be = *(const f32x4*)&gb[512 + c];
      f32x4 o_;
#pragma unroll
      for (int e = 0; e < 4; ++e) o_[e] = (v[e] - mu)*rstd*ga[e] + be[e];
      uint2 u; u.x = pk2h(o_[0], o_[1]); u.y = pk2h(o_[2], o_[3]);
      *(uint2*)&xb[xbrow + c] = u;
    }
  }
}

// ---------------------------------------------------------------------------
// Fused FFN-up + ReGLU: H[N x 768] = (A@Wa^T + ba) * relu(A@Wb^T + bb), fp16.
// BK=64 swizzled; 48KB LDS, 2 blocks/CU.
// ---------------------------------------------------------------------------
__global__ __launch_bounds__(256,2) void gemm_ffn(
    const ushort* __restrict__ A, const ushort* __restrict__ Wa, const ushort* __restrict__ Wb,
    const float* __restrict__ ba, const float* __restrict__ bb, ushort* __restrict__ H,
    int K, int ldc, int gx, int nwg)
{
  __shared__ char lds[49152];       // As @0, Was @16384, Wbs @32768
  const int t = threadIdx.x, lane = t & 63, w = t >> 6;
  const int fr = lane & 15, g = lane >> 4;
  const int l7 = lane & 7, l8 = lane >> 3;
  const int wg = xcd_wg(blockIdx.x, nwg);
  const int row0 = (wg / gx) << 7;
  const int col0 = (wg % gx) << 7;
  const int wr = (w >> 1) << 6, wc = (w & 1) << 6;

  const int chunkoff = (l7 ^ l8) << 3;
  const ushort* Ag  = A  + (size_t)(row0 + w*8 + l8) * K + chunkoff;
  const ushort* WaG = Wa + (size_t)(col0 + w*8 + l8) * K + chunkoff;
  const ushort* WbG = Wb + (size_t)(col0 + w*8 + l8) * K + chunkoff;

  f32x4 aa[4][4] = {}, ab[4][4] = {};

  for (int k0 = 0; k0 < K; k0 += 64) {
    __syncthreads();
#pragma unroll
    for (int p = 0; p < 4; ++p) {
      gload16(Ag  + (size_t)(p*32)*K + k0, lds + p*4096 + w*1024);
      gload16(WaG + (size_t)(p*32)*K + k0, lds + 16384 + p*4096 + w*1024);
      gload16(WbG + (size_t)(p*32)*K + k0, lds + 32768 + p*4096 + w*1024);
    }
    __syncthreads();
#pragma unroll
    for (int ks = 0; ks < 2; ++ks) {
      half8 af[4], wa[4], wb[4];
#pragma unroll
      for (int m = 0; m < 4; ++m) {
        const int row = wr + m*16 + fr;
        af[m] = *(const half8*)(lds + row*128 + (((g + ks*4) ^ (fr & 7)) << 4));
      }
#pragma unroll
      for (int n = 0; n < 4; ++n) {
        const int row = wc + n*16 + fr;
        const int off = row*128 + (((g + ks*4) ^ (fr & 7)) << 4);
        wa[n] = *(const half8*)(lds + 16384 + off);
        wb[n] = *(const half8*)(lds + 32768 + off);
      }
#pragma unroll
      for (int m = 0; m < 4; ++m)
#pragma unroll
        for (int n = 0; n < 4; ++n) {
          aa[m][n] = __builtin_amdgcn_mfma_f32_16x16x32_f16(af[m], wa[n], aa[m][n], 0, 0, 0);
          ab[m][n] = __builtin_amdgcn_mfma_f32_16x16x32_f16(af[m], wb[n], ab[m][n], 0, 0, 0);
        }
    }
  }

  const int r0 = (lane >> 4) << 2;
#pragma unroll
  for (int m = 0; m < 4; ++m) {
    const int rg = row0 + wr + m*16 + r0;
#pragma unroll
    for (int n = 0; n < 4; ++n) {
      const int cg = col0 + wc + n*16 + fr;
      const float bav = ba[cg], bbv = bb[cg];
#pragma unroll
      for (int r = 0; r < 4; ++r) {
        const float av = aa[m][n][r] + bav;
        const float bv = ab[m][n][r] + bbv;
        H[(size_t)(rg + r)*ldc + cg] = f2h(av * fmaxf(bv, 0.f));
      }
    }
  }
}

// ---------------------------------------------------------------------------
// Fused attention v2: 512 threads, 8 waves, 256 q-rows/block.
// blocks 0..2047 = flash path; blocks 2048..3071 = CLS-row path (q row 512).
// K/V/VT shared by 8 waves -> staging+transpose amortized 2x vs 4-wave.
// LDS 56KB -> 2 blocks/CU = 16 waves/CU (same residency as 4-wave version).
// ---------------------------------------------------------------------------
__global__ __launch_bounds__(512,2) void attn_fused(
    const ushort* __restrict__ qkv, ushort* __restrict__ o)
{
  __shared__ char lds[57344];
  const int t = threadIdx.x;

  if (blockIdx.x >= 2048) {
    // ---------------- CLS path (512 threads) ----------------
    const int bh = blockIdx.x - 2048;
    const int b = bh >> 3, h = bh & 7;
    float* sc   = (float*)lds;                 // [SEQ]
    float* qsh  = (float*)(lds + 2112);        // [64]
    float* red  = (float*)(lds + 2368);        // [16]
    float* osum = (float*)(lds + 2432);        // [512]
    const ushort* k = qkv + 512;
    const ushort* v = qkv + 1024;
    const ushort* qb2 = qkv + (size_t)512*QKVS;
    if (t < 64) qsh[t] = h2f(qb2[(size_t)b*SEQ*QKVS + h*64 + t]);
    __syncthreads();
    for (int key = t; key < SEQ; key += 512) {
      const ushort* kr = k + ((size_t)b*SEQ + key)*QKVS + h*64;
      float s = 0.f;
#pragma unroll 8
      for (int d = 0; d < 64; ++d) s += qsh[d]*h2f(kr[d]);
      sc[key] = s;
    }
    __syncthreads();
    float lm = -1e30f;
    for (int key = t; key < SEQ; key += 512) lm = fmaxf(lm, sc[key]);
#pragma unroll
    for (int mask=1; mask<64; mask<<=1) lm = fmaxf(lm, __shfl_xor(lm, mask));
    if ((t&63)==0) red[t>>6] = lm;
    __syncthreads();
    float mx = red[0];
#pragma unroll
    for (int i2 = 1; i2 < 8; ++i2) mx = fmaxf(mx, red[i2]);
    float ls = 0.f;
    for (int key = t; key < SEQ; key += 512){ float pp = exp2f(sc[key]-mx); sc[key]=pp; ls += pp; }
#pragma unroll
    for (int mask=1; mask<64; mask<<=1) ls += __shfl_xor(ls, mask);
    if ((t&63)==0) red[8 + (t>>6)] = ls;
    __syncthreads();
    float ssum = red[8];
#pragma unroll
    for (int i2 = 1; i2 < 8; ++i2) ssum += red[8 + i2];
    const int d = t & 63, kc = t >> 6;   // kc 0..7
    float op = 0.f;
    for (int key = kc; key < SEQ; key += 8)
      op += sc[key] * h2f(v[((size_t)b*SEQ + key)*QKVS + h*64 + d]);
    osum[t] = op;
    __syncthreads();
    if (t < 64) {
      float oo = 0.f;
#pragma unroll
      for (int i2 = 0; i2 < 8; ++i2) oo += osum[t + i2*64];
      o[((size_t)b*SEQ + 512)*DMODEL + h*64 + t] = f2h(oo / ssum);
    }
    return;
  }

  // ---------------- flash path (8 waves, 256 q-rows) ----------------
  const int bid = blockIdx.x;
  const int sw = (bid & 7)*256 + (bid >> 3);   // 2048 % 8 == 0, bijective
  const int qt = sw & 1;
  const int hb = sw >> 1;
  const int h = hb & 7, b = hb >> 3;
  const int lane = t & 63, w = t >> 6;         // w 0..7
  const int fr = lane & 15, g = lane >> 4, gq4 = g << 2;
  const size_t rowB = (size_t)b * SEQ;
  const ushort* q = qkv;
  const ushort* k = qkv + 512;
  const ushort* v = qkv + 1024;

  char* const Ks  = lds;                 // 8KB
  char* const Vs  = lds + 8192;          // 8KB
  char* const VTs = lds + 16384;         // 8KB
  char* const pb  = lds + 24576 + w*4096;  // 8 x 4KB

  const int qr0 = qt*256 + w*32;         // 0..480, all rows < 512

  half8 qf[2][2];
#pragma unroll
  for (int nq = 0; nq < 2; ++nq) {
    const int qrow = qr0 + nq*16 + fr;
#pragma unroll
    for (int kk = 0; kk < 2; ++kk)
      qf[nq][kk] = *(const half8*)&q[(rowB + qrow)*QKVS + h*64 + kk*32 + g*8];
  }

  f32x4 accO[2][4] = {};
  float mrun[2] = {-1e30f, -1e30f};
  float lrun[2] = {0.f, 0.f};

  // staging: one 16B load per thread per buffer; row = t>>3, slot = t&7
  const int srowS = t >> 3, sslot = t & 7;
  const int chunkS = sslot ^ (srowS & 7);
  auto STAGE = [&](int kt2) {
    const int keyg = min(kt2*KVB + srowS, 512);
    const size_t gsrc = (rowB + keyg)*QKVS + h*64 + chunkS*8;
    gload16(k + gsrc, Ks + t*16);
    gload16(v + gsrc, Vs + t*16);
  };

  // V-transpose mapping: 4 dims x 2 keys per thread
  const int td0 = (t & 15) << 2;         // 0..60
  const int tk0 = (t >> 4) << 1;         // 0..62

  STAGE(0);

  for (int kt = 0; kt < NKT; ++kt) {
    __syncthreads();

    f32x4 sc4[4][2] = {};
    __builtin_amdgcn_s_setprio(1);
#pragma unroll
    for (int kk = 0; kk < 2; ++kk) {
      half8 kf[4];
#pragma unroll
      for (int mk = 0; mk < 4; ++mk) {
        const int row = mk*16 + fr;
        kf[mk] = *(const half8*)(Ks + row*128 + ((kk*64 + g*16) ^ ((fr&7)<<4)));
      }
#pragma unroll
      for (int mk = 0; mk < 4; ++mk)
#pragma unroll
        for (int nq = 0; nq < 2; ++nq)
          sc4[mk][nq] = __builtin_amdgcn_mfma_f32_16x16x32_f16(kf[mk], qf[nq][kk], sc4[mk][nq], 0, 0, 0);
    }
    __builtin_amdgcn_s_setprio(0);

    // ---- in-LDS V transpose (512 threads: 2x uint2 read, 4x uint write)
    {
      const uint2 a0 = *(const uint2*)(Vs + tk0*128     + ((td0*2) ^ ((tk0&7)<<4)));
      const uint2 a1 = *(const uint2*)(Vs + (tk0+1)*128 + ((td0*2) ^ (((tk0+1)&7)<<4)));
      uint vals[4];
      vals[0] = (a0.x & 0xffffu) | (a1.x << 16);
      vals[1] = (a0.x >> 16)     | (a1.x & 0xffff0000u);
      vals[2] = (a0.y & 0xffffu) | (a1.y << 16);
      vals[3] = (a0.y >> 16)     | (a1.y & 0xffff0000u);
#pragma unroll
      for (int j = 0; j < 4; ++j) {
        const int drow = td0 + j;
        *(uint*)(VTs + drow*128 + ((tk0*2) ^ ((drow&7)<<4))) = vals[j];
      }
    }

    if (kt == NKT-1) {
#pragma unroll
      for (int mk = 0; mk < 4; ++mk)
#pragma unroll
        for (int r = 0; r < 4; ++r)
          if (mk + gq4 + r) { sc4[mk][0][r] = -1e30f; sc4[mk][1][r] = -1e30f; }
    }

    __syncthreads();

    if (kt+1 < NKT) STAGE(kt+1);

    float al2[2];
    bool resc[2];
#pragma unroll
    for (int nq = 0; nq < 2; ++nq) {
      float tm = sc4[0][nq][0];
#pragma unroll
      for (int mk = 0; mk < 4; ++mk)
#pragma unroll
        for (int r = 0; r < 4; ++r) tm = fmaxf(tm, sc4[mk][nq][r]);
      tm = fmaxf(tm, __shfl_xor(tm, 16));
      tm = fmaxf(tm, __shfl_xor(tm, 32));
      float mref;
      if (__all(tm - mrun[nq] <= 8.f)) {
        mref = mrun[nq];
        al2[nq] = 1.f; resc[nq] = false;
      } else {
        const float mnew = fmaxf(mrun[nq], tm);
        al2[nq] = exp2f(mrun[nq] - mnew);
        mrun[nq] = mnew;
        mref = mnew;
        resc[nq] = true;
      }
      float rs = 0.f;
#pragma unroll
      for (int mk = 0; mk < 4; ++mk)
#pragma unroll
        for (int r = 0; r < 4; ++r) {
          const float pv = exp2f(sc4[mk][nq][r] - mref);
          sc4[mk][nq][r] = pv;
          rs += pv;
        }
      rs += __shfl_xor(rs, 16);
      rs += __shfl_xor(rs, 32);
      lrun[nq] = resc[nq] ? (lrun[nq]*al2[nq] + rs) : (lrun[nq] + rs);
      char* prow = pb + (nq*16 + fr)*128;
#pragma unroll
      for (int mk = 0; mk < 4; ++mk) {
        uint2 pk;
        pk.x = pk2h(sc4[mk][nq][0], sc4[mk][nq][1]);
        pk.y = pk2h(sc4[mk][nq][2], sc4[mk][nq][3]);
        *(uint2*)(prow + ((mk*32 + gq4*2) ^ ((fr&7)<<4))) = pk;
      }
    }

#pragma unroll
    for (int mq = 0; mq < 2; ++mq) {
      if (resc[mq]) {
#pragma unroll
        for (int r = 0; r < 4; ++r) {
          const float alr = __shfl(al2[mq], (lane & 48) | (gq4 + r));
#pragma unroll
          for (int dn = 0; dn < 4; ++dn) accO[mq][dn][r] *= alr;
        }
      }
    }

    asm volatile("" ::: "memory");

    __builtin_amdgcn_s_setprio(1);
#pragma unroll
    for (int kk2 = 0; kk2 < 2; ++kk2) {
      half8 pf[2];
#pragma unroll
      for (int mq = 0; mq < 2; ++mq)
        pf[mq] = *(const half8*)(pb + (mq*16 + fr)*128 + ((kk2*64 + g*16) ^ ((fr&7)<<4)));
      half8 vf[4];
#pragma unroll
      for (int dn = 0; dn < 4; ++dn) {
        const int row = dn*16 + fr;
        vf[dn] = *(const half8*)(VTs + row*128 + ((kk2*64 + g*16) ^ ((fr&7)<<4)));
      }
#pragma unroll
      for (int mq = 0; mq < 2; ++mq)
#pragma unroll
        for (int dn = 0; dn < 4; ++dn)
          accO[mq][dn] = __builtin_amdgcn_mfma_f32_16x16x32_f16(pf[mq], vf[dn], accO[mq][dn], 0, 0, 0);
    }
    __builtin_amdgcn_s_setprio(0);
  }

#pragma unroll
  for (int mq = 0; mq < 2; ++mq)
#pragma unroll
    for (int r = 0; r < 4; ++r) {
      const int qrow = qr0 + mq*16 + gq4 + r;
      const float ls = __shfl(lrun[mq], (lane & 48) | (gq4 + r));
      const float inv = 1.f / ls;
#pragma unroll
      for (int dn = 0; dn < 4; ++dn)
        o[(rowB + qrow)*DMODEL + h*64 + dn*16 + fr] = f2h(accO[mq][dn][r] * inv);
    }
}

// ---------------------------------------------------------------------------
// Standalone single-q attention (layer-3 decode; q/out stride 512).
// ---------------------------------------------------------------------------
__global__ __launch_bounds__(256) void attn_cls(
    const ushort* __restrict__ qbase, size_t qstride,
    const ushort* __restrict__ qkv,
    ushort* __restrict__ obase, size_t ostride)
{
  const int bh = blockIdx.x;
  const int b = bh >> 3, h = bh & 7;
  const int t = threadIdx.x;
  __shared__ float sc[SEQ];
  __shared__ float qsh[64];
  __shared__ float red[8];
  __shared__ float osum[256];
  const ushort* k = qkv + 512;
  const ushort* v = qkv + 1024;
  if (t < 64) qsh[t] = h2f(qbase[(size_t)b*qstride + h*64 + t]);
  __syncthreads();
  for (int key = t; key < SEQ; key += 256) {
    const ushort* kr = k + ((size_t)b*SEQ + key)*QKVS + h*64;
    float s = 0.f;
#pragma unroll 8
    for (int d = 0; d < 64; ++d) s += qsh[d]*h2f(kr[d]);
    sc[key] = s;
  }
  __syncthreads();
  float lm = -1e30f;
  for (int key = t; key < SEQ; key += 256) lm = fmaxf(lm, sc[key]);
#pragma unroll
  for (int mask=1; mask<64; mask<<=1) lm = fmaxf(lm, __shfl_xor(lm, mask));
  if ((t&63)==0) red[t>>6] = lm;
  __syncthreads();
  const float mx = fmaxf(fmaxf(red[0],red[1]), fmaxf(red[2],red[3]));
  float ls = 0.f;
  for (int key = t; key < SEQ; key += 256){ float pp = exp2f(sc[key]-mx); sc[key]=pp; ls += pp; }
#pragma unroll
  for (int mask=1; mask<64; mask<<=1) ls += __shfl_xor(ls, mask);
  if ((t&63)==0) red[4 + (t>>6)] = ls;
  __syncthreads();
  const float ssum = red[4]+red[5]+red[6]+red[7];
  const int d = t & 63, kc = t >> 6;
  float op = 0.f;
  for (int key = kc; key < SEQ; key += 4)
    op += sc[key] * h2f(v[((size_t)b*SEQ + key)*QKVS + h*64 + d]);
  osum[t] = op;
  __syncthreads();
  if (t < 64) {
    const float oo = (osum[t]+osum[64+t]+osum[128+t]+osum[192+t]) / ssum;
    obase[(size_t)b*ostride + h*64 + t] = f2h(oo);
  }
}

// ---------------------------------------------------------------------------
__global__ __launch_bounds__(256) void ln_kernel(
    const float* __restrict__ x, const float* __restrict__ gamma, const float* __restrict__ beta,
    ushort* __restrict__ out, int nrows)
{
  const int row = blockIdx.x*4 + (threadIdx.x >> 6);
  const int lane = threadIdx.x & 63;
  if (row >= nrows) return;
  const float* xr = x + (size_t)row*DMODEL;
  float4 a = *(const float4*)(xr + lane*8);
  float4 b = *(const float4*)(xr + lane*8 + 4);
  float s  = a.x+a.y+a.z+a.w+b.x+b.y+b.z+b.w;
  float ss = a.x*a.x+a.y*a.y+a.z*a.z+a.w*a.w+b.x*b.x+b.y*b.y+b.z*b.z+b.w*b.w;
#pragma unroll
  for (int mask=1; mask<64; mask<<=1){ s += __shfl_xor(s,mask); ss += __shfl_xor(ss,mask); }
  const float mu = s*(1.f/512.f);
  const float rstd = rsqrtf(ss*(1.f/512.f) - mu*mu + 1e-5f);
  float vals[8] = {a.x,a.y,a.z,a.w,b.x,b.y,b.z,b.w};
  short8 pk;
#pragma unroll
  for (int j=0;j<8;++j){
    const int c = lane*8 + j;
    pk[j] = (short)f2h((vals[j]-mu)*rstd*gamma[c] + beta[c]);
  }
  *(short8*)(out + (size_t)row*DMODEL + lane*8) = pk;
}

// ---------------------------------------------------------------------------
__global__ void embed_kernel(const float* __restrict__ x_num, const float* __restrict__ cls_w,
                             float* __restrict__ x, ushort* __restrict__ xb)
{
  const size_t i = (size_t)blockIdx.x*256 + threadIdx.x;
  if (i >= (size_t)NROWS*128) return;
  const int row = (int)(i >> 7);
  const int c4 = ((int)(i & 127)) << 2;
  const int b = row / SEQ;
  const int s = row - b*SEQ;
  float4 val;
  if (s == 0) val = *(const float4*)(cls_w + c4);
  else        val = *(const float4*)(x_num + ((size_t)b*512 + (s-1))*512 + c4);
  *(float4*)(x + (size_t)row*DMODEL + c4) = val;
  ushort4 pk;
  pk.x = f2h(val.x); pk.y = f2h(val.y); pk.z = f2h(val.z); pk.w = f2h(val.w);
  *(ushort4*)(xb + (size_t)row*DMODEL + c4) = pk;
}

// ---------------------------------------------------------------------------
__global__ void convert_pad(const float* __restrict__ in, ushort* __restrict__ out,
                            int R, int C, int RP, int CP, int layers, float scale,
                            int r0, int srcRL, size_t ostride)
{
  const size_t i = (size_t)blockIdx.x*256 + threadIdx.x;
  const size_t per = (size_t)RP*CP;
  if (i >= per*layers) return;
  const int l = (int)(i / per);
  const int rem = (int)(i - (size_t)l*per);
  const int r = rem / CP;
  const int c = rem - r*CP;
  ushort val = 0;
  if (r < R && c < C) val = f2h(in[((size_t)l*srcRL + r0 + r)*C + c] * scale);
  out[(size_t)l*ostride + (size_t)r*CP + c] = val;
}

__global__ void build_bias(const float* __restrict__ bq, const float* __restrict__ bk,
                           const float* __restrict__ bv, const float* __restrict__ l0b,
                           float* __restrict__ fqkv, float* __restrict__ fa, float* __restrict__ fb)
{
  const int i = blockIdx.x*256 + threadIdx.x;
  if (i < 4*1536) {
    const int l = i / 1536, j = i - l*1536;
    float val;
    if (j < 512)       val = bq[l*512 + j] * QSF;
    else if (j < 1024) val = bk[l*512 + j - 512];
    else               val = bv[l*512 + j - 1024];
    fqkv[i] = val;
  }
  if (i < 4*HP) {
    const int l = i / HP, j = i - l*HP;
    fa[i] = (j < DHID) ? l0b[l*DHID2 + j] : 0.f;
    fb[i] = (j < DHID) ? l0b[l*DHID2 + DHID + j] : 0.f;
  }
}

__global__ void gather_cls(const ushort* __restrict__ xb, const float* __restrict__ x,
                           ushort* __restrict__ xq, float* __restrict__ xc)
{
  const int b = blockIdx.x, lane = threadIdx.x;
  const size_t src = (size_t)b*SEQ*DMODEL;
  *(short8*)(xq + b*DMODEL + lane*8) = *(const short8*)(xb + src + lane*8);
  *(float4*)(xc + b*DMODEL + lane*8)     = *(const float4*)(x + src + lane*8);
  *(float4*)(xc + b*DMODEL + lane*8 + 4) = *(const float4*)(x + src + lane*8 + 4);
}

__global__ void head_kernel(const float* __restrict__ xc, const float* __restrict__ g,
                            const float* __restrict__ be, const float* __restrict__ hw,
                            const float* __restrict__ hb, float* __restrict__ out)
{
  const int row = blockIdx.x;
  const int lane = threadIdx.x;
  const float* xr = xc + (size_t)row*DMODEL;
  float4 a = *(const float4*)(xr + lane*8);
  float4 b = *(const float4*)(xr + lane*8 + 4);
  float s  = a.x+a.y+a.z+a.w+b.x+b.y+b.z+b.w;
  float ss = a.x*a.x+a.y*a.y+a.z*a.z+a.w*a.w+b.x*b.x+b.y*b.y+b.z*b.z+b.w*b.w;
#pragma unroll
  for (int mask=1; mask<64; mask<<=1){ s += __shfl_xor(s,mask); ss += __shfl_xor(ss,mask); }
  const float mu = s*(1.f/512.f);
  const float rstd = rsqrtf(ss*(1.f/512.f) - mu*mu + 1e-5f);
  float vals[8] = {a.x,a.y,a.z,a.w,b.x,b.y,b.z,b.w};
  float acc = 0.f;
#pragma unroll
  for (int j=0;j<8;++j){
    const int c = lane*8 + j;
    float tv = (vals[j]-mu)*rstd*g[c] + be[c];
    acc += fmaxf(tv, 0.f) * hw[c];
  }
#pragma unroll
  for (int mask=1; mask<64; mask<<=1) acc += __shfl_xor(acc, mask);
  if (lane==0) out[row] = acc + hb[0];
}

// ---------------------------------------------------------------------------
extern "C" void kernel_launch(void* const* d_in, const int* in_sizes, int n_in,
                              void* d_out, int out_size, void* d_ws, size_t ws_size,
                              hipStream_t stream)
{
  const float* x_num = (const float*)d_in[0];
  const float* cls_w = (const float*)d_in[1];
  const float* Wq = (const float*)d_in[2];
  const float* bq = (const float*)d_in[3];
  const float* Wk = (const float*)d_in[4];
  const float* bk = (const float*)d_in[5];
  const float* Wv = (const float*)d_in[6];
  const float* bv = (const float*)d_in[7];
  const float* Wo = (const float*)d_in[8];
  const float* bo = (const float*)d_in[9];
  const float* l0_w = (const float*)d_in[10];
  const float* l0_b = (const float*)d_in[11];
  const float* l1_w = (const float*)d_in[12];
  const float* l1_b = (const float*)d_in[13];
  const float* n0_g = (const float*)d_in[14];
  const float* n0_b = (const float*)d_in[15];
  const float* n1_g = (const float*)d_in[16];
  const float* n1_b = (const float*)d_in[17];
  const float* ln_g = (const float*)d_in[18];
  const float* ln_b = (const float*)d_in[19];
  const float* head_w = (const float*)d_in[20];
  const float* head_b = (const float*)d_in[21];
  float* out = (float*)d_out;

  char* p = (char*)d_ws;
  auto alloc = [&](size_t bytes){ char* r = p; p += (bytes + 255) & ~(size_t)255; return r; };

  float* x  = (float*)alloc((size_t)NROWS*DMODEL*4);          // residual fp32
  char* U   = alloc((size_t)NROWS*DMODEL*2);                  // xb / attn-out
  ushort* xb = (ushort*)U;
  ushort* ob = (ushort*)U;
  char* QKVG = alloc((size_t)NROWS*QKVS*2);                   // qkv; also h [NROWS][768]
  ushort* qkv = (ushort*)QKVG;
  ushort* hbuf = (ushort*)QKVG;
  ushort* wqkvb = (ushort*)alloc((size_t)4*QKVS*512*2);
  ushort* wob  = (ushort*)alloc((size_t)4*512*512*2);
  ushort* wl0a = (ushort*)alloc((size_t)4*HP*512*2);
  ushort* wl0b = (ushort*)alloc((size_t)4*HP*512*2);
  ushort* l1wp = (ushort*)alloc((size_t)4*512*HP*2);
  float*  fqkvb = (float*)alloc((size_t)4*QKVS*4);
  float*  l0ba = (float*)alloc((size_t)4*HP*4);
  float*  l0bb = (float*)alloc((size_t)4*HP*4);
  ushort* xq_cls = (ushort*)alloc(128*512*2);
  float*  xcf = (float*)alloc(128*512*4);
  ushort* qc = (ushort*)alloc(128*512*2);
  ushort* oc = (ushort*)alloc(128*512*2);
  ushort* hc = (ushort*)alloc((size_t)128*HP*2);
  ushort* xcb = (ushort*)alloc(128*512*2);

  auto cdiv = [](size_t a, size_t b){ return (unsigned)((a + b - 1)/b); };

  // weight conversion: fused QKV [1536x512] per layer (q-part scaled by QSF)
  convert_pad<<<cdiv((size_t)4*512*512,256),256,0,stream>>>(Wq, wqkvb,            512,512,512,512,4, QSF, 0, 512, (size_t)QKVS*512);
  convert_pad<<<cdiv((size_t)4*512*512,256),256,0,stream>>>(Wk, wqkvb + 512*512,  512,512,512,512,4, 1.f, 0, 512, (size_t)QKVS*512);
  convert_pad<<<cdiv((size_t)4*512*512,256),256,0,stream>>>(Wv, wqkvb + 1024*512, 512,512,512,512,4, 1.f, 0, 512, (size_t)QKVS*512);
  convert_pad<<<cdiv((size_t)4*512*512,256),256,0,stream>>>(Wo, wob, 512,512,512,512,4, 1.f, 0, 512, (size_t)512*512);
  convert_pad<<<cdiv((size_t)4*HP*512,256),256,0,stream>>>(l0_w, wl0a, DHID,512,HP,512,4, 1.f, 0,    DHID2, (size_t)HP*512);
  convert_pad<<<cdiv((size_t)4*HP*512,256),256,0,stream>>>(l0_w, wl0b, DHID,512,HP,512,4, 1.f, DHID, DHID2, (size_t)HP*512);
  convert_pad<<<cdiv((size_t)4*512*HP,256),256,0,stream>>>(l1_w, l1wp, 512,DHID,512,HP,4, 1.f, 0, 512, (size_t)512*HP);
  build_bias<<<cdiv(4*QKVS,256),256,0,stream>>>(bq, bk, bv, l0_b, fqkvb, l0ba, l0bb);

  embed_kernel<<<cdiv((size_t)NROWS*128,256),256,0,stream>>>(x_num, cls_w, x, xb);

  const int nwQKV = 12*513, nwF = 6*513, nwKV = 8*513;
  const int nRL = NROWS/64;   // 1026
  for (int i = 0; i < 3; ++i) {
    gemm_bt<0><<<nwQKV,256,0,stream>>>(xb, wqkvb+(size_t)i*QKVS*512, fqkvb+(size_t)i*QKVS, qkv, nullptr, 512, QKVS, 12, nwQKV);
    attn_fused<<<3072,512,0,stream>>>(qkv, ob);
    // WO gemm + residual + LN(n1[i]) -> x, xb
    gemm_res_ln<<<nRL,256,0,stream>>>(ob, wob+(size_t)i*262144, bo+i*512, x,
                                      n1_g+(size_t)i*512, n1_b+(size_t)i*512, xb, 512);
    gemm_ffn<<<nwF,256,0,stream>>>(xb, wl0a+(size_t)i*HP*512, wl0b+(size_t)i*HP*512,
                                   l0ba+(size_t)i*HP, l0bb+(size_t)i*HP, hbuf, 512, HP, 6, nwF);
    // L1 gemm + residual + LN(n0[i]) -> x, xb  (consumed by layer i+1 / layer 3)
    gemm_res_ln<<<nRL,256,0,stream>>>(hbuf, l1wp+(size_t)i*512*HP, l1_b+i*512, x,
                                      n0_g+(size_t)i*512, n0_b+(size_t)i*512, xb, HP);
  }

  // layer 3 (CLS query only) — xb already = LN_n0[2](x)
  gather_cls<<<128,64,0,stream>>>(xb, x, xq_cls, xcf);
  gemm_bt<0><<<4,256,0,stream>>>(xq_cls, wqkvb+(size_t)3*QKVS*512, fqkvb+(size_t)3*QKVS, qc, nullptr, 512, 512, 4, 4);
  gemm_bt<0><<<nwKV,256,0,stream>>>(xb, wqkvb+(size_t)3*QKVS*512 + 512*512, fqkvb+(size_t)3*QKVS + 512,
                                    qkv + 512, nullptr, 512, QKVS, 8, nwKV);
  attn_cls<<<1024,256,0,stream>>>(qc, 512, qkv, oc, 512);
  gemm_bt<1><<<4,256,0,stream>>>(oc, wob+(size_t)3*262144, bo+3*512, nullptr, xcf, 512, 512, 4, 4);
  ln_kernel<<<cdiv(128,4),256,0,stream>>>(xcf, n1_g+3*512, n1_b+3*512, xcb, 128);
  gemm_ffn<<<6,256,0,stream>>>(xcb, wl0a+(size_t)3*HP*512, wl0b+(size_t)3*HP*512,
                               l0ba+(size_t)3*HP, l0bb+(size_t)3*HP, hc, 512, HP, 6, 6);
  gemm_bt<1><<<4,256,0,stream>>>(hc, l1wp+(size_t)3*512*HP, l1_b+3*512, nullptr, xcf, HP, 512, 4, 4);
  head_kernel<<<128,64,0,stream>>>(xcf, ln_g, ln_b, head_w, head_b, out);
}

// Round 16
// 2382.646 us; speedup vs baseline: 1.0824x; 1.0824x over previous
//
#include <hip/hip_runtime.h>
#include <stdint.h>

typedef __attribute__((ext_vector_type(4))) float f32x4;
typedef __attribute__((ext_vector_type(8))) short short8;
typedef __attribute__((ext_vector_type(8))) _Float16 half8;

#define DMODEL 512
#define SEQ 513
#define BATCH 128
#define NROWS (BATCH*SEQ)   // 65664 = 513 * 128
#define DHID 682
#define DHID2 1364
#define HP 768
#define QKVS 1536
#define KVB 64
#define NKT 9
#define QSF 0.1803368801111244f   // 0.125 * log2(e)

__device__ __forceinline__ float h2f(ushort u){ return (float)__builtin_bit_cast(_Float16, u); }
__device__ __forceinline__ ushort f2h(float f){ return __builtin_bit_cast(ushort, (_Float16)f); }
__device__ __forceinline__ uint pk2h(float a, float b){
  return __builtin_bit_cast(uint, __builtin_amdgcn_cvt_pkrtz(a, b));
}
__device__ __forceinline__ void gload16(const void* g, void* lds){
  __builtin_amdgcn_global_load_lds((const __attribute__((address_space(1))) void*)g,
                                   (__attribute__((address_space(3))) void*)lds, 16, 0, 0);
}
// bijective XCD-chunked flat-grid swizzle (m204)
__device__ __forceinline__ int xcd_wg(int orig, int nwg){
  const int q = nwg >> 3, r = nwg & 7;
  const int xcd = orig & 7, idx = orig >> 3;
  return (xcd < r) ? (xcd*(q+1) + idx) : (r*(q+1) + (xcd-r)*q + idx);
}

// ---------------------------------------------------------------------------
// GEMM: C[N x O] = A[N x K] @ W[O x K]^T (+bias). fp16 in, fp32 accum.
// 128x128 tile, BK=64, 4 waves, 32KB LDS, 3 blocks/CU, chunk-XOR swizzle.
// EPI=0: write fp16 Cb. EPI=1: Cf[idx] += acc + bias.
// ---------------------------------------------------------------------------
template<int EPI>
__global__ __launch_bounds__(256,3) void gemm_bt(
    const ushort* __restrict__ A, const ushort* __restrict__ W,
    const float* __restrict__ bias, ushort* __restrict__ Cb, float* __restrict__ Cf,
    int K, int ldc, int gx, int nwg)
{
  __shared__ char lds[32768];       // As @0, Ws @16384
  const int t = threadIdx.x, lane = t & 63, w = t >> 6;
  const int fr = lane & 15, g = lane >> 4;
  const int l7 = lane & 7, l8 = lane >> 3;
  const int wg = xcd_wg(blockIdx.x, nwg);
  const int row0 = (wg / gx) << 7;
  const int col0 = (wg % gx) << 7;
  const int wr = (w >> 1) << 6, wc = (w & 1) << 6;

  const int chunkoff = (l7 ^ l8) << 3;
  const ushort* Ag = A + (size_t)(row0 + w*8 + l8) * K + chunkoff;
  const ushort* Wg = W + (size_t)(col0 + w*8 + l8) * K + chunkoff;

  f32x4 acc[4][4] = {};

  for (int k0 = 0; k0 < K; k0 += 64) {
    __syncthreads();
#pragma unroll
    for (int p = 0; p < 4; ++p) {
      gload16(Ag + (size_t)(p*32)*K + k0, lds + p*4096 + w*1024);
      gload16(Wg + (size_t)(p*32)*K + k0, lds + 16384 + p*4096 + w*1024);
    }
    __syncthreads();
#pragma unroll
    for (int ks = 0; ks < 2; ++ks) {
      half8 af[4], wf[4];
#pragma unroll
      for (int m = 0; m < 4; ++m) {
        const int row = wr + m*16 + fr;
        af[m] = *(const half8*)(lds + row*128 + (((g + ks*4) ^ (fr & 7)) << 4));
      }
#pragma unroll
      for (int n = 0; n < 4; ++n) {
        const int row = wc + n*16 + fr;
        wf[n] = *(const half8*)(lds + 16384 + row*128 + (((g + ks*4) ^ (fr & 7)) << 4));
      }
#pragma unroll
      for (int m = 0; m < 4; ++m)
#pragma unroll
        for (int n = 0; n < 4; ++n)
          acc[m][n] = __builtin_amdgcn_mfma_f32_16x16x32_f16(af[m], wf[n], acc[m][n], 0, 0, 0);
    }
  }

  const int r0 = (lane >> 4) << 2;
#pragma unroll
  for (int m = 0; m < 4; ++m) {
    const int rg = row0 + wr + m*16 + r0;
#pragma unroll
    for (int n = 0; n < 4; ++n) {
      const int cg = col0 + wc + n*16 + fr;
      const float bi = bias[cg];
      if (EPI == 0) {
#pragma unroll
        for (int r = 0; r < 4; ++r)
          Cb[(size_t)(rg + r)*ldc + cg] = f2h(acc[m][n][r] + bi);
      } else {
#pragma unroll
        for (int r = 0; r < 4; ++r) {
          const size_t ix = (size_t)(rg + r)*ldc + cg;
          Cf[ix] += acc[m][n][r] + bi;
        }
      }
    }
  }
}

// ---------------------------------------------------------------------------
// Fused residual GEMM + LayerNorm, vectorized epilogue v4 (round-14 proven).
// ---------------------------------------------------------------------------
__global__ __launch_bounds__(256,2) void gemm_res_ln(
    const ushort* __restrict__ A, const ushort* __restrict__ W,
    const float* __restrict__ bias, float* __restrict__ x,
    const float* __restrict__ gamma, const float* __restrict__ beta,
    ushort* __restrict__ xb, int K)
{
  __shared__ char lds[73728];        // K-loop: A [64][128B] @0, W [512][128B] @8192
                                     // epilogue: fb16 @0, redrow @66560, gb @67072
  const int t = threadIdx.x, lane = t & 63, w = t >> 6;
  const int fr = lane & 15, g = lane >> 4;
  const int l7 = lane & 7, l8 = lane >> 3;
  const int row0 = blockIdx.x << 6;

  const int chunkoff = (l7 ^ l8) << 3;
  const ushort* Ag = A + (size_t)(row0 + w*8 + l8) * K + chunkoff;
  const ushort* Wg = W + (size_t)(w*8 + l8) * K + chunkoff;

  f32x4 acc[4][8] = {};

  for (int k0 = 0; k0 < K; k0 += 64) {
    __syncthreads();
    gload16(Ag + k0,                 lds + w*1024);
    gload16(Ag + (size_t)32*K + k0,  lds + 4096 + w*1024);
#pragma unroll
    for (int p = 0; p < 16; ++p)
      gload16(Wg + (size_t)(p*32)*K + k0, lds + 8192 + p*4096 + w*1024);
    __syncthreads();
#pragma unroll
    for (int ks = 0; ks < 2; ++ks) {
      half8 af[4], wf[8];
#pragma unroll
      for (int m = 0; m < 4; ++m) {
        const int row = m*16 + fr;
        af[m] = *(const half8*)(lds + row*128 + (((g + ks*4) ^ (fr & 7)) << 4));
      }
#pragma unroll
      for (int n = 0; n < 8; ++n) {
        const int row = (w << 7) + n*16 + fr;
        wf[n] = *(const half8*)(lds + 8192 + row*128 + (((g + ks*4) ^ (fr & 7)) << 4));
      }
#pragma unroll
      for (int m = 0; m < 4; ++m)
#pragma unroll
        for (int n = 0; n < 8; ++n)
          acc[m][n] = __builtin_amdgcn_mfma_f32_16x16x32_f16(af[m], wf[n], acc[m][n], 0, 0, 0);
    }
  }

  // ---------------- epilogue v4 ----------------
  ushort* fb16   = (ushort*)lds;              // [64][520]
  float2* redrow = (float2*)(lds + 66560);    // [64]
  float*  gb     = (float*)(lds + 67072);     // gamma[512] | beta[512]

  __syncthreads();
#pragma unroll
  for (int n = 0; n < 8; ++n) {
    const int cg = (w << 7) + n*16 + fr;
    const float bi = bias[cg];
#pragma unroll
    for (int m = 0; m < 4; ++m)
#pragma unroll
      for (int r = 0; r < 4; ++r)
        fb16[(m*16 + g*4 + r)*520 + cg] = f2h(acc[m][n][r] + bi);
  }
  if (t < 128) *(f32x4*)&gb[t*4]            = *(const f32x4*)&gamma[t*4];
  else         *(f32x4*)&gb[512 + (t-128)*4] = *(const f32x4*)&beta[(t-128)*4];
  __syncthreads();

  const int q = t & 15;
  const int rbase = t >> 4;
#pragma unroll
  for (int rr = 0; rr < 4; ++rr) {
    const int row = rr*16 + rbase;
    const size_t xrow = (size_t)(row0 + row)*DMODEL;
    float ps = 0.f, pss = 0.f;
#pragma unroll
    for (int j = 0; j < 8; ++j) {
      const int c = q*4 + j*64;
      const uint2 pk = *(const uint2*)&fb16[row*520 + c];
      f32x4 v;
      v[0] = h2f((ushort)(pk.x & 0xffffu)); v[1] = h2f((ushort)(pk.x >> 16));
      v[2] = h2f((ushort)(pk.y & 0xffffu)); v[3] = h2f((ushort)(pk.y >> 16));
      const f32x4 xo = *(const f32x4*)&x[xrow + c];
      v += xo;
      *(f32x4*)&x[xrow + c] = v;
      uint2 opk; opk.x = pk2h(v[0], v[1]); opk.y = pk2h(v[2], v[3]);
      *(uint2*)&fb16[row*520 + c] = opk;
      ps  += v[0]+v[1]+v[2]+v[3];
      pss += v[0]*v[0]+v[1]*v[1]+v[2]*v[2]+v[3]*v[3];
    }
#pragma unroll
    for (int mask = 1; mask <= 8; mask <<= 1) {
      ps  += __shfl_xor(ps,  mask);
      pss += __shfl_xor(pss, mask);
    }
    if (q == 0) redrow[row] = float2{ps, pss};
  }
  __syncthreads();
#pragma unroll
  for (int rr = 0; rr < 4; ++rr) {
    const int row = rr*16 + rbase;
    const float2 sr = redrow[row];
    const float mu = sr.x * (1.f/512.f);
    const float rstd = rsqrtf(sr.y*(1.f/512.f) - mu*mu + 1e-5f);
    const size_t xbrow = (size_t)(row0 + row)*DMODEL;
#pragma unroll
    for (int j = 0; j < 8; ++j) {
      const int c = q*4 + j*64;
      const uint2 pk = *(const uint2*)&fb16[row*520 + c];
      f32x4 v;
      v[0] = h2f((ushort)(pk.x & 0xffffu)); v[1] = h2f((ushort)(pk.x >> 16));
      v[2] = h2f((ushort)(pk.y & 0xffffu)); v[3] = h2f((ushort)(pk.y >> 16));
      const f32x4 ga = *(const f32x4*)&gb[c];
      const f32x4 be = *(const f32x4*)&gb[512 + c];
      f32x4 o_;
#pragma unroll
      for (int e = 0; e < 4; ++e) o_[e] = (v[e] - mu)*rstd*ga[e] + be[e];
      uint2 u; u.x = pk2h(o_[0], o_[1]); u.y = pk2h(o_[2], o_[3]);
      *(uint2*)&xb[xbrow + c] = u;
    }
  }
}

// ---------------------------------------------------------------------------
// Fused FFN-up + ReGLU: H[N x 768] = (A@Wa^T + ba) * relu(A@Wb^T + bb), fp16.
// BK=64 swizzled; 48KB LDS, 2 blocks/CU.
// ---------------------------------------------------------------------------
__global__ __launch_bounds__(256,2) void gemm_ffn(
    const ushort* __restrict__ A, const ushort* __restrict__ Wa, const ushort* __restrict__ Wb,
    const float* __restrict__ ba, const float* __restrict__ bb, ushort* __restrict__ H,
    int K, int ldc, int gx, int nwg)
{
  __shared__ char lds[49152];       // As @0, Was @16384, Wbs @32768
  const int t = threadIdx.x, lane = t & 63, w = t >> 6;
  const int fr = lane & 15, g = lane >> 4;
  const int l7 = lane & 7, l8 = lane >> 3;
  const int wg = xcd_wg(blockIdx.x, nwg);
  const int row0 = (wg / gx) << 7;
  const int col0 = (wg % gx) << 7;
  const int wr = (w >> 1) << 6, wc = (w & 1) << 6;

  const int chunkoff = (l7 ^ l8) << 3;
  const ushort* Ag  = A  + (size_t)(row0 + w*8 + l8) * K + chunkoff;
  const ushort* WaG = Wa + (size_t)(col0 + w*8 + l8) * K + chunkoff;
  const ushort* WbG = Wb + (size_t)(col0 + w*8 + l8) * K + chunkoff;

  f32x4 aa[4][4] = {}, ab[4][4] = {};

  for (int k0 = 0; k0 < K; k0 += 64) {
    __syncthreads();
#pragma unroll
    for (int p = 0; p < 4; ++p) {
      gload16(Ag  + (size_t)(p*32)*K + k0, lds + p*4096 + w*1024);
      gload16(WaG + (size_t)(p*32)*K + k0, lds + 16384 + p*4096 + w*1024);
      gload16(WbG + (size_t)(p*32)*K + k0, lds + 32768 + p*4096 + w*1024);
    }
    __syncthreads();
#pragma unroll
    for (int ks = 0; ks < 2; ++ks) {
      half8 af[4], wa[4], wb[4];
#pragma unroll
      for (int m = 0; m < 4; ++m) {
        const int row = wr + m*16 + fr;
        af[m] = *(const half8*)(lds + row*128 + (((g + ks*4) ^ (fr & 7)) << 4));
      }
#pragma unroll
      for (int n = 0; n < 4; ++n) {
        const int row = wc + n*16 + fr;
        const int off = row*128 + (((g + ks*4) ^ (fr & 7)) << 4);
        wa[n] = *(const half8*)(lds + 16384 + off);
        wb[n] = *(const half8*)(lds + 32768 + off);
      }
#pragma unroll
      for (int m = 0; m < 4; ++m)
#pragma unroll
        for (int n = 0; n < 4; ++n) {
          aa[m][n] = __builtin_amdgcn_mfma_f32_16x16x32_f16(af[m], wa[n], aa[m][n], 0, 0, 0);
          ab[m][n] = __builtin_amdgcn_mfma_f32_16x16x32_f16(af[m], wb[n], ab[m][n], 0, 0, 0);
        }
    }
  }

  const int r0 = (lane >> 4) << 2;
#pragma unroll
  for (int m = 0; m < 4; ++m) {
    const int rg = row0 + wr + m*16 + r0;
#pragma unroll
    for (int n = 0; n < 4; ++n) {
      const int cg = col0 + wc + n*16 + fr;
      const float bav = ba[cg], bbv = bb[cg];
#pragma unroll
      for (int r = 0; r < 4; ++r) {
        const float av = aa[m][n][r] + bav;
        const float bv = ab[m][n][r] + bbv;
        H[(size_t)(rg + r)*ldc + cg] = f2h(av * fmaxf(bv, 0.f));
      }
    }
  }
}

// ---------------------------------------------------------------------------
// Fused attention (round-14 proven): 256 threads, 4 waves, 128 q-rows/block.
// blocks 0..4095 = flash path; blocks 4096..5119 = CLS-row path (q row 512).
// ---------------------------------------------------------------------------
__global__ __launch_bounds__(256,4) void attn_fused(
    const ushort* __restrict__ qkv, ushort* __restrict__ o)
{
  __shared__ char lds[40960];
  const int t = threadIdx.x;

  if (blockIdx.x >= 4096) {
    const int bh = blockIdx.x - 4096;
    const int b = bh >> 3, h = bh & 7;
    float* sc   = (float*)lds;
    float* qsh  = (float*)(lds + 2112);
    float* red  = (float*)(lds + 2368);
    float* osum = (float*)(lds + 2432);
    const ushort* k = qkv + 512;
    const ushort* v = qkv + 1024;
    const ushort* qb2 = qkv + (size_t)512*QKVS;
    if (t < 64) qsh[t] = h2f(qb2[(size_t)b*SEQ*QKVS + h*64 + t]);
    __syncthreads();
    for (int key = t; key < SEQ; key += 256) {
      const ushort* kr = k + ((size_t)b*SEQ + key)*QKVS + h*64;
      float s = 0.f;
#pragma unroll 8
      for (int d = 0; d < 64; ++d) s += qsh[d]*h2f(kr[d]);
      sc[key] = s;
    }
    __syncthreads();
    float lm = -1e30f;
    for (int key = t; key < SEQ; key += 256) lm = fmaxf(lm, sc[key]);
#pragma unroll
    for (int mask=1; mask<64; mask<<=1) lm = fmaxf(lm, __shfl_xor(lm, mask));
    if ((t&63)==0) red[t>>6] = lm;
    __syncthreads();
    const float mx = fmaxf(fmaxf(red[0],red[1]), fmaxf(red[2],red[3]));
    float ls = 0.f;
    for (int key = t; key < SEQ; key += 256){ float pp = exp2f(sc[key]-mx); sc[key]=pp; ls += pp; }
#pragma unroll
    for (int mask=1; mask<64; mask<<=1) ls += __shfl_xor(ls, mask);
    if ((t&63)==0) red[4 + (t>>6)] = ls;
    __syncthreads();
    const float ssum = red[4]+red[5]+red[6]+red[7];
    const int d = t & 63, kc = t >> 6;
    float op = 0.f;
    for (int key = kc; key < SEQ; key += 4)
      op += sc[key] * h2f(v[((size_t)b*SEQ + key)*QKVS + h*64 + d]);
    osum[t] = op;
    __syncthreads();
    if (t < 64) {
      const float oo = (osum[t]+osum[64+t]+osum[128+t]+osum[192+t]) / ssum;
      o[((size_t)b*SEQ + 512)*DMODEL + h*64 + t] = f2h(oo);
    }
    return;
  }

  const int bid = blockIdx.x;
  const int sw = (bid & 7)*512 + (bid >> 3);
  const int qt = sw & 3;
  const int hb = sw >> 2;
  const int h = hb & 7, b = hb >> 3;
  const int lane = t & 63, w = t >> 6;
  const int fr = lane & 15, g = lane >> 4, gq4 = g << 2;
  const size_t rowB = (size_t)b * SEQ;
  const ushort* q = qkv;
  const ushort* k = qkv + 512;
  const ushort* v = qkv + 1024;

  char* const Ks  = lds;
  char* const Vs  = lds + 8192;
  char* const VTs = lds + 16384;
  char* const pb  = lds + 24576 + w*4096;

  const int qr0 = qt*128 + w*32;

  half8 qf[2][2];
#pragma unroll
  for (int nq = 0; nq < 2; ++nq) {
    const int qrow = qr0 + nq*16 + fr;
#pragma unroll
    for (int kk = 0; kk < 2; ++kk)
      qf[nq][kk] = *(const half8*)&q[(rowB + qrow)*QKVS + h*64 + kk*32 + g*8];
  }

  f32x4 accO[2][4] = {};
  float mrun[2] = {-1e30f, -1e30f};
  float lrun[2] = {0.f, 0.f};

  const int l8 = lane >> 3, l7 = lane & 7;
  const int chunk = l7 ^ l8;
  auto STAGE = [&](int kt2) {
#pragma unroll
    for (int i = 0; i < 2; ++i) {
      const int row = i*32 + (w<<3) + l8;
      const int keyg = min(kt2*KVB + row, 512);
      const size_t gsrc = (rowB + keyg)*QKVS + h*64 + chunk*8;
      gload16(k + gsrc, Ks + i*4096 + w*1024);
      gload16(v + gsrc, Vs + i*4096 + w*1024);
    }
  };

  const int db  = (lane & 7) | ((w & 1) << 3);
  const int kbq = l8 | ((w & 2) << 2);
  const int d0 = db << 2, key0 = kbq << 2;

  STAGE(0);

  for (int kt = 0; kt < NKT; ++kt) {
    __syncthreads();

    f32x4 sc4[4][2] = {};
    __builtin_amdgcn_s_setprio(1);
#pragma unroll
    for (int kk = 0; kk < 2; ++kk) {
      half8 kf[4];
#pragma unroll
      for (int mk = 0; mk < 4; ++mk) {
        const int row = mk*16 + fr;
        kf[mk] = *(const half8*)(Ks + row*128 + ((kk*64 + g*16) ^ ((fr&7)<<4)));
      }
#pragma unroll
      for (int mk = 0; mk < 4; ++mk)
#pragma unroll
        for (int nq = 0; nq < 2; ++nq)
          sc4[mk][nq] = __builtin_amdgcn_mfma_f32_16x16x32_f16(kf[mk], qf[nq][kk], sc4[mk][nq], 0, 0, 0);
    }
    __builtin_amdgcn_s_setprio(0);

    {
      uint2 a[4];
#pragma unroll
      for (int i = 0; i < 4; ++i) {
        const int row = key0 + i;
        a[i] = *(const uint2*)(Vs + row*128 + ((d0*2) ^ ((row&7)<<4)));
      }
      uint2 bb[4];
      bb[0].x = (a[0].x & 0xffffu) | (a[1].x << 16);
      bb[0].y = (a[2].x & 0xffffu) | (a[3].x << 16);
      bb[1].x = (a[0].x >> 16) | (a[1].x & 0xffff0000u);
      bb[1].y = (a[2].x >> 16) | (a[3].x & 0xffff0000u);
      bb[2].x = (a[0].y & 0xffffu) | (a[1].y << 16);
      bb[2].y = (a[2].y & 0xffffu) | (a[3].y << 16);
      bb[3].x = (a[0].y >> 16) | (a[1].y & 0xffff0000u);
      bb[3].y = (a[2].y >> 16) | (a[3].y & 0xffff0000u);
#pragma unroll
      for (int j = 0; j < 4; ++j) {
        const int drow = d0 + j;
        *(uint2*)(VTs + drow*128 + ((key0*2) ^ ((drow&7)<<4))) = bb[j];
      }
    }

    if (kt == NKT-1) {
#pragma unroll
      for (int mk = 0; mk < 4; ++mk)
#pragma unroll
        for (int r = 0; r < 4; ++r)
          if (mk + gq4 + r) { sc4[mk][0][r] = -1e30f; sc4[mk][1][r] = -1e30f; }
    }

    __syncthreads();

    if (kt+1 < NKT) STAGE(kt+1);

    float al2[2];
    bool resc[2];
#pragma unroll
    for (int nq = 0; nq < 2; ++nq) {
      float tm = sc4[0][nq][0];
#pragma unroll
      for (int mk = 0; mk < 4; ++mk)
#pragma unroll
        for (int r = 0; r < 4; ++r) tm = fmaxf(tm, sc4[mk][nq][r]);
      tm = fmaxf(tm, __shfl_xor(tm, 16));
      tm = fmaxf(tm, __shfl_xor(tm, 32));
      float mref;
      if (__all(tm - mrun[nq] <= 8.f)) {
        mref = mrun[nq];
        al2[nq] = 1.f; resc[nq] = false;
      } else {
        const float mnew = fmaxf(mrun[nq], tm);
        al2[nq] = exp2f(mrun[nq] - mnew);
        mrun[nq] = mnew;
        mref = mnew;
        resc[nq] = true;
      }
      float rs = 0.f;
#pragma unroll
      for (int mk = 0; mk < 4; ++mk)
#pragma unroll
        for (int r = 0; r < 4; ++r) {
          const float pv = exp2f(sc4[mk][nq][r] - mref);
          sc4[mk][nq][r] = pv;
          rs += pv;
        }
      rs += __shfl_xor(rs, 16);
      rs += __shfl_xor(rs, 32);
      lrun[nq] = resc[nq] ? (lrun[nq]*al2[nq] + rs) : (lrun[nq] + rs);
      char* prow = pb + (nq*16 + fr)*128;
#pragma unroll
      for (int mk = 0; mk < 4; ++mk) {
        uint2 pk;
        pk.x = pk2h(sc4[mk][nq][0], sc4[mk][nq][1]);
        pk.y = pk2h(sc4[mk][nq][2], sc4[mk][nq][3]);
        *(uint2*)(prow + ((mk*32 + gq4*2) ^ ((fr&7)<<4))) = pk;
      }
    }

#pragma unroll
    for (int mq = 0; mq < 2; ++mq) {
      if (resc[mq]) {
#pragma unroll
        for (int r = 0; r < 4; ++r) {
          const float alr = __shfl(al2[mq], (lane & 48) | (gq4 + r));
#pragma unroll
          for (int dn = 0; dn < 4; ++dn) accO[mq][dn][r] *= alr;
        }
      }
    }

    asm volatile("" ::: "memory");

    __builtin_amdgcn_s_setprio(1);
#pragma unroll
    for (int kk2 = 0; kk2 < 2; ++kk2) {
      half8 pf[2];
#pragma unroll
      for (int mq = 0; mq < 2; ++mq)
        pf[mq] = *(const half8*)(pb + (mq*16 + fr)*128 + ((kk2*64 + g*16) ^ ((fr&7)<<4)));
      half8 vf[4];
#pragma unroll
      for (int dn = 0; dn < 4; ++dn) {
        const int row = dn*16 + fr;
        vf[dn] = *(const half8*)(VTs + row*128 + ((kk2*64 + g*16) ^ ((fr&7)<<4)));
      }
#pragma unroll
      for (int mq = 0; mq < 2; ++mq)
#pragma unroll
        for (int dn = 0; dn < 4; ++dn)
          accO[mq][dn] = __builtin_amdgcn_mfma_f32_16x16x32_f16(pf[mq], vf[dn], accO[mq][dn], 0, 0, 0);
    }
    __builtin_amdgcn_s_setprio(0);
  }

#pragma unroll
  for (int mq = 0; mq < 2; ++mq)
#pragma unroll
    for (int r = 0; r < 4; ++r) {
      const int qrow = qr0 + mq*16 + gq4 + r;
      const float ls = __shfl(lrun[mq], (lane & 48) | (gq4 + r));
      const float inv = 1.f / ls;
#pragma unroll
      for (int dn = 0; dn < 4; ++dn)
        o[(rowB + qrow)*DMODEL + h*64 + dn*16 + fr] = f2h(accO[mq][dn][r] * inv);
    }
}

// ---------------------------------------------------------------------------
// Standalone single-q attention (layer-3 decode; q/out stride 512).
// ---------------------------------------------------------------------------
__global__ __launch_bounds__(256) void attn_cls(
    const ushort* __restrict__ qbase, size_t qstride,
    const ushort* __restrict__ qkv,
    ushort* __restrict__ obase, size_t ostride)
{
  const int bh = blockIdx.x;
  const int b = bh >> 3, h = bh & 7;
  const int t = threadIdx.x;
  __shared__ float sc[SEQ];
  __shared__ float qsh[64];
  __shared__ float red[8];
  __shared__ float osum[256];
  const ushort* k = qkv + 512;
  const ushort* v = qkv + 1024;
  if (t < 64) qsh[t] = h2f(qbase[(size_t)b*qstride + h*64 + t]);
  __syncthreads();
  for (int key = t; key < SEQ; key += 256) {
    const ushort* kr = k + ((size_t)b*SEQ + key)*QKVS + h*64;
    float s = 0.f;
#pragma unroll 8
    for (int d = 0; d < 64; ++d) s += qsh[d]*h2f(kr[d]);
    sc[key] = s;
  }
  __syncthreads();
  float lm = -1e30f;
  for (int key = t; key < SEQ; key += 256) lm = fmaxf(lm, sc[key]);
#pragma unroll
  for (int mask=1; mask<64; mask<<=1) lm = fmaxf(lm, __shfl_xor(lm, mask));
  if ((t&63)==0) red[t>>6] = lm;
  __syncthreads();
  const float mx = fmaxf(fmaxf(red[0],red[1]), fmaxf(red[2],red[3]));
  float ls = 0.f;
  for (int key = t; key < SEQ; key += 256){ float pp = exp2f(sc[key]-mx); sc[key]=pp; ls += pp; }
#pragma unroll
  for (int mask=1; mask<64; mask<<=1) ls += __shfl_xor(ls, mask);
  if ((t&63)==0) red[4 + (t>>6)] = ls;
  __syncthreads();
  const float ssum = red[4]+red[5]+red[6]+red[7];
  const int d = t & 63, kc = t >> 6;
  float op = 0.f;
  for (int key = kc; key < SEQ; key += 4)
    op += sc[key] * h2f(v[((size_t)b*SEQ + key)*QKVS + h*64 + d]);
  osum[t] = op;
  __syncthreads();
  if (t < 64) {
    const float oo = (osum[t]+osum[64+t]+osum[128+t]+osum[192+t]) / ssum;
    obase[(size_t)b*ostride + h*64 + t] = f2h(oo);
  }
}

// ---------------------------------------------------------------------------
__global__ __launch_bounds__(256) void ln_kernel(
    const float* __restrict__ x, const float* __restrict__ gamma, const float* __restrict__ beta,
    ushort* __restrict__ out, int nrows)
{
  const int row = blockIdx.x*4 + (threadIdx.x >> 6);
  const int lane = threadIdx.x & 63;
  if (row >= nrows) return;
  const float* xr = x + (size_t)row*DMODEL;
  float4 a = *(const float4*)(xr + lane*8);
  float4 b = *(const float4*)(xr + lane*8 + 4);
  float s  = a.x+a.y+a.z+a.w+b.x+b.y+b.z+b.w;
  float ss = a.x*a.x+a.y*a.y+a.z*a.z+a.w*a.w+b.x*b.x+b.y*b.y+b.z*b.z+b.w*b.w;
#pragma unroll
  for (int mask=1; mask<64; mask<<=1){ s += __shfl_xor(s,mask); ss += __shfl_xor(ss,mask); }
  const float mu = s*(1.f/512.f);
  const float rstd = rsqrtf(ss*(1.f/512.f) - mu*mu + 1e-5f);
  float vals[8] = {a.x,a.y,a.z,a.w,b.x,b.y,b.z,b.w};
  short8 pk;
#pragma unroll
  for (int j=0;j<8;++j){
    const int c = lane*8 + j;
    pk[j] = (short)f2h((vals[j]-mu)*rstd*gamma[c] + beta[c]);
  }
  *(short8*)(out + (size_t)row*DMODEL + lane*8) = pk;
}

// ---------------------------------------------------------------------------
__global__ void embed_kernel(const float* __restrict__ x_num, const float* __restrict__ cls_w,
                             float* __restrict__ x, ushort* __restrict__ xb)
{
  const size_t i = (size_t)blockIdx.x*256 + threadIdx.x;
  if (i >= (size_t)NROWS*128) return;
  const int row = (int)(i >> 7);
  const int c4 = ((int)(i & 127)) << 2;
  const int b = row / SEQ;
  const int s = row - b*SEQ;
  float4 val;
  if (s == 0) val = *(const float4*)(cls_w + c4);
  else        val = *(const float4*)(x_num + ((size_t)b*512 + (s-1))*512 + c4);
  *(float4*)(x + (size_t)row*DMODEL + c4) = val;
  ushort4 pk;
  pk.x = f2h(val.x); pk.y = f2h(val.y); pk.z = f2h(val.z); pk.w = f2h(val.w);
  *(ushort4*)(xb + (size_t)row*DMODEL + c4) = pk;
}

// ---------------------------------------------------------------------------
__global__ void convert_pad(const float* __restrict__ in, ushort* __restrict__ out,
                            int R, int C, int RP, int CP, int layers, float scale,
                            int r0, int srcRL, size_t ostride)
{
  const size_t i = (size_t)blockIdx.x*256 + threadIdx.x;
  const size_t per = (size_t)RP*CP;
  if (i >= per*layers) return;
  const int l = (int)(i / per);
  const int rem = (int)(i - (size_t)l*per);
  const int r = rem / CP;
  const int c = rem - r*CP;
  ushort val = 0;
  if (r < R && c < C) val = f2h(in[((size_t)l*srcRL + r0 + r)*C + c] * scale);
  out[(size_t)l*ostride + (size_t)r*CP + c] = val;
}

__global__ void build_bias(const float* __restrict__ bq, const float* __restrict__ bk,
                           const float* __restrict__ bv, const float* __restrict__ l0b,
                           float* __restrict__ fqkv, float* __restrict__ fa, float* __restrict__ fb)
{
  const int i = blockIdx.x*256 + threadIdx.x;
  if (i < 4*1536) {
    const int l = i / 1536, j = i - l*1536;
    float val;
    if (j < 512)       val = bq[l*512 + j] * QSF;
    else if (j < 1024) val = bk[l*512 + j - 512];
    else               val = bv[l*512 + j - 1024];
    fqkv[i] = val;
  }
  if (i < 4*HP) {
    const int l = i / HP, j = i - l*HP;
    fa[i] = (j < DHID) ? l0b[l*DHID2 + j] : 0.f;
    fb[i] = (j < DHID) ? l0b[l*DHID2 + DHID + j] : 0.f;
  }
}

__global__ void gather_cls(const ushort* __restrict__ xb, const float* __restrict__ x,
                           ushort* __restrict__ xq, float* __restrict__ xc)
{
  const int b = blockIdx.x, lane = threadIdx.x;
  const size_t src = (size_t)b*SEQ*DMODEL;
  *(short8*)(xq + b*DMODEL + lane*8) = *(const short8*)(xb + src + lane*8);
  *(float4*)(xc + b*DMODEL + lane*8)     = *(const float4*)(x + src + lane*8);
  *(float4*)(xc + b*DMODEL + lane*8 + 4) = *(const float4*)(x + src + lane*8 + 4);
}

__global__ void head_kernel(const float* __restrict__ xc, const float* __restrict__ g,
                            const float* __restrict__ be, const float* __restrict__ hw,
                            const float* __restrict__ hb, float* __restrict__ out)
{
  const int row = blockIdx.x;
  const int lane = threadIdx.x;
  const float* xr = xc + (size_t)row*DMODEL;
  float4 a = *(const float4*)(xr + lane*8);
  float4 b = *(const float4*)(xr + lane*8 + 4);
  float s  = a.x+a.y+a.z+a.w+b.x+b.y+b.z+b.w;
  float ss = a.x*a.x+a.y*a.y+a.z*a.z+a.w*a.w+b.x*b.x+b.y*b.y+b.z*b.z+b.w*b.w;
#pragma unroll
  for (int mask=1; mask<64; mask<<=1){ s += __shfl_xor(s,mask); ss += __shfl_xor(ss,mask); }
  const float mu = s*(1.f/512.f);
  const float rstd = rsqrtf(ss*(1.f/512.f) - mu*mu + 1e-5f);
  float vals[8] = {a.x,a.y,a.z,a.w,b.x,b.y,b.z,b.w};
  float acc = 0.f;
#pragma unroll
  for (int j=0;j<8;++j){
    const int c = lane*8 + j;
    float tv = (vals[j]-mu)*rstd*g[c] + be[c];
    acc += fmaxf(tv, 0.f) * hw[c];
  }
#pragma unroll
  for (int mask=1; mask<64; mask<<=1) acc += __shfl_xor(acc, mask);
  if (lane==0) out[row] = acc + hb[0];
}

// ---------------------------------------------------------------------------
extern "C" void kernel_launch(void* const* d_in, const int* in_sizes, int n_in,
                              void* d_out, int out_size, void* d_ws, size_t ws_size,
                              hipStream_t stream)
{
  const float* x_num = (const float*)d_in[0];
  const float* cls_w = (const float*)d_in[1];
  const float* Wq = (const float*)d_in[2];
  const float* bq = (const float*)d_in[3];
  const float* Wk = (const float*)d_in[4];
  const float* bk = (const float*)d_in[5];
  const float* Wv = (const float*)d_in[6];
  const float* bv = (const float*)d_in[7];
  const float* Wo = (const float*)d_in[8];
  const float* bo = (const float*)d_in[9];
  const float* l0_w = (const float*)d_in[10];
  const float* l0_b = (const float*)d_in[11];
  const float* l1_w = (const float*)d_in[12];
  const float* l1_b = (const float*)d_in[13];
  const float* n0_g = (const float*)d_in[14];
  const float* n0_b = (const float*)d_in[15];
  const float* n1_g = (const float*)d_in[16];
  const float* n1_b = (const float*)d_in[17];
  const float* ln_g = (const float*)d_in[18];
  const float* ln_b = (const float*)d_in[19];
  const float* head_w = (const float*)d_in[20];
  const float* head_b = (const float*)d_in[21];
  float* out = (float*)d_out;

  char* p = (char*)d_ws;
  auto alloc = [&](size_t bytes){ char* r = p; p += (bytes + 255) & ~(size_t)255; return r; };

  float* x  = (float*)alloc((size_t)NROWS*DMODEL*4);          // residual fp32
  char* U   = alloc((size_t)NROWS*DMODEL*2);                  // xb / attn-out
  ushort* xb = (ushort*)U;
  ushort* ob = (ushort*)U;
  char* QKVG = alloc((size_t)NROWS*QKVS*2);                   // qkv; also h [NROWS][768]
  ushort* qkv = (ushort*)QKVG;
  ushort* hbuf = (ushort*)QKVG;
  ushort* wqkvb = (ushort*)alloc((size_t)4*QKVS*512*2);
  ushort* wob  = (ushort*)alloc((size_t)4*512*512*2);
  ushort* wl0a = (ushort*)alloc((size_t)4*HP*512*2);
  ushort* wl0b = (ushort*)alloc((size_t)4*HP*512*2);
  ushort* l1wp = (ushort*)alloc((size_t)4*512*HP*2);
  float*  fqkvb = (float*)alloc((size_t)4*QKVS*4);
  float*  l0ba = (float*)alloc((size_t)4*HP*4);
  float*  l0bb = (float*)alloc((size_t)4*HP*4);
  ushort* xq_cls = (ushort*)alloc(128*512*2);
  float*  xcf = (float*)alloc(128*512*4);
  ushort* qc = (ushort*)alloc(128*512*2);
  ushort* oc = (ushort*)alloc(128*512*2);
  ushort* hc = (ushort*)alloc((size_t)128*HP*2);
  ushort* xcb = (ushort*)alloc(128*512*2);

  auto cdiv = [](size_t a, size_t b){ return (unsigned)((a + b - 1)/b); };

  // weight conversion: fused QKV [1536x512] per layer (q-part scaled by QSF)
  convert_pad<<<cdiv((size_t)4*512*512,256),256,0,stream>>>(Wq, wqkvb,            512,512,512,512,4, QSF, 0, 512, (size_t)QKVS*512);
  convert_pad<<<cdiv((size_t)4*512*512,256),256,0,stream>>>(Wk, wqkvb + 512*512,  512,512,512,512,4, 1.f, 0, 512, (size_t)QKVS*512);
  convert_pad<<<cdiv((size_t)4*512*512,256),256,0,stream>>>(Wv, wqkvb + 1024*512, 512,512,512,512,4, 1.f, 0, 512, (size_t)QKVS*512);
  convert_pad<<<cdiv((size_t)4*512*512,256),256,0,stream>>>(Wo, wob, 512,512,512,512,4, 1.f, 0, 512, (size_t)512*512);
  convert_pad<<<cdiv((size_t)4*HP*512,256),256,0,stream>>>(l0_w, wl0a, DHID,512,HP,512,4, 1.f, 0,    DHID2, (size_t)HP*512);
  convert_pad<<<cdiv((size_t)4*HP*512,256),256,0,stream>>>(l0_w, wl0b, DHID,512,HP,512,4, 1.f, DHID, DHID2, (size_t)HP*512);
  convert_pad<<<cdiv((size_t)4*512*HP,256),256,0,stream>>>(l1_w, l1wp, 512,DHID,512,HP,4, 1.f, 0, 512, (size_t)512*HP);
  build_bias<<<cdiv(4*QKVS,256),256,0,stream>>>(bq, bk, bv, l0_b, fqkvb, l0ba, l0bb);

  embed_kernel<<<cdiv((size_t)NROWS*128,256),256,0,stream>>>(x_num, cls_w, x, xb);

  const int nwQKV = 12*513, nwF = 6*513, nwKV = 8*513;
  const int nRL = NROWS/64;   // 1026
  for (int i = 0; i < 3; ++i) {
    gemm_bt<0><<<nwQKV,256,0,stream>>>(xb, wqkvb+(size_t)i*QKVS*512, fqkvb+(size_t)i*QKVS, qkv, nullptr, 512, QKVS, 12, nwQKV);
    attn_fused<<<5120,256,0,stream>>>(qkv, ob);
    // WO gemm + residual + LN(n1[i]) -> x, xb
    gemm_res_ln<<<nRL,256,0,stream>>>(ob, wob+(size_t)i*262144, bo+i*512, x,
                                      n1_g+(size_t)i*512, n1_b+(size_t)i*512, xb, 512);
    gemm_ffn<<<nwF,256,0,stream>>>(xb, wl0a+(size_t)i*HP*512, wl0b+(size_t)i*HP*512,
                                   l0ba+(size_t)i*HP, l0bb+(size_t)i*HP, hbuf, 512, HP, 6, nwF);
    // L1 gemm + residual + LN(n0[i]) -> x, xb  (consumed by layer i+1 / layer 3)
    gemm_res_ln<<<nRL,256,0,stream>>>(hbuf, l1wp+(size_t)i*512*HP, l1_b+i*512, x,
                                      n0_g+(size_t)i*512, n0_b+(size_t)i*512, xb, HP);
  }

  // layer 3 (CLS query only) — xb already = LN_n0[2](x)
  gather_cls<<<128,64,0,stream>>>(xb, x, xq_cls, xcf);
  gemm_bt<0><<<4,256,0,stream>>>(xq_cls, wqkvb+(size_t)3*QKVS*512, fqkvb+(size_t)3*QKVS, qc, nullptr, 512, 512, 4, 4);
  gemm_bt<0><<<nwKV,256,0,stream>>>(xb, wqkvb+(size_t)3*QKVS*512 + 512*512, fqkvb+(size_t)3*QKVS + 512,
                                    qkv + 512, nullptr, 512, QKVS, 8, nwKV);
  attn_cls<<<1024,256,0,stream>>>(qc, 512, qkv, oc, 512);
  gemm_bt<1><<<4,256,0,stream>>>(oc, wob+(size_t)3*262144, bo+3*512, nullptr, xcf, 512, 512, 4, 4);
  ln_kernel<<<cdiv(128,4),256,0,stream>>>(xcf, n1_g+3*512, n1_b+3*512, xcb, 128);
  gemm_ffn<<<6,256,0,stream>>>(xcb, wl0a+(size_t)3*HP*512, wl0b+(size_t)3*HP*512,
                               l0ba+(size_t)3*HP, l0bb+(size_t)3*HP, hc, 512, HP, 6, 6);
  gemm_bt<1><<<4,256,0,stream>>>(hc, l1wp+(size_t)3*512*HP, l1_b+3*512, nullptr, xcf, HP, 512, 4, 4);
  head_kernel<<<128,64,0,stream>>>(xcf, ln_g, ln_b, head_w, head_b, out);
}

// Round 17
// 2376.001 us; speedup vs baseline: 1.0854x; 1.0028x over previous
//
#include <hip/hip_runtime.h>
#include <stdint.h>

typedef __attribute__((ext_vector_type(4))) float f32x4;
typedef __attribute__((ext_vector_type(8))) short short8;
typedef __attribute__((ext_vector_type(8))) _Float16 half8;

#define DMODEL 512
#define SEQ 513
#define BATCH 128
#define NROWS (BATCH*SEQ)   // 65664 = 513 * 128
#define DHID 682
#define DHID2 1364
#define HP 768
#define QKVS 1536
#define KVB 64
#define NKT 9
#define QSF 0.1803368801111244f   // 0.125 * log2(e)

__device__ __forceinline__ float h2f(ushort u){ return (float)__builtin_bit_cast(_Float16, u); }
__device__ __forceinline__ ushort f2h(float f){ return __builtin_bit_cast(ushort, (_Float16)f); }
__device__ __forceinline__ uint pk2h(float a, float b){
  return __builtin_bit_cast(uint, __builtin_amdgcn_cvt_pkrtz(a, b));
}
__device__ __forceinline__ void gload16(const void* g, void* lds){
  __builtin_amdgcn_global_load_lds((const __attribute__((address_space(1))) void*)g,
                                   (__attribute__((address_space(3))) void*)lds, 16, 0, 0);
}
// bijective XCD-chunked flat-grid swizzle (m204)
__device__ __forceinline__ int xcd_wg(int orig, int nwg){
  const int q = nwg >> 3, r = nwg & 7;
  const int xcd = orig & 7, idx = orig >> 3;
  return (xcd < r) ? (xcd*(q+1) + idx) : (r*(q+1) + (xcd-r)*q + idx);
}

// ---------------------------------------------------------------------------
// GEMM: C[N x O] = A[N x K] @ W[O x K]^T (+bias). fp16 in, fp32 accum.
// 128x128 tile, BK=64, 4 waves, 32KB LDS, 3 blocks/CU, chunk-XOR swizzle.
// EPI=0: write fp16 Cb. EPI=1: Cf[idx] += acc + bias.
// ---------------------------------------------------------------------------
template<int EPI>
__global__ __launch_bounds__(256,3) void gemm_bt(
    const ushort* __restrict__ A, const ushort* __restrict__ W,
    const float* __restrict__ bias, ushort* __restrict__ Cb, float* __restrict__ Cf,
    int K, int ldc, int gx, int nwg)
{
  __shared__ char lds[32768];       // As @0, Ws @16384
  const int t = threadIdx.x, lane = t & 63, w = t >> 6;
  const int fr = lane & 15, g = lane >> 4;
  const int l7 = lane & 7, l8 = lane >> 3;
  const int wg = xcd_wg(blockIdx.x, nwg);
  const int row0 = (wg / gx) << 7;
  const int col0 = (wg % gx) << 7;
  const int wr = (w >> 1) << 6, wc = (w & 1) << 6;

  const int chunkoff = (l7 ^ l8) << 3;
  const ushort* Ag = A + (size_t)(row0 + w*8 + l8) * K + chunkoff;
  const ushort* Wg = W + (size_t)(col0 + w*8 + l8) * K + chunkoff;

  f32x4 acc[4][4] = {};

  for (int k0 = 0; k0 < K; k0 += 64) {
    __syncthreads();
#pragma unroll
    for (int p = 0; p < 4; ++p) {
      gload16(Ag + (size_t)(p*32)*K + k0, lds + p*4096 + w*1024);
      gload16(Wg + (size_t)(p*32)*K + k0, lds + 16384 + p*4096 + w*1024);
    }
    __syncthreads();
#pragma unroll
    for (int ks = 0; ks < 2; ++ks) {
      half8 af[4], wf[4];
#pragma unroll
      for (int m = 0; m < 4; ++m) {
        const int row = wr + m*16 + fr;
        af[m] = *(const half8*)(lds + row*128 + (((g + ks*4) ^ (fr & 7)) << 4));
      }
#pragma unroll
      for (int n = 0; n < 4; ++n) {
        const int row = wc + n*16 + fr;
        wf[n] = *(const half8*)(lds + 16384 + row*128 + (((g + ks*4) ^ (fr & 7)) << 4));
      }
#pragma unroll
      for (int m = 0; m < 4; ++m)
#pragma unroll
        for (int n = 0; n < 4; ++n)
          acc[m][n] = __builtin_amdgcn_mfma_f32_16x16x32_f16(af[m], wf[n], acc[m][n], 0, 0, 0);
    }
  }

  const int r0 = (lane >> 4) << 2;
#pragma unroll
  for (int m = 0; m < 4; ++m) {
    const int rg = row0 + wr + m*16 + r0;
#pragma unroll
    for (int n = 0; n < 4; ++n) {
      const int cg = col0 + wc + n*16 + fr;
      const float bi = bias[cg];
      if (EPI == 0) {
#pragma unroll
        for (int r = 0; r < 4; ++r)
          Cb[(size_t)(rg + r)*ldc + cg] = f2h(acc[m][n][r] + bi);
      } else {
#pragma unroll
        for (int r = 0; r < 4; ++r) {
          const size_t ix = (size_t)(rg + r)*ldc + cg;
          Cf[ix] += acc[m][n][r] + bi;
        }
      }
    }
  }
}

// ---------------------------------------------------------------------------
// Fused residual GEMM + LayerNorm, vectorized epilogue v4 (round-14 proven).
// XW=1: write full fp32 x. XW=0: write x only for CLS rows (row%513==0) —
// used for the final call whose x output is consumed only by gather_cls.
// ---------------------------------------------------------------------------
template<int XW>
__global__ __launch_bounds__(256,2) void gemm_res_ln(
    const ushort* __restrict__ A, const ushort* __restrict__ W,
    const float* __restrict__ bias, float* __restrict__ x,
    const float* __restrict__ gamma, const float* __restrict__ beta,
    ushort* __restrict__ xb, int K)
{
  __shared__ char lds[73728];        // K-loop: A [64][128B] @0, W [512][128B] @8192
                                     // epilogue: fb16 @0, redrow @66560, gb @67072
  const int t = threadIdx.x, lane = t & 63, w = t >> 6;
  const int fr = lane & 15, g = lane >> 4;
  const int l7 = lane & 7, l8 = lane >> 3;
  const int row0 = blockIdx.x << 6;

  const int chunkoff = (l7 ^ l8) << 3;
  const ushort* Ag = A + (size_t)(row0 + w*8 + l8) * K + chunkoff;
  const ushort* Wg = W + (size_t)(w*8 + l8) * K + chunkoff;

  f32x4 acc[4][8] = {};

  for (int k0 = 0; k0 < K; k0 += 64) {
    __syncthreads();
    gload16(Ag + k0,                 lds + w*1024);
    gload16(Ag + (size_t)32*K + k0,  lds + 4096 + w*1024);
#pragma unroll
    for (int p = 0; p < 16; ++p)
      gload16(Wg + (size_t)(p*32)*K + k0, lds + 8192 + p*4096 + w*1024);
    __syncthreads();
#pragma unroll
    for (int ks = 0; ks < 2; ++ks) {
      half8 af[4], wf[8];
#pragma unroll
      for (int m = 0; m < 4; ++m) {
        const int row = m*16 + fr;
        af[m] = *(const half8*)(lds + row*128 + (((g + ks*4) ^ (fr & 7)) << 4));
      }
#pragma unroll
      for (int n = 0; n < 8; ++n) {
        const int row = (w << 7) + n*16 + fr;
        wf[n] = *(const half8*)(lds + 8192 + row*128 + (((g + ks*4) ^ (fr & 7)) << 4));
      }
#pragma unroll
      for (int m = 0; m < 4; ++m)
#pragma unroll
        for (int n = 0; n < 8; ++n)
          acc[m][n] = __builtin_amdgcn_mfma_f32_16x16x32_f16(af[m], wf[n], acc[m][n], 0, 0, 0);
    }
  }

  // ---------------- epilogue v4 ----------------
  ushort* fb16   = (ushort*)lds;              // [64][520]
  float2* redrow = (float2*)(lds + 66560);    // [64]
  float*  gb     = (float*)(lds + 67072);     // gamma[512] | beta[512]

  __syncthreads();
#pragma unroll
  for (int n = 0; n < 8; ++n) {
    const int cg = (w << 7) + n*16 + fr;
    const float bi = bias[cg];
#pragma unroll
    for (int m = 0; m < 4; ++m)
#pragma unroll
      for (int r = 0; r < 4; ++r)
        fb16[(m*16 + g*4 + r)*520 + cg] = f2h(acc[m][n][r] + bi);
  }
  if (t < 128) *(f32x4*)&gb[t*4]            = *(const f32x4*)&gamma[t*4];
  else         *(f32x4*)&gb[512 + (t-128)*4] = *(const f32x4*)&beta[(t-128)*4];
  __syncthreads();

  const int q = t & 15;
  const int rbase = t >> 4;
#pragma unroll
  for (int rr = 0; rr < 4; ++rr) {
    const int row = rr*16 + rbase;
    const int grow = row0 + row;
    const bool wrx = XW || (grow % SEQ) == 0;
    const size_t xrow = (size_t)grow*DMODEL;
    float ps = 0.f, pss = 0.f;
#pragma unroll
    for (int j = 0; j < 8; ++j) {
      const int c = q*4 + j*64;
      const uint2 pk = *(const uint2*)&fb16[row*520 + c];
      f32x4 v;
      v[0] = h2f((ushort)(pk.x & 0xffffu)); v[1] = h2f((ushort)(pk.x >> 16));
      v[2] = h2f((ushort)(pk.y & 0xffffu)); v[3] = h2f((ushort)(pk.y >> 16));
      const f32x4 xo = *(const f32x4*)&x[xrow + c];
      v += xo;
      if (wrx) *(f32x4*)&x[xrow + c] = v;
      uint2 opk; opk.x = pk2h(v[0], v[1]); opk.y = pk2h(v[2], v[3]);
      *(uint2*)&fb16[row*520 + c] = opk;
      ps  += v[0]+v[1]+v[2]+v[3];
      pss += v[0]*v[0]+v[1]*v[1]+v[2]*v[2]+v[3]*v[3];
    }
#pragma unroll
    for (int mask = 1; mask <= 8; mask <<= 1) {
      ps  += __shfl_xor(ps,  mask);
      pss += __shfl_xor(pss, mask);
    }
    if (q == 0) redrow[row] = float2{ps, pss};
  }
  __syncthreads();
#pragma unroll
  for (int rr = 0; rr < 4; ++rr) {
    const int row = rr*16 + rbase;
    const float2 sr = redrow[row];
    const float mu = sr.x * (1.f/512.f);
    const float rstd = rsqrtf(sr.y*(1.f/512.f) - mu*mu + 1e-5f);
    const size_t xbrow = (size_t)(row0 + row)*DMODEL;
#pragma unroll
    for (int j = 0; j < 8; ++j) {
      const int c = q*4 + j*64;
      const uint2 pk = *(const uint2*)&fb16[row*520 + c];
      f32x4 v;
      v[0] = h2f((ushort)(pk.x & 0xffffu)); v[1] = h2f((ushort)(pk.x >> 16));
      v[2] = h2f((ushort)(pk.y & 0xffffu)); v[3] = h2f((ushort)(pk.y >> 16));
      const f32x4 ga = *(const f32x4*)&gb[c];
      const f32x4 be = *(const f32x4*)&gb[512 + c];
      f32x4 o_;
#pragma unroll
      for (int e = 0; e < 4; ++e) o_[e] = (v[e] - mu)*rstd*ga[e] + be[e];
      uint2 u; u.x = pk2h(o_[0], o_[1]); u.y = pk2h(o_[2], o_[3]);
      *(uint2*)&xb[xbrow + c] = u;
    }
  }
}

// ---------------------------------------------------------------------------
// Fused FFN-up + ReGLU: H[N x 768] = (A@Wa^T + ba) * relu(A@Wb^T + bb), fp16.
// BK=64 swizzled; 48KB LDS, 2 blocks/CU.
// ---------------------------------------------------------------------------
__global__ __launch_bounds__(256,2) void gemm_ffn(
    const ushort* __restrict__ A, const ushort* __restrict__ Wa, const ushort* __restrict__ Wb,
    const float* __restrict__ ba, const float* __restrict__ bb, ushort* __restrict__ H,
    int K, int ldc, int gx, int nwg)
{
  __shared__ char lds[49152];       // As @0, Was @16384, Wbs @32768
  const int t = threadIdx.x, lane = t & 63, w = t >> 6;
  const int fr = lane & 15, g = lane >> 4;
  const int l7 = lane & 7, l8 = lane >> 3;
  const int wg = xcd_wg(blockIdx.x, nwg);
  const int row0 = (wg / gx) << 7;
  const int col0 = (wg % gx) << 7;
  const int wr = (w >> 1) << 6, wc = (w & 1) << 6;

  const int chunkoff = (l7 ^ l8) << 3;
  const ushort* Ag  = A  + (size_t)(row0 + w*8 + l8) * K + chunkoff;
  const ushort* WaG = Wa + (size_t)(col0 + w*8 + l8) * K + chunkoff;
  const ushort* WbG = Wb + (size_t)(col0 + w*8 + l8) * K + chunkoff;

  f32x4 aa[4][4] = {}, ab[4][4] = {};

  for (int k0 = 0; k0 < K; k0 += 64) {
    __syncthreads();
#pragma unroll
    for (int p = 0; p < 4; ++p) {
      gload16(Ag  + (size_t)(p*32)*K + k0, lds + p*4096 + w*1024);
      gload16(WaG + (size_t)(p*32)*K + k0, lds + 16384 + p*4096 + w*1024);
      gload16(WbG + (size_t)(p*32)*K + k0, lds + 32768 + p*4096 + w*1024);
    }
    __syncthreads();
#pragma unroll
    for (int ks = 0; ks < 2; ++ks) {
      half8 af[4], wa[4], wb[4];
#pragma unroll
      for (int m = 0; m < 4; ++m) {
        const int row = wr + m*16 + fr;
        af[m] = *(const half8*)(lds + row*128 + (((g + ks*4) ^ (fr & 7)) << 4));
      }
#pragma unroll
      for (int n = 0; n < 4; ++n) {
        const int row = wc + n*16 + fr;
        const int off = row*128 + (((g + ks*4) ^ (fr & 7)) << 4);
        wa[n] = *(const half8*)(lds + 16384 + off);
        wb[n] = *(const half8*)(lds + 32768 + off);
      }
#pragma unroll
      for (int m = 0; m < 4; ++m)
#pragma unroll
        for (int n = 0; n < 4; ++n) {
          aa[m][n] = __builtin_amdgcn_mfma_f32_16x16x32_f16(af[m], wa[n], aa[m][n], 0, 0, 0);
          ab[m][n] = __builtin_amdgcn_mfma_f32_16x16x32_f16(af[m], wb[n], ab[m][n], 0, 0, 0);
        }
    }
  }

  const int r0 = (lane >> 4) << 2;
#pragma unroll
  for (int m = 0; m < 4; ++m) {
    const int rg = row0 + wr + m*16 + r0;
#pragma unroll
    for (int n = 0; n < 4; ++n) {
      const int cg = col0 + wc + n*16 + fr;
      const float bav = ba[cg], bbv = bb[cg];
#pragma unroll
      for (int r = 0; r < 4; ++r) {
        const float av = aa[m][n][r] + bav;
        const float bv = ab[m][n][r] + bbv;
        H[(size_t)(rg + r)*ldc + cg] = f2h(av * fmaxf(bv, 0.f));
      }
    }
  }
}

// ---------------------------------------------------------------------------
// Fused attention (round-14 proven): 256 threads, 4 waves, 128 q-rows/block.
// blocks 0..4095 = flash path; blocks 4096..5119 = CLS-row path (q row 512).
// ---------------------------------------------------------------------------
__global__ __launch_bounds__(256,4) void attn_fused(
    const ushort* __restrict__ qkv, ushort* __restrict__ o)
{
  __shared__ char lds[40960];
  const int t = threadIdx.x;

  if (blockIdx.x >= 4096) {
    const int bh = blockIdx.x - 4096;
    const int b = bh >> 3, h = bh & 7;
    float* sc   = (float*)lds;
    float* qsh  = (float*)(lds + 2112);
    float* red  = (float*)(lds + 2368);
    float* osum = (float*)(lds + 2432);
    const ushort* k = qkv + 512;
    const ushort* v = qkv + 1024;
    const ushort* qb2 = qkv + (size_t)512*QKVS;
    if (t < 64) qsh[t] = h2f(qb2[(size_t)b*SEQ*QKVS + h*64 + t]);
    __syncthreads();
    for (int key = t; key < SEQ; key += 256) {
      const ushort* kr = k + ((size_t)b*SEQ + key)*QKVS + h*64;
      float s = 0.f;
#pragma unroll 8
      for (int d = 0; d < 64; ++d) s += qsh[d]*h2f(kr[d]);
      sc[key] = s;
    }
    __syncthreads();
    float lm = -1e30f;
    for (int key = t; key < SEQ; key += 256) lm = fmaxf(lm, sc[key]);
#pragma unroll
    for (int mask=1; mask<64; mask<<=1) lm = fmaxf(lm, __shfl_xor(lm, mask));
    if ((t&63)==0) red[t>>6] = lm;
    __syncthreads();
    const float mx = fmaxf(fmaxf(red[0],red[1]), fmaxf(red[2],red[3]));
    float ls = 0.f;
    for (int key = t; key < SEQ; key += 256){ float pp = exp2f(sc[key]-mx); sc[key]=pp; ls += pp; }
#pragma unroll
    for (int mask=1; mask<64; mask<<=1) ls += __shfl_xor(ls, mask);
    if ((t&63)==0) red[4 + (t>>6)] = ls;
    __syncthreads();
    const float ssum = red[4]+red[5]+red[6]+red[7];
    const int d = t & 63, kc = t >> 6;
    float op = 0.f;
    for (int key = kc; key < SEQ; key += 4)
      op += sc[key] * h2f(v[((size_t)b*SEQ + key)*QKVS + h*64 + d]);
    osum[t] = op;
    __syncthreads();
    if (t < 64) {
      const float oo = (osum[t]+osum[64+t]+osum[128+t]+osum[192+t]) / ssum;
      o[((size_t)b*SEQ + 512)*DMODEL + h*64 + t] = f2h(oo);
    }
    return;
  }

  const int bid = blockIdx.x;
  const int sw = (bid & 7)*512 + (bid >> 3);
  const int qt = sw & 3;
  const int hb = sw >> 2;
  const int h = hb & 7, b = hb >> 3;
  const int lane = t & 63, w = t >> 6;
  const int fr = lane & 15, g = lane >> 4, gq4 = g << 2;
  const size_t rowB = (size_t)b * SEQ;
  const ushort* q = qkv;
  const ushort* k = qkv + 512;
  const ushort* v = qkv + 1024;

  char* const Ks  = lds;
  char* const Vs  = lds + 8192;
  char* const VTs = lds + 16384;
  char* const pb  = lds + 24576 + w*4096;

  const int qr0 = qt*128 + w*32;

  half8 qf[2][2];
#pragma unroll
  for (int nq = 0; nq < 2; ++nq) {
    const int qrow = qr0 + nq*16 + fr;
#pragma unroll
    for (int kk = 0; kk < 2; ++kk)
      qf[nq][kk] = *(const half8*)&q[(rowB + qrow)*QKVS + h*64 + kk*32 + g*8];
  }

  f32x4 accO[2][4] = {};
  float mrun[2] = {-1e30f, -1e30f};
  float lrun[2] = {0.f, 0.f};

  const int l8 = lane >> 3, l7 = lane & 7;
  const int chunk = l7 ^ l8;
  auto STAGE = [&](int kt2) {
#pragma unroll
    for (int i = 0; i < 2; ++i) {
      const int row = i*32 + (w<<3) + l8;
      const int keyg = min(kt2*KVB + row, 512);
      const size_t gsrc = (rowB + keyg)*QKVS + h*64 + chunk*8;
      gload16(k + gsrc, Ks + i*4096 + w*1024);
      gload16(v + gsrc, Vs + i*4096 + w*1024);
    }
  };

  const int db  = (lane & 7) | ((w & 1) << 3);
  const int kbq = l8 | ((w & 2) << 2);
  const int d0 = db << 2, key0 = kbq << 2;

  STAGE(0);

  for (int kt = 0; kt < NKT; ++kt) {
    __syncthreads();

    f32x4 sc4[4][2] = {};
    __builtin_amdgcn_s_setprio(1);
#pragma unroll
    for (int kk = 0; kk < 2; ++kk) {
      half8 kf[4];
#pragma unroll
      for (int mk = 0; mk < 4; ++mk) {
        const int row = mk*16 + fr;
        kf[mk] = *(const half8*)(Ks + row*128 + ((kk*64 + g*16) ^ ((fr&7)<<4)));
      }
#pragma unroll
      for (int mk = 0; mk < 4; ++mk)
#pragma unroll
        for (int nq = 0; nq < 2; ++nq)
          sc4[mk][nq] = __builtin_amdgcn_mfma_f32_16x16x32_f16(kf[mk], qf[nq][kk], sc4[mk][nq], 0, 0, 0);
    }
    __builtin_amdgcn_s_setprio(0);

    {
      uint2 a[4];
#pragma unroll
      for (int i = 0; i < 4; ++i) {
        const int row = key0 + i;
        a[i] = *(const uint2*)(Vs + row*128 + ((d0*2) ^ ((row&7)<<4)));
      }
      uint2 bb[4];
      bb[0].x = (a[0].x & 0xffffu) | (a[1].x << 16);
      bb[0].y = (a[2].x & 0xffffu) | (a[3].x << 16);
      bb[1].x = (a[0].x >> 16) | (a[1].x & 0xffff0000u);
      bb[1].y = (a[2].x >> 16) | (a[3].x & 0xffff0000u);
      bb[2].x = (a[0].y & 0xffffu) | (a[1].y << 16);
      bb[2].y = (a[2].y & 0xffffu) | (a[3].y << 16);
      bb[3].x = (a[0].y >> 16) | (a[1].y & 0xffff0000u);
      bb[3].y = (a[2].y >> 16) | (a[3].y & 0xffff0000u);
#pragma unroll
      for (int j = 0; j < 4; ++j) {
        const int drow = d0 + j;
        *(uint2*)(VTs + drow*128 + ((key0*2) ^ ((drow&7)<<4))) = bb[j];
      }
    }

    if (kt == NKT-1) {
#pragma unroll
      for (int mk = 0; mk < 4; ++mk)
#pragma unroll
        for (int r = 0; r < 4; ++r)
          if (mk + gq4 + r) { sc4[mk][0][r] = -1e30f; sc4[mk][1][r] = -1e30f; }
    }

    __syncthreads();

    if (kt+1 < NKT) STAGE(kt+1);

    float al2[2];
    bool resc[2];
#pragma unroll
    for (int nq = 0; nq < 2; ++nq) {
      float tm = sc4[0][nq][0];
#pragma unroll
      for (int mk = 0; mk < 4; ++mk)
#pragma unroll
        for (int r = 0; r < 4; ++r) tm = fmaxf(tm, sc4[mk][nq][r]);
      tm = fmaxf(tm, __shfl_xor(tm, 16));
      tm = fmaxf(tm, __shfl_xor(tm, 32));
      float mref;
      if (__all(tm - mrun[nq] <= 8.f)) {
        mref = mrun[nq];
        al2[nq] = 1.f; resc[nq] = false;
      } else {
        const float mnew = fmaxf(mrun[nq], tm);
        al2[nq] = exp2f(mrun[nq] - mnew);
        mrun[nq] = mnew;
        mref = mnew;
        resc[nq] = true;
      }
      float rs = 0.f;
#pragma unroll
      for (int mk = 0; mk < 4; ++mk)
#pragma unroll
        for (int r = 0; r < 4; ++r) {
          const float pv = exp2f(sc4[mk][nq][r] - mref);
          sc4[mk][nq][r] = pv;
          rs += pv;
        }
      rs += __shfl_xor(rs, 16);
      rs += __shfl_xor(rs, 32);
      lrun[nq] = resc[nq] ? (lrun[nq]*al2[nq] + rs) : (lrun[nq] + rs);
      char* prow = pb + (nq*16 + fr)*128;
#pragma unroll
      for (int mk = 0; mk < 4; ++mk) {
        uint2 pk;
        pk.x = pk2h(sc4[mk][nq][0], sc4[mk][nq][1]);
        pk.y = pk2h(sc4[mk][nq][2], sc4[mk][nq][3]);
        *(uint2*)(prow + ((mk*32 + gq4*2) ^ ((fr&7)<<4))) = pk;
      }
    }

#pragma unroll
    for (int mq = 0; mq < 2; ++mq) {
      if (resc[mq]) {
#pragma unroll
        for (int r = 0; r < 4; ++r) {
          const float alr = __shfl(al2[mq], (lane & 48) | (gq4 + r));
#pragma unroll
          for (int dn = 0; dn < 4; ++dn) accO[mq][dn][r] *= alr;
        }
      }
    }

    asm volatile("" ::: "memory");

    __builtin_amdgcn_s_setprio(1);
#pragma unroll
    for (int kk2 = 0; kk2 < 2; ++kk2) {
      half8 pf[2];
#pragma unroll
      for (int mq = 0; mq < 2; ++mq)
        pf[mq] = *(const half8*)(pb + (mq*16 + fr)*128 + ((kk2*64 + g*16) ^ ((fr&7)<<4)));
      half8 vf[4];
#pragma unroll
      for (int dn = 0; dn < 4; ++dn) {
        const int row = dn*16 + fr;
        vf[dn] = *(const half8*)(VTs + row*128 + ((kk2*64 + g*16) ^ ((fr&7)<<4)));
      }
#pragma unroll
      for (int mq = 0; mq < 2; ++mq)
#pragma unroll
        for (int dn = 0; dn < 4; ++dn)
          accO[mq][dn] = __builtin_amdgcn_mfma_f32_16x16x32_f16(pf[mq], vf[dn], accO[mq][dn], 0, 0, 0);
    }
    __builtin_amdgcn_s_setprio(0);
  }

#pragma unroll
  for (int mq = 0; mq < 2; ++mq)
#pragma unroll
    for (int r = 0; r < 4; ++r) {
      const int qrow = qr0 + mq*16 + gq4 + r;
      const float ls = __shfl(lrun[mq], (lane & 48) | (gq4 + r));
      const float inv = 1.f / ls;
#pragma unroll
      for (int dn = 0; dn < 4; ++dn)
        o[(rowB + qrow)*DMODEL + h*64 + dn*16 + fr] = f2h(accO[mq][dn][r] * inv);
    }
}

// ---------------------------------------------------------------------------
// Standalone single-q attention (layer-3 decode; q/out stride 512).
// ---------------------------------------------------------------------------
__global__ __launch_bounds__(256) void attn_cls(
    const ushort* __restrict__ qbase, size_t qstride,
    const ushort* __restrict__ qkv,
    ushort* __restrict__ obase, size_t ostride)
{
  const int bh = blockIdx.x;
  const int b = bh >> 3, h = bh & 7;
  const int t = threadIdx.x;
  __shared__ float sc[SEQ];
  __shared__ float qsh[64];
  __shared__ float red[8];
  __shared__ float osum[256];
  const ushort* k = qkv + 512;
  const ushort* v = qkv + 1024;
  if (t < 64) qsh[t] = h2f(qbase[(size_t)b*qstride + h*64 + t]);
  __syncthreads();
  for (int key = t; key < SEQ; key += 256) {
    const ushort* kr = k + ((size_t)b*SEQ + key)*QKVS + h*64;
    float s = 0.f;
#pragma unroll 8
    for (int d = 0; d < 64; ++d) s += qsh[d]*h2f(kr[d]);
    sc[key] = s;
  }
  __syncthreads();
  float lm = -1e30f;
  for (int key = t; key < SEQ; key += 256) lm = fmaxf(lm, sc[key]);
#pragma unroll
  for (int mask=1; mask<64; mask<<=1) lm = fmaxf(lm, __shfl_xor(lm, mask));
  if ((t&63)==0) red[t>>6] = lm;
  __syncthreads();
  const float mx = fmaxf(fmaxf(red[0],red[1]), fmaxf(red[2],red[3]));
  float ls = 0.f;
  for (int key = t; key < SEQ; key += 256){ float pp = exp2f(sc[key]-mx); sc[key]=pp; ls += pp; }
#pragma unroll
  for (int mask=1; mask<64; mask<<=1) ls += __shfl_xor(ls, mask);
  if ((t&63)==0) red[4 + (t>>6)] = ls;
  __syncthreads();
  const float ssum = red[4]+red[5]+red[6]+red[7];
  const int d = t & 63, kc = t >> 6;
  float op = 0.f;
  for (int key = kc; key < SEQ; key += 4)
    op += sc[key] * h2f(v[((size_t)b*SEQ + key)*QKVS + h*64 + d]);
  osum[t] = op;
  __syncthreads();
  if (t < 64) {
    const float oo = (osum[t]+osum[64+t]+osum[128+t]+osum[192+t]) / ssum;
    obase[(size_t)b*ostride + h*64 + t] = f2h(oo);
  }
}

// ---------------------------------------------------------------------------
__global__ __launch_bounds__(256) void ln_kernel(
    const float* __restrict__ x, const float* __restrict__ gamma, const float* __restrict__ beta,
    ushort* __restrict__ out, int nrows)
{
  const int row = blockIdx.x*4 + (threadIdx.x >> 6);
  const int lane = threadIdx.x & 63;
  if (row >= nrows) return;
  const float* xr = x + (size_t)row*DMODEL;
  float4 a = *(const float4*)(xr + lane*8);
  float4 b = *(const float4*)(xr + lane*8 + 4);
  float s  = a.x+a.y+a.z+a.w+b.x+b.y+b.z+b.w;
  float ss = a.x*a.x+a.y*a.y+a.z*a.z+a.w*a.w+b.x*b.x+b.y*b.y+b.z*b.z+b.w*b.w;
#pragma unroll
  for (int mask=1; mask<64; mask<<=1){ s += __shfl_xor(s,mask); ss += __shfl_xor(ss,mask); }
  const float mu = s*(1.f/512.f);
  const float rstd = rsqrtf(ss*(1.f/512.f) - mu*mu + 1e-5f);
  float vals[8] = {a.x,a.y,a.z,a.w,b.x,b.y,b.z,b.w};
  short8 pk;
#pragma unroll
  for (int j=0;j<8;++j){
    const int c = lane*8 + j;
    pk[j] = (short)f2h((vals[j]-mu)*rstd*gamma[c] + beta[c]);
  }
  *(short8*)(out + (size_t)row*DMODEL + lane*8) = pk;
}

// ---------------------------------------------------------------------------
__global__ void embed_kernel(const float* __restrict__ x_num, const float* __restrict__ cls_w,
                             float* __restrict__ x, ushort* __restrict__ xb)
{
  const size_t i = (size_t)blockIdx.x*256 + threadIdx.x;
  if (i >= (size_t)NROWS*128) return;
  const int row = (int)(i >> 7);
  const int c4 = ((int)(i & 127)) << 2;
  const int b = row / SEQ;
  const int s = row - b*SEQ;
  float4 val;
  if (s == 0) val = *(const float4*)(cls_w + c4);
  else        val = *(const float4*)(x_num + ((size_t)b*512 + (s-1))*512 + c4);
  *(float4*)(x + (size_t)row*DMODEL + c4) = val;
  ushort4 pk;
  pk.x = f2h(val.x); pk.y = f2h(val.y); pk.z = f2h(val.z); pk.w = f2h(val.w);
  *(ushort4*)(xb + (size_t)row*DMODEL + c4) = pk;
}

// ---------------------------------------------------------------------------
__global__ void convert_pad(const float* __restrict__ in, ushort* __restrict__ out,
                            int R, int C, int RP, int CP, int layers, float scale,
                            int r0, int srcRL, size_t ostride)
{
  const size_t i = (size_t)blockIdx.x*256 + threadIdx.x;
  const size_t per = (size_t)RP*CP;
  if (i >= per*layers) return;
  const int l = (int)(i / per);
  const int rem = (int)(i - (size_t)l*per);
  const int r = rem / CP;
  const int c = rem - r*CP;
  ushort val = 0;
  if (r < R && c < C) val = f2h(in[((size_t)l*srcRL + r0 + r)*C + c] * scale);
  out[(size_t)l*ostride + (size_t)r*CP + c] = val;
}

__global__ void build_bias(const float* __restrict__ bq, const float* __restrict__ bk,
                           const float* __restrict__ bv, const float* __restrict__ l0b,
                           float* __restrict__ fqkv, float* __restrict__ fa, float* __restrict__ fb)
{
  const int i = blockIdx.x*256 + threadIdx.x;
  if (i < 4*1536) {
    const int l = i / 1536, j = i - l*1536;
    float val;
    if (j < 512)       val = bq[l*512 + j] * QSF;
    else if (j < 1024) val = bk[l*512 + j - 512];
    else               val = bv[l*512 + j - 1024];
    fqkv[i] = val;
  }
  if (i < 4*HP) {
    const int l = i / HP, j = i - l*HP;
    fa[i] = (j < DHID) ? l0b[l*DHID2 + j] : 0.f;
    fb[i] = (j < DHID) ? l0b[l*DHID2 + DHID + j] : 0.f;
  }
}

__global__ void gather_cls(const ushort* __restrict__ xb, const float* __restrict__ x,
                           ushort* __restrict__ xq, float* __restrict__ xc)
{
  const int b = blockIdx.x, lane = threadIdx.x;
  const size_t src = (size_t)b*SEQ*DMODEL;
  *(short8*)(xq + b*DMODEL + lane*8) = *(const short8*)(xb + src + lane*8);
  *(float4*)(xc + b*DMODEL + lane*8)     = *(const float4*)(x + src + lane*8);
  *(float4*)(xc + b*DMODEL + lane*8 + 4) = *(const float4*)(x + src + lane*8 + 4);
}

__global__ void head_kernel(const float* __restrict__ xc, const float* __restrict__ g,
                            const float* __restrict__ be, const float* __restrict__ hw,
                            const float* __restrict__ hb, float* __restrict__ out)
{
  const int row = blockIdx.x;
  const int lane = threadIdx.x;
  const float* xr = xc + (size_t)row*DMODEL;
  float4 a = *(const float4*)(xr + lane*8);
  float4 b = *(const float4*)(xr + lane*8 + 4);
  float s  = a.x+a.y+a.z+a.w+b.x+b.y+b.z+b.w;
  float ss = a.x*a.x+a.y*a.y+a.z*a.z+a.w*a.w+b.x*b.x+b.y*b.y+b.z*b.z+b.w*b.w;
#pragma unroll
  for (int mask=1; mask<64; mask<<=1){ s += __shfl_xor(s,mask); ss += __shfl_xor(ss,mask); }
  const float mu = s*(1.f/512.f);
  const float rstd = rsqrtf(ss*(1.f/512.f) - mu*mu + 1e-5f);
  float vals[8] = {a.x,a.y,a.z,a.w,b.x,b.y,b.z,b.w};
  float acc = 0.f;
#pragma unroll
  for (int j=0;j<8;++j){
    const int c = lane*8 + j;
    float tv = (vals[j]-mu)*rstd*g[c] + be[c];
    acc += fmaxf(tv, 0.f) * hw[c];
  }
#pragma unroll
  for (int mask=1; mask<64; mask<<=1) acc += __shfl_xor(acc, mask);
  if (lane==0) out[row] = acc + hb[0];
}

// ---------------------------------------------------------------------------
extern "C" void kernel_launch(void* const* d_in, const int* in_sizes, int n_in,
                              void* d_out, int out_size, void* d_ws, size_t ws_size,
                              hipStream_t stream)
{
  const float* x_num = (const float*)d_in[0];
  const float* cls_w = (const float*)d_in[1];
  const float* Wq = (const float*)d_in[2];
  const float* bq = (const float*)d_in[3];
  const float* Wk = (const float*)d_in[4];
  const float* bk = (const float*)d_in[5];
  const float* Wv = (const float*)d_in[6];
  const float* bv = (const float*)d_in[7];
  const float* Wo = (const float*)d_in[8];
  const float* bo = (const float*)d_in[9];
  const float* l0_w = (const float*)d_in[10];
  const float* l0_b = (const float*)d_in[11];
  const float* l1_w = (const float*)d_in[12];
  const float* l1_b = (const float*)d_in[13];
  const float* n0_g = (const float*)d_in[14];
  const float* n0_b = (const float*)d_in[15];
  const float* n1_g = (const float*)d_in[16];
  const float* n1_b = (const float*)d_in[17];
  const float* ln_g = (const float*)d_in[18];
  const float* ln_b = (const float*)d_in[19];
  const float* head_w = (const float*)d_in[20];
  const float* head_b = (const float*)d_in[21];
  float* out = (float*)d_out;

  char* p = (char*)d_ws;
  auto alloc = [&](size_t bytes){ char* r = p; p += (bytes + 255) & ~(size_t)255; return r; };

  float* x  = (float*)alloc((size_t)NROWS*DMODEL*4);          // residual fp32
  char* U   = alloc((size_t)NROWS*DMODEL*2);                  // xb / attn-out
  ushort* xb = (ushort*)U;
  ushort* ob = (ushort*)U;
  char* QKVG = alloc((size_t)NROWS*QKVS*2);                   // qkv; also h [NROWS][768]
  ushort* qkv = (ushort*)QKVG;
  ushort* hbuf = (ushort*)QKVG;
  ushort* wqkvb = (ushort*)alloc((size_t)4*QKVS*512*2);
  ushort* wob  = (ushort*)alloc((size_t)4*512*512*2);
  ushort* wl0a = (ushort*)alloc((size_t)4*HP*512*2);
  ushort* wl0b = (ushort*)alloc((size_t)4*HP*512*2);
  ushort* l1wp = (ushort*)alloc((size_t)4*512*HP*2);
  float*  fqkvb = (float*)alloc((size_t)4*QKVS*4);
  float*  l0ba = (float*)alloc((size_t)4*HP*4);
  float*  l0bb = (float*)alloc((size_t)4*HP*4);
  ushort* xq_cls = (ushort*)alloc(128*512*2);
  float*  xcf = (float*)alloc(128*512*4);
  ushort* qc = (ushort*)alloc(128*512*2);
  ushort* oc = (ushort*)alloc(128*512*2);
  ushort* hc = (ushort*)alloc((size_t)128*HP*2);
  ushort* xcb = (ushort*)alloc(128*512*2);

  auto cdiv = [](size_t a, size_t b){ return (unsigned)((a + b - 1)/b); };

  // weight conversion: fused QKV [1536x512] per layer (q-part scaled by QSF)
  convert_pad<<<cdiv((size_t)4*512*512,256),256,0,stream>>>(Wq, wqkvb,            512,512,512,512,4, QSF, 0, 512, (size_t)QKVS*512);
  convert_pad<<<cdiv((size_t)4*512*512,256),256,0,stream>>>(Wk, wqkvb + 512*512,  512,512,512,512,4, 1.f, 0, 512, (size_t)QKVS*512);
  convert_pad<<<cdiv((size_t)4*512*512,256),256,0,stream>>>(Wv, wqkvb + 1024*512, 512,512,512,512,4, 1.f, 0, 512, (size_t)QKVS*512);
  convert_pad<<<cdiv((size_t)4*512*512,256),256,0,stream>>>(Wo, wob, 512,512,512,512,4, 1.f, 0, 512, (size_t)512*512);
  convert_pad<<<cdiv((size_t)4*HP*512,256),256,0,stream>>>(l0_w, wl0a, DHID,512,HP,512,4, 1.f, 0,    DHID2, (size_t)HP*512);
  convert_pad<<<cdiv((size_t)4*HP*512,256),256,0,stream>>>(l0_w, wl0b, DHID,512,HP,512,4, 1.f, DHID, DHID2, (size_t)HP*512);
  convert_pad<<<cdiv((size_t)4*512*HP,256),256,0,stream>>>(l1_w, l1wp, 512,DHID,512,HP,4, 1.f, 0, 512, (size_t)512*HP);
  build_bias<<<cdiv(4*QKVS,256),256,0,stream>>>(bq, bk, bv, l0_b, fqkvb, l0ba, l0bb);

  embed_kernel<<<cdiv((size_t)NROWS*128,256),256,0,stream>>>(x_num, cls_w, x, xb);

  const int nwQKV = 12*513, nwF = 6*513, nwKV = 8*513;
  const int nRL = NROWS/64;   // 1026
  for (int i = 0; i < 3; ++i) {
    gemm_bt<0><<<nwQKV,256,0,stream>>>(xb, wqkvb+(size_t)i*QKVS*512, fqkvb+(size_t)i*QKVS, qkv, nullptr, 512, QKVS, 12, nwQKV);
    attn_fused<<<5120,256,0,stream>>>(qkv, ob);
    // WO gemm + residual + LN(n1[i]) -> x, xb
    gemm_res_ln<1><<<nRL,256,0,stream>>>(ob, wob+(size_t)i*262144, bo+i*512, x,
                                         n1_g+(size_t)i*512, n1_b+(size_t)i*512, xb, 512);
    gemm_ffn<<<nwF,256,0,stream>>>(xb, wl0a+(size_t)i*HP*512, wl0b+(size_t)i*HP*512,
                                   l0ba+(size_t)i*HP, l0bb+(size_t)i*HP, hbuf, 512, HP, 6, nwF);
    // L1 gemm + residual + LN(n0[i]) -> x, xb  (consumed by layer i+1 / layer 3)
    // Last layer (i==2): x is only read again at CLS rows -> skip other x-writes.
    if (i < 2)
      gemm_res_ln<1><<<nRL,256,0,stream>>>(hbuf, l1wp+(size_t)i*512*HP, l1_b+i*512, x,
                                           n0_g+(size_t)i*512, n0_b+(size_t)i*512, xb, HP);
    else
      gemm_res_ln<0><<<nRL,256,0,stream>>>(hbuf, l1wp+(size_t)i*512*HP, l1_b+i*512, x,
                                           n0_g+(size_t)i*512, n0_b+(size_t)i*512, xb, HP);
  }

  // layer 3 (CLS query only) — xb already = LN_n0[2](x)
  gather_cls<<<128,64,0,stream>>>(xb, x, xq_cls, xcf);
  gemm_bt<0><<<4,256,0,stream>>>(xq_cls, wqkvb+(size_t)3*QKVS*512, fqkvb+(size_t)3*QKVS, qc, nullptr, 512, 512, 4, 4);
  gemm_bt<0><<<nwKV,256,0,stream>>>(xb, wqkvb+(size_t)3*QKVS*512 + 512*512, fqkvb+(size_t)3*QKVS + 512,
                                    qkv + 512, nullptr, 512, QKVS, 8, nwKV);
  attn_cls<<<1024,256,0,stream>>>(qc, 512, qkv, oc, 512);
  gemm_bt<1><<<4,256,0,stream>>>(oc, wob+(size_t)3*262144, bo+3*512, nullptr, xcf, 512, 512, 4, 4);
  ln_kernel<<<cdiv(128,4),256,0,stream>>>(xcf, n1_g+3*512, n1_b+3*512, xcb, 128);
  gemm_ffn<<<6,256,0,stream>>>(xcb, wl0a+(size_t)3*HP*512, wl0b+(size_t)3*HP*512,
                               l0ba+(size_t)3*HP, l0bb+(size_t)3*HP, hc, 512, HP, 6, 6);
  gemm_bt<1><<<4,256,0,stream>>>(hc, l1wp+(size_t)3*512*HP, l1_b+3*512, nullptr, xcf, HP, 512, 4, 4);
  head_kernel<<<128,64,0,stream>>>(xcf, ln_g, ln_b, head_w, head_b, out);
}

// Round 18
// 2359.124 us; speedup vs baseline: 1.0932x; 1.0072x over previous
//
#include <hip/hip_runtime.h>
#include <stdint.h>

typedef __attribute__((ext_vector_type(4))) float f32x4;
typedef __attribute__((ext_vector_type(8))) short short8;
typedef __attribute__((ext_vector_type(8))) _Float16 half8;

#define DMODEL 512
#define SEQ 513
#define BATCH 128
#define NROWS (BATCH*SEQ)   // 65664 = 513 * 128
#define DHID 682
#define DHID2 1364
#define HP 768
#define QKVS 1536
#define KVB 64
#define NKT8 8              // keys 0..511; key 512 folded into softmax init
#define QSF 0.1803368801111244f   // 0.125 * log2(e)

__device__ __forceinline__ float h2f(ushort u){ return (float)__builtin_bit_cast(_Float16, u); }
__device__ __forceinline__ ushort f2h(float f){ return __builtin_bit_cast(ushort, (_Float16)f); }
__device__ __forceinline__ uint pk2h(float a, float b){
  return __builtin_bit_cast(uint, __builtin_amdgcn_cvt_pkrtz(a, b));
}
__device__ __forceinline__ void gload16(const void* g, void* lds){
  __builtin_amdgcn_global_load_lds((const __attribute__((address_space(1))) void*)g,
                                   (__attribute__((address_space(3))) void*)lds, 16, 0, 0);
}
// bijective XCD-chunked flat-grid swizzle (m204)
__device__ __forceinline__ int xcd_wg(int orig, int nwg){
  const int q = nwg >> 3, r = nwg & 7;
  const int xcd = orig & 7, idx = orig >> 3;
  return (xcd < r) ? (xcd*(q+1) + idx) : (r*(q+1) + (xcd-r)*q + idx);
}

// ---------------------------------------------------------------------------
// GEMM: C[N x O] = A[N x K] @ W[O x K]^T (+bias). fp16 in, fp32 accum.
// 128x128 tile, BK=64, 4 waves, 32KB LDS, 3 blocks/CU, chunk-XOR swizzle.
// EPI=0: write fp16 Cb. EPI=1: Cf[idx] += acc + bias.
// ---------------------------------------------------------------------------
template<int EPI>
__global__ __launch_bounds__(256,3) void gemm_bt(
    const ushort* __restrict__ A, const ushort* __restrict__ W,
    const float* __restrict__ bias, ushort* __restrict__ Cb, float* __restrict__ Cf,
    int K, int ldc, int gx, int nwg)
{
  __shared__ char lds[32768];       // As @0, Ws @16384
  const int t = threadIdx.x, lane = t & 63, w = t >> 6;
  const int fr = lane & 15, g = lane >> 4;
  const int l7 = lane & 7, l8 = lane >> 3;
  const int wg = xcd_wg(blockIdx.x, nwg);
  const int row0 = (wg / gx) << 7;
  const int col0 = (wg % gx) << 7;
  const int wr = (w >> 1) << 6, wc = (w & 1) << 6;

  const int chunkoff = (l7 ^ l8) << 3;
  const ushort* Ag = A + (size_t)(row0 + w*8 + l8) * K + chunkoff;
  const ushort* Wg = W + (size_t)(col0 + w*8 + l8) * K + chunkoff;

  f32x4 acc[4][4] = {};

  for (int k0 = 0; k0 < K; k0 += 64) {
    __syncthreads();
#pragma unroll
    for (int p = 0; p < 4; ++p) {
      gload16(Ag + (size_t)(p*32)*K + k0, lds + p*4096 + w*1024);
      gload16(Wg + (size_t)(p*32)*K + k0, lds + 16384 + p*4096 + w*1024);
    }
    __syncthreads();
#pragma unroll
    for (int ks = 0; ks < 2; ++ks) {
      half8 af[4], wf[4];
#pragma unroll
      for (int m = 0; m < 4; ++m) {
        const int row = wr + m*16 + fr;
        af[m] = *(const half8*)(lds + row*128 + (((g + ks*4) ^ (fr & 7)) << 4));
      }
#pragma unroll
      for (int n = 0; n < 4; ++n) {
        const int row = wc + n*16 + fr;
        wf[n] = *(const half8*)(lds + 16384 + row*128 + (((g + ks*4) ^ (fr & 7)) << 4));
      }
#pragma unroll
      for (int m = 0; m < 4; ++m)
#pragma unroll
        for (int n = 0; n < 4; ++n)
          acc[m][n] = __builtin_amdgcn_mfma_f32_16x16x32_f16(af[m], wf[n], acc[m][n], 0, 0, 0);
    }
  }

  const int r0 = (lane >> 4) << 2;
#pragma unroll
  for (int m = 0; m < 4; ++m) {
    const int rg = row0 + wr + m*16 + r0;
#pragma unroll
    for (int n = 0; n < 4; ++n) {
      const int cg = col0 + wc + n*16 + fr;
      const float bi = bias[cg];
      if (EPI == 0) {
#pragma unroll
        for (int r = 0; r < 4; ++r)
          Cb[(size_t)(rg + r)*ldc + cg] = f2h(acc[m][n][r] + bi);
      } else {
#pragma unroll
        for (int r = 0; r < 4; ++r) {
          const size_t ix = (size_t)(rg + r)*ldc + cg;
          Cf[ix] += acc[m][n][r] + bi;
        }
      }
    }
  }
}

// ---------------------------------------------------------------------------
// Fused residual GEMM + LayerNorm, vectorized epilogue v4 (round-14 proven).
// XW=1: write full fp32 x. XW=0: write x only for CLS rows (row%513==0).
// ---------------------------------------------------------------------------
template<int XW>
__global__ __launch_bounds__(256,2) void gemm_res_ln(
    const ushort* __restrict__ A, const ushort* __restrict__ W,
    const float* __restrict__ bias, float* __restrict__ x,
    const float* __restrict__ gamma, const float* __restrict__ beta,
    ushort* __restrict__ xb, int K)
{
  __shared__ char lds[73728];        // K-loop: A [64][128B] @0, W [512][128B] @8192
                                     // epilogue: fb16 @0, redrow @66560, gb @67072
  const int t = threadIdx.x, lane = t & 63, w = t >> 6;
  const int fr = lane & 15, g = lane >> 4;
  const int l7 = lane & 7, l8 = lane >> 3;
  const int row0 = blockIdx.x << 6;

  const int chunkoff = (l7 ^ l8) << 3;
  const ushort* Ag = A + (size_t)(row0 + w*8 + l8) * K + chunkoff;
  const ushort* Wg = W + (size_t)(w*8 + l8) * K + chunkoff;

  f32x4 acc[4][8] = {};

  for (int k0 = 0; k0 < K; k0 += 64) {
    __syncthreads();
    gload16(Ag + k0,                 lds + w*1024);
    gload16(Ag + (size_t)32*K + k0,  lds + 4096 + w*1024);
#pragma unroll
    for (int p = 0; p < 16; ++p)
      gload16(Wg + (size_t)(p*32)*K + k0, lds + 8192 + p*4096 + w*1024);
    __syncthreads();
#pragma unroll
    for (int ks = 0; ks < 2; ++ks) {
      half8 af[4], wf[8];
#pragma unroll
      for (int m = 0; m < 4; ++m) {
        const int row = m*16 + fr;
        af[m] = *(const half8*)(lds + row*128 + (((g + ks*4) ^ (fr & 7)) << 4));
      }
#pragma unroll
      for (int n = 0; n < 8; ++n) {
        const int row = (w << 7) + n*16 + fr;
        wf[n] = *(const half8*)(lds + 8192 + row*128 + (((g + ks*4) ^ (fr & 7)) << 4));
      }
#pragma unroll
      for (int m = 0; m < 4; ++m)
#pragma unroll
        for (int n = 0; n < 8; ++n)
          acc[m][n] = __builtin_amdgcn_mfma_f32_16x16x32_f16(af[m], wf[n], acc[m][n], 0, 0, 0);
    }
  }

  // ---------------- epilogue v4 ----------------
  ushort* fb16   = (ushort*)lds;              // [64][520]
  float2* redrow = (float2*)(lds + 66560);    // [64]
  float*  gb     = (float*)(lds + 67072);     // gamma[512] | beta[512]

  __syncthreads();
#pragma unroll
  for (int n = 0; n < 8; ++n) {
    const int cg = (w << 7) + n*16 + fr;
    const float bi = bias[cg];
#pragma unroll
    for (int m = 0; m < 4; ++m)
#pragma unroll
      for (int r = 0; r < 4; ++r)
        fb16[(m*16 + g*4 + r)*520 + cg] = f2h(acc[m][n][r] + bi);
  }
  if (t < 128) *(f32x4*)&gb[t*4]            = *(const f32x4*)&gamma[t*4];
  else         *(f32x4*)&gb[512 + (t-128)*4] = *(const f32x4*)&beta[(t-128)*4];
  __syncthreads();

  const int q = t & 15;
  const int rbase = t >> 4;
#pragma unroll
  for (int rr = 0; rr < 4; ++rr) {
    const int row = rr*16 + rbase;
    const int grow = row0 + row;
    const bool wrx = XW || (grow % SEQ) == 0;
    const size_t xrow = (size_t)grow*DMODEL;
    float ps = 0.f, pss = 0.f;
#pragma unroll
    for (int j = 0; j < 8; ++j) {
      const int c = q*4 + j*64;
      const uint2 pk = *(const uint2*)&fb16[row*520 + c];
      f32x4 v;
      v[0] = h2f((ushort)(pk.x & 0xffffu)); v[1] = h2f((ushort)(pk.x >> 16));
      v[2] = h2f((ushort)(pk.y & 0xffffu)); v[3] = h2f((ushort)(pk.y >> 16));
      const f32x4 xo = *(const f32x4*)&x[xrow + c];
      v += xo;
      if (wrx) *(f32x4*)&x[xrow + c] = v;
      uint2 opk; opk.x = pk2h(v[0], v[1]); opk.y = pk2h(v[2], v[3]);
      *(uint2*)&fb16[row*520 + c] = opk;
      ps  += v[0]+v[1]+v[2]+v[3];
      pss += v[0]*v[0]+v[1]*v[1]+v[2]*v[2]+v[3]*v[3];
    }
#pragma unroll
    for (int mask = 1; mask <= 8; mask <<= 1) {
      ps  += __shfl_xor(ps,  mask);
      pss += __shfl_xor(pss, mask);
    }
    if (q == 0) redrow[row] = float2{ps, pss};
  }
  __syncthreads();
#pragma unroll
  for (int rr = 0; rr < 4; ++rr) {
    const int row = rr*16 + rbase;
    const float2 sr = redrow[row];
    const float mu = sr.x * (1.f/512.f);
    const float rstd = rsqrtf(sr.y*(1.f/512.f) - mu*mu + 1e-5f);
    const size_t xbrow = (size_t)(row0 + row)*DMODEL;
#pragma unroll
    for (int j = 0; j < 8; ++j) {
      const int c = q*4 + j*64;
      const uint2 pk = *(const uint2*)&fb16[row*520 + c];
      f32x4 v;
      v[0] = h2f((ushort)(pk.x & 0xffffu)); v[1] = h2f((ushort)(pk.x >> 16));
      v[2] = h2f((ushort)(pk.y & 0xffffu)); v[3] = h2f((ushort)(pk.y >> 16));
      const f32x4 ga = *(const f32x4*)&gb[c];
      const f32x4 be = *(const f32x4*)&gb[512 + c];
      f32x4 o_;
#pragma unroll
      for (int e = 0; e < 4; ++e) o_[e] = (v[e] - mu)*rstd*ga[e] + be[e];
      uint2 u; u.x = pk2h(o_[0], o_[1]); u.y = pk2h(o_[2], o_[3]);
      *(uint2*)&xb[xbrow + c] = u;
    }
  }
}

// ---------------------------------------------------------------------------
// Fused FFN-up + ReGLU: H[N x 768] = (A@Wa^T + ba) * relu(A@Wb^T + bb), fp16.
// BK=64 swizzled; 48KB LDS, 2 blocks/CU.
// ---------------------------------------------------------------------------
__global__ __launch_bounds__(256,2) void gemm_ffn(
    const ushort* __restrict__ A, const ushort* __restrict__ Wa, const ushort* __restrict__ Wb,
    const float* __restrict__ ba, const float* __restrict__ bb, ushort* __restrict__ H,
    int K, int ldc, int gx, int nwg)
{
  __shared__ char lds[49152];       // As @0, Was @16384, Wbs @32768
  const int t = threadIdx.x, lane = t & 63, w = t >> 6;
  const int fr = lane & 15, g = lane >> 4;
  const int l7 = lane & 7, l8 = lane >> 3;
  const int wg = xcd_wg(blockIdx.x, nwg);
  const int row0 = (wg / gx) << 7;
  const int col0 = (wg % gx) << 7;
  const int wr = (w >> 1) << 6, wc = (w & 1) << 6;

  const int chunkoff = (l7 ^ l8) << 3;
  const ushort* Ag  = A  + (size_t)(row0 + w*8 + l8) * K + chunkoff;
  const ushort* WaG = Wa + (size_t)(col0 + w*8 + l8) * K + chunkoff;
  const ushort* WbG = Wb + (size_t)(col0 + w*8 + l8) * K + chunkoff;

  f32x4 aa[4][4] = {}, ab[4][4] = {};

  for (int k0 = 0; k0 < K; k0 += 64) {
    __syncthreads();
#pragma unroll
    for (int p = 0; p < 4; ++p) {
      gload16(Ag  + (size_t)(p*32)*K + k0, lds + p*4096 + w*1024);
      gload16(WaG + (size_t)(p*32)*K + k0, lds + 16384 + p*4096 + w*1024);
      gload16(WbG + (size_t)(p*32)*K + k0, lds + 32768 + p*4096 + w*1024);
    }
    __syncthreads();
#pragma unroll
    for (int ks = 0; ks < 2; ++ks) {
      half8 af[4], wa[4], wb[4];
#pragma unroll
      for (int m = 0; m < 4; ++m) {
        const int row = wr + m*16 + fr;
        af[m] = *(const half8*)(lds + row*128 + (((g + ks*4) ^ (fr & 7)) << 4));
      }
#pragma unroll
      for (int n = 0; n < 4; ++n) {
        const int row = wc + n*16 + fr;
        const int off = row*128 + (((g + ks*4) ^ (fr & 7)) << 4);
        wa[n] = *(const half8*)(lds + 16384 + off);
        wb[n] = *(const half8*)(lds + 32768 + off);
      }
#pragma unroll
      for (int m = 0; m < 4; ++m)
#pragma unroll
        for (int n = 0; n < 4; ++n) {
          aa[m][n] = __builtin_amdgcn_mfma_f32_16x16x32_f16(af[m], wa[n], aa[m][n], 0, 0, 0);
          ab[m][n] = __builtin_amdgcn_mfma_f32_16x16x32_f16(af[m], wb[n], ab[m][n], 0, 0, 0);
        }
    }
  }

  const int r0 = (lane >> 4) << 2;
#pragma unroll
  for (int m = 0; m < 4; ++m) {
    const int rg = row0 + wr + m*16 + r0;
#pragma unroll
    for (int n = 0; n < 4; ++n) {
      const int cg = col0 + wc + n*16 + fr;
      const float bav = ba[cg], bbv = bb[cg];
#pragma unroll
      for (int r = 0; r < 4; ++r) {
        const float av = aa[m][n][r] + bav;
        const float bv = ab[m][n][r] + bbv;
        H[(size_t)(rg + r)*ldc + cg] = f2h(av * fmaxf(bv, 0.f));
      }
    }
  }
}

// ---------------------------------------------------------------------------
// Fused attention: 256 threads, 4 waves, 128 q-rows/block.
// blocks 0..4095 = flash path (8 unmasked K-tiles; key 512 folded into the
// online-softmax INIT state); blocks 4096..5119 = CLS-row path (q row 512).
// ---------------------------------------------------------------------------
__global__ __launch_bounds__(256,4) void attn_fused(
    const ushort* __restrict__ qkv, ushort* __restrict__ o)
{
  __shared__ char lds[40960];
  const int t = threadIdx.x;

  if (blockIdx.x >= 4096) {
    const int bh = blockIdx.x - 4096;
    const int b = bh >> 3, h = bh & 7;
    float* sc   = (float*)lds;
    float* qsh  = (float*)(lds + 2112);
    float* red  = (float*)(lds + 2368);
    float* osum = (float*)(lds + 2432);
    const ushort* k = qkv + 512;
    const ushort* v = qkv + 1024;
    const ushort* qb2 = qkv + (size_t)512*QKVS;
    if (t < 64) qsh[t] = h2f(qb2[(size_t)b*SEQ*QKVS + h*64 + t]);
    __syncthreads();
    for (int key = t; key < SEQ; key += 256) {
      const ushort* kr = k + ((size_t)b*SEQ + key)*QKVS + h*64;
      float s = 0.f;
#pragma unroll 8
      for (int d = 0; d < 64; ++d) s += qsh[d]*h2f(kr[d]);
      sc[key] = s;
    }
    __syncthreads();
    float lm = -1e30f;
    for (int key = t; key < SEQ; key += 256) lm = fmaxf(lm, sc[key]);
#pragma unroll
    for (int mask=1; mask<64; mask<<=1) lm = fmaxf(lm, __shfl_xor(lm, mask));
    if ((t&63)==0) red[t>>6] = lm;
    __syncthreads();
    const float mx = fmaxf(fmaxf(red[0],red[1]), fmaxf(red[2],red[3]));
    float ls = 0.f;
    for (int key = t; key < SEQ; key += 256){ float pp = exp2f(sc[key]-mx); sc[key]=pp; ls += pp; }
#pragma unroll
    for (int mask=1; mask<64; mask<<=1) ls += __shfl_xor(ls, mask);
    if ((t&63)==0) red[4 + (t>>6)] = ls;
    __syncthreads();
    const float ssum = red[4]+red[5]+red[6]+red[7];
    const int d = t & 63, kc = t >> 6;
    float op = 0.f;
    for (int key = kc; key < SEQ; key += 4)
      op += sc[key] * h2f(v[((size_t)b*SEQ + key)*QKVS + h*64 + d]);
    osum[t] = op;
    __syncthreads();
    if (t < 64) {
      const float oo = (osum[t]+osum[64+t]+osum[128+t]+osum[192+t]) / ssum;
      o[((size_t)b*SEQ + 512)*DMODEL + h*64 + t] = f2h(oo);
    }
    return;
  }

  const int bid = blockIdx.x;
  const int sw = (bid & 7)*512 + (bid >> 3);
  const int qt = sw & 3;
  const int hb = sw >> 2;
  const int h = hb & 7, b = hb >> 3;
  const int lane = t & 63, w = t >> 6;
  const int fr = lane & 15, g = lane >> 4, gq4 = g << 2;
  const size_t rowB = (size_t)b * SEQ;
  const ushort* q = qkv;
  const ushort* k = qkv + 512;
  const ushort* v = qkv + 1024;

  char* const Ks  = lds;
  char* const Vs  = lds + 8192;
  char* const VTs = lds + 16384;
  char* const pb  = lds + 24576 + w*4096;

  const int qr0 = qt*128 + w*32;

  half8 qf[2][2];
#pragma unroll
  for (int nq = 0; nq < 2; ++nq) {
    const int qrow = qr0 + nq*16 + fr;
#pragma unroll
    for (int kk = 0; kk < 2; ++kk)
      qf[nq][kk] = *(const half8*)&q[(rowB + qrow)*QKVS + h*64 + kk*32 + g*8];
  }

  // ---- softmax init with key 512 (weight 1 at its own max) ----
  f32x4 accO[2][4];
  float mrun[2], lrun[2];
  {
    const ushort* k512 = k + (rowB + 512)*QKVS + h*64;
    const ushort* v512 = v + (rowB + 512)*QKVS + h*64;
    half8 kf512[2];
#pragma unroll
    for (int kk = 0; kk < 2; ++kk)
      kf512[kk] = *(const half8*)&k512[kk*32 + g*8];
#pragma unroll
    for (int nq = 0; nq < 2; ++nq) {
      float s = 0.f;
#pragma unroll
      for (int kk = 0; kk < 2; ++kk)
#pragma unroll
        for (int j = 0; j < 8; ++j)
          s += (float)qf[nq][kk][j] * (float)kf512[kk][j];
      s += __shfl_xor(s, 16);
      s += __shfl_xor(s, 32);
      mrun[nq] = s;          // per-lane valid for q-row nq*16 + fr
      lrun[nq] = 1.f;
    }
    float v0[4];
#pragma unroll
    for (int dn = 0; dn < 4; ++dn) v0[dn] = h2f(v512[dn*16 + fr]);
#pragma unroll
    for (int mq = 0; mq < 2; ++mq)
#pragma unroll
      for (int dn = 0; dn < 4; ++dn)
#pragma unroll
        for (int r = 0; r < 4; ++r) accO[mq][dn][r] = v0[dn];
  }

  const int l8 = lane >> 3, l7 = lane & 7;
  const int chunk = l7 ^ l8;
  auto STAGE = [&](int kt2) {
#pragma unroll
    for (int i = 0; i < 2; ++i) {
      const int row = i*32 + (w<<3) + l8;
      const int keyg = kt2*KVB + row;           // always < 512 here
      const size_t gsrc = (rowB + keyg)*QKVS + h*64 + chunk*8;
      gload16(k + gsrc, Ks + i*4096 + w*1024);
      gload16(v + gsrc, Vs + i*4096 + w*1024);
    }
  };

  const int db  = (lane & 7) | ((w & 1) << 3);
  const int kbq = l8 | ((w & 2) << 2);
  const int d0 = db << 2, key0 = kbq << 2;

  STAGE(0);

  for (int kt = 0; kt < NKT8; ++kt) {
    __syncthreads();

    f32x4 sc4[4][2] = {};
    __builtin_amdgcn_s_setprio(1);
#pragma unroll
    for (int kk = 0; kk < 2; ++kk) {
      half8 kf[4];
#pragma unroll
      for (int mk = 0; mk < 4; ++mk) {
        const int row = mk*16 + fr;
        kf[mk] = *(const half8*)(Ks + row*128 + ((kk*64 + g*16) ^ ((fr&7)<<4)));
      }
#pragma unroll
      for (int mk = 0; mk < 4; ++mk)
#pragma unroll
        for (int nq = 0; nq < 2; ++nq)
          sc4[mk][nq] = __builtin_amdgcn_mfma_f32_16x16x32_f16(kf[mk], qf[nq][kk], sc4[mk][nq], 0, 0, 0);
    }
    __builtin_amdgcn_s_setprio(0);

    {
      uint2 a[4];
#pragma unroll
      for (int i = 0; i < 4; ++i) {
        const int row = key0 + i;
        a[i] = *(const uint2*)(Vs + row*128 + ((d0*2) ^ ((row&7)<<4)));
      }
      uint2 bb[4];
      bb[0].x = (a[0].x & 0xffffu) | (a[1].x << 16);
      bb[0].y = (a[2].x & 0xffffu) | (a[3].x << 16);
      bb[1].x = (a[0].x >> 16) | (a[1].x & 0xffff0000u);
      bb[1].y = (a[2].x >> 16) | (a[3].x & 0xffff0000u);
      bb[2].x = (a[0].y & 0xffffu) | (a[1].y << 16);
      bb[2].y = (a[2].y & 0xffffu) | (a[3].y << 16);
      bb[3].x = (a[0].y >> 16) | (a[1].y & 0xffff0000u);
      bb[3].y = (a[2].y >> 16) | (a[3].y & 0xffff0000u);
#pragma unroll
      for (int j = 0; j < 4; ++j) {
        const int drow = d0 + j;
        *(uint2*)(VTs + drow*128 + ((key0*2) ^ ((drow&7)<<4))) = bb[j];
      }
    }

    __syncthreads();

    if (kt+1 < NKT8) STAGE(kt+1);

    float al2[2];
    bool resc[2];
#pragma unroll
    for (int nq = 0; nq < 2; ++nq) {
      float tm = sc4[0][nq][0];
#pragma unroll
      for (int mk = 0; mk < 4; ++mk)
#pragma unroll
        for (int r = 0; r < 4; ++r) tm = fmaxf(tm, sc4[mk][nq][r]);
      tm = fmaxf(tm, __shfl_xor(tm, 16));
      tm = fmaxf(tm, __shfl_xor(tm, 32));
      float mref;
      if (__all(tm - mrun[nq] <= 8.f)) {
        mref = mrun[nq];
        al2[nq] = 1.f; resc[nq] = false;
      } else {
        const float mnew = fmaxf(mrun[nq], tm);
        al2[nq] = exp2f(mrun[nq] - mnew);
        mrun[nq] = mnew;
        mref = mnew;
        resc[nq] = true;
      }
      float rs = 0.f;
#pragma unroll
      for (int mk = 0; mk < 4; ++mk)
#pragma unroll
        for (int r = 0; r < 4; ++r) {
          const float pv = exp2f(sc4[mk][nq][r] - mref);
          sc4[mk][nq][r] = pv;
          rs += pv;
        }
      rs += __shfl_xor(rs, 16);
      rs += __shfl_xor(rs, 32);
      lrun[nq] = resc[nq] ? (lrun[nq]*al2[nq] + rs) : (lrun[nq] + rs);
      char* prow = pb + (nq*16 + fr)*128;
#pragma unroll
      for (int mk = 0; mk < 4; ++mk) {
        uint2 pk;
        pk.x = pk2h(sc4[mk][nq][0], sc4[mk][nq][1]);
        pk.y = pk2h(sc4[mk][nq][2], sc4[mk][nq][3]);
        *(uint2*)(prow + ((mk*32 + gq4*2) ^ ((fr&7)<<4))) = pk;
      }
    }

#pragma unroll
    for (int mq = 0; mq < 2; ++mq) {
      if (resc[mq]) {
#pragma unroll
        for (int r = 0; r < 4; ++r) {
          const float alr = __shfl(al2[mq], (lane & 48) | (gq4 + r));
#pragma unroll
          for (int dn = 0; dn < 4; ++dn) accO[mq][dn][r] *= alr;
        }
      }
    }

    asm volatile("" ::: "memory");

    __builtin_amdgcn_s_setprio(1);
#pragma unroll
    for (int kk2 = 0; kk2 < 2; ++kk2) {
      half8 pf[2];
#pragma unroll
      for (int mq = 0; mq < 2; ++mq)
        pf[mq] = *(const half8*)(pb + (mq*16 + fr)*128 + ((kk2*64 + g*16) ^ ((fr&7)<<4)));
      half8 vf[4];
#pragma unroll
      for (int dn = 0; dn < 4; ++dn) {
        const int row = dn*16 + fr;
        vf[dn] = *(const half8*)(VTs + row*128 + ((kk2*64 + g*16) ^ ((fr&7)<<4)));
      }
#pragma unroll
      for (int mq = 0; mq < 2; ++mq)
#pragma unroll
        for (int dn = 0; dn < 4; ++dn)
          accO[mq][dn] = __builtin_amdgcn_mfma_f32_16x16x32_f16(pf[mq], vf[dn], accO[mq][dn], 0, 0, 0);
    }
    __builtin_amdgcn_s_setprio(0);
  }

#pragma unroll
  for (int mq = 0; mq < 2; ++mq)
#pragma unroll
    for (int r = 0; r < 4; ++r) {
      const int qrow = qr0 + mq*16 + gq4 + r;
      const float ls = __shfl(lrun[mq], (lane & 48) | (gq4 + r));
      const float inv = 1.f / ls;
#pragma unroll
      for (int dn = 0; dn < 4; ++dn)
        o[(rowB + qrow)*DMODEL + h*64 + dn*16 + fr] = f2h(accO[mq][dn][r] * inv);
    }
}

// ---------------------------------------------------------------------------
// Standalone single-q attention (layer-3 decode; q/out stride 512).
// ---------------------------------------------------------------------------
__global__ __launch_bounds__(256) void attn_cls(
    const ushort* __restrict__ qbase, size_t qstride,
    const ushort* __restrict__ qkv,
    ushort* __restrict__ obase, size_t ostride)
{
  const int bh = blockIdx.x;
  const int b = bh >> 3, h = bh & 7;
  const int t = threadIdx.x;
  __shared__ float sc[SEQ];
  __shared__ float qsh[64];
  __shared__ float red[8];
  __shared__ float osum[256];
  const ushort* k = qkv + 512;
  const ushort* v = qkv + 1024;
  if (t < 64) qsh[t] = h2f(qbase[(size_t)b*qstride + h*64 + t]);
  __syncthreads();
  for (int key = t; key < SEQ; key += 256) {
    const ushort* kr = k + ((size_t)b*SEQ + key)*QKVS + h*64;
    float s = 0.f;
#pragma unroll 8
    for (int d = 0; d < 64; ++d) s += qsh[d]*h2f(kr[d]);
    sc[key] = s;
  }
  __syncthreads();
  float lm = -1e30f;
  for (int key = t; key < SEQ; key += 256) lm = fmaxf(lm, sc[key]);
#pragma unroll
  for (int mask=1; mask<64; mask<<=1) lm = fmaxf(lm, __shfl_xor(lm, mask));
  if ((t&63)==0) red[t>>6] = lm;
  __syncthreads();
  const float mx = fmaxf(fmaxf(red[0],red[1]), fmaxf(red[2],red[3]));
  float ls = 0.f;
  for (int key = t; key < SEQ; key += 256){ float pp = exp2f(sc[key]-mx); sc[key]=pp; ls += pp; }
#pragma unroll
  for (int mask=1; mask<64; mask<<=1) ls += __shfl_xor(ls, mask);
  if ((t&63)==0) red[4 + (t>>6)] = ls;
  __syncthreads();
  const float ssum = red[4]+red[5]+red[6]+red[7];
  const int d = t & 63, kc = t >> 6;
  float op = 0.f;
  for (int key = kc; key < SEQ; key += 4)
    op += sc[key] * h2f(v[((size_t)b*SEQ + key)*QKVS + h*64 + d]);
  osum[t] = op;
  __syncthreads();
  if (t < 64) {
    const float oo = (osum[t]+osum[64+t]+osum[128+t]+osum[192+t]) / ssum;
    obase[(size_t)b*ostride + h*64 + t] = f2h(oo);
  }
}

// ---------------------------------------------------------------------------
__global__ __launch_bounds__(256) void ln_kernel(
    const float* __restrict__ x, const float* __restrict__ gamma, const float* __restrict__ beta,
    ushort* __restrict__ out, int nrows)
{
  const int row = blockIdx.x*4 + (threadIdx.x >> 6);
  const int lane = threadIdx.x & 63;
  if (row >= nrows) return;
  const float* xr = x + (size_t)row*DMODEL;
  float4 a = *(const float4*)(xr + lane*8);
  float4 b = *(const float4*)(xr + lane*8 + 4);
  float s  = a.x+a.y+a.z+a.w+b.x+b.y+b.z+b.w;
  float ss = a.x*a.x+a.y*a.y+a.z*a.z+a.w*a.w+b.x*b.x+b.y*b.y+b.z*b.z+b.w*b.w;
#pragma unroll
  for (int mask=1; mask<64; mask<<=1){ s += __shfl_xor(s,mask); ss += __shfl_xor(ss,mask); }
  const float mu = s*(1.f/512.f);
  const float rstd = rsqrtf(ss*(1.f/512.f) - mu*mu + 1e-5f);
  float vals[8] = {a.x,a.y,a.z,a.w,b.x,b.y,b.z,b.w};
  short8 pk;
#pragma unroll
  for (int j=0;j<8;++j){
    const int c = lane*8 + j;
    pk[j] = (short)f2h((vals[j]-mu)*rstd*gamma[c] + beta[c]);
  }
  *(short8*)(out + (size_t)row*DMODEL + lane*8) = pk;
}

// ---------------------------------------------------------------------------
__global__ void embed_kernel(const float* __restrict__ x_num, const float* __restrict__ cls_w,
                             float* __restrict__ x, ushort* __restrict__ xb)
{
  const size_t i = (size_t)blockIdx.x*256 + threadIdx.x;
  if (i >= (size_t)NROWS*128) return;
  const int row = (int)(i >> 7);
  const int c4 = ((int)(i & 127)) << 2;
  const int b = row / SEQ;
  const int s = row - b*SEQ;
  float4 val;
  if (s == 0) val = *(const float4*)(cls_w + c4);
  else        val = *(const float4*)(x_num + ((size_t)b*512 + (s-1))*512 + c4);
  *(float4*)(x + (size_t)row*DMODEL + c4) = val;
  ushort4 pk;
  pk.x = f2h(val.x); pk.y = f2h(val.y); pk.z = f2h(val.z); pk.w = f2h(val.w);
  *(ushort4*)(xb + (size_t)row*DMODEL + c4) = pk;
}

// ---------------------------------------------------------------------------
__global__ void convert_pad(const float* __restrict__ in, ushort* __restrict__ out,
                            int R, int C, int RP, int CP, int layers, float scale,
                            int r0, int srcRL, size_t ostride)
{
  const size_t i = (size_t)blockIdx.x*256 + threadIdx.x;
  const size_t per = (size_t)RP*CP;
  if (i >= per*layers) return;
  const int l = (int)(i / per);
  const int rem = (int)(i - (size_t)l*per);
  const int r = rem / CP;
  const int c = rem - r*CP;
  ushort val = 0;
  if (r < R && c < C) val = f2h(in[((size_t)l*srcRL + r0 + r)*C + c] * scale);
  out[(size_t)l*ostride + (size_t)r*CP + c] = val;
}

__global__ void build_bias(const float* __restrict__ bq, const float* __restrict__ bk,
                           const float* __restrict__ bv, const float* __restrict__ l0b,
                           float* __restrict__ fqkv, float* __restrict__ fa, float* __restrict__ fb)
{
  const int i = blockIdx.x*256 + threadIdx.x;
  if (i < 4*1536) {
    const int l = i / 1536, j = i - l*1536;
    float val;
    if (j < 512)       val = bq[l*512 + j] * QSF;
    else if (j < 1024) val = bk[l*512 + j - 512];
    else               val = bv[l*512 + j - 1024];
    fqkv[i] = val;
  }
  if (i < 4*HP) {
    const int l = i / HP, j = i - l*HP;
    fa[i] = (j < DHID) ? l0b[l*DHID2 + j] : 0.f;
    fb[i] = (j < DHID) ? l0b[l*DHID2 + DHID + j] : 0.f;
  }
}

__global__ void gather_cls(const ushort* __restrict__ xb, const float* __restrict__ x,
                           ushort* __restrict__ xq, float* __restrict__ xc)
{
  const int b = blockIdx.x, lane = threadIdx.x;
  const size_t src = (size_t)b*SEQ*DMODEL;
  *(short8*)(xq + b*DMODEL + lane*8) = *(const short8*)(xb + src + lane*8);
  *(float4*)(xc + b*DMODEL + lane*8)     = *(const float4*)(x + src + lane*8);
  *(float4*)(xc + b*DMODEL + lane*8 + 4) = *(const float4*)(x + src + lane*8 + 4);
}

__global__ void head_kernel(const float* __restrict__ xc, const float* __restrict__ g,
                            const float* __restrict__ be, const float* __restrict__ hw,
                            const float* __restrict__ hb, float* __restrict__ out)
{
  const int row = blockIdx.x;
  const int lane = threadIdx.x;
  const float* xr = xc + (size_t)row*DMODEL;
  float4 a = *(const float4*)(xr + lane*8);
  float4 b = *(const float4*)(xr + lane*8 + 4);
  float s  = a.x+a.y+a.z+a.w+b.x+b.y+b.z+b.w;
  float ss = a.x*a.x+a.y*a.y+a.z*a.z+a.w*a.w+b.x*b.x+b.y*b.y+b.z*b.z+b.w*b.w;
#pragma unroll
  for (int mask=1; mask<64; mask<<=1){ s += __shfl_xor(s,mask); ss += __shfl_xor(ss,mask); }
  const float mu = s*(1.f/512.f);
  const float rstd = rsqrtf(ss*(1.f/512.f) - mu*mu + 1e-5f);
  float vals[8] = {a.x,a.y,a.z,a.w,b.x,b.y,b.z,b.w};
  float acc = 0.f;
#pragma unroll
  for (int j=0;j<8;++j){
    const int c = lane*8 + j;
    float tv = (vals[j]-mu)*rstd*g[c] + be[c];
    acc += fmaxf(tv, 0.f) * hw[c];
  }
#pragma unroll
  for (int mask=1; mask<64; mask<<=1) acc += __shfl_xor(acc, mask);
  if (lane==0) out[row] = acc + hb[0];
}

// ---------------------------------------------------------------------------
extern "C" void kernel_launch(void* const* d_in, const int* in_sizes, int n_in,
                              void* d_out, int out_size, void* d_ws, size_t ws_size,
                              hipStream_t stream)
{
  const float* x_num = (const float*)d_in[0];
  const float* cls_w = (const float*)d_in[1];
  const float* Wq = (const float*)d_in[2];
  const float* bq = (const float*)d_in[3];
  const float* Wk = (const float*)d_in[4];
  const float* bk = (const float*)d_in[5];
  const float* Wv = (const float*)d_in[6];
  const float* bv = (const float*)d_in[7];
  const float* Wo = (const float*)d_in[8];
  const float* bo = (const float*)d_in[9];
  const float* l0_w = (const float*)d_in[10];
  const float* l0_b = (const float*)d_in[11];
  const float* l1_w = (const float*)d_in[12];
  const float* l1_b = (const float*)d_in[13];
  const float* n0_g = (const float*)d_in[14];
  const float* n0_b = (const float*)d_in[15];
  const float* n1_g = (const float*)d_in[16];
  const float* n1_b = (const float*)d_in[17];
  const float* ln_g = (const float*)d_in[18];
  const float* ln_b = (const float*)d_in[19];
  const float* head_w = (const float*)d_in[20];
  const float* head_b = (const float*)d_in[21];
  float* out = (float*)d_out;

  char* p = (char*)d_ws;
  auto alloc = [&](size_t bytes){ char* r = p; p += (bytes + 255) & ~(size_t)255; return r; };

  float* x  = (float*)alloc((size_t)NROWS*DMODEL*4);          // residual fp32
  char* U   = alloc((size_t)NROWS*DMODEL*2);                  // xb / attn-out
  ushort* xb = (ushort*)U;
  ushort* ob = (ushort*)U;
  char* QKVG = alloc((size_t)NROWS*QKVS*2);                   // qkv; also h [NROWS][768]
  ushort* qkv = (ushort*)QKVG;
  ushort* hbuf = (ushort*)QKVG;
  ushort* wqkvb = (ushort*)alloc((size_t)4*QKVS*512*2);
  ushort* wob  = (ushort*)alloc((size_t)4*512*512*2);
  ushort* wl0a = (ushort*)alloc((size_t)4*HP*512*2);
  ushort* wl0b = (ushort*)alloc((size_t)4*HP*512*2);
  ushort* l1wp = (ushort*)alloc((size_t)4*512*HP*2);
  float*  fqkvb = (float*)alloc((size_t)4*QKVS*4);
  float*  l0ba = (float*)alloc((size_t)4*HP*4);
  float*  l0bb = (float*)alloc((size_t)4*HP*4);
  ushort* xq_cls = (ushort*)alloc(128*512*2);
  float*  xcf = (float*)alloc(128*512*4);
  ushort* qc = (ushort*)alloc(128*512*2);
  ushort* oc = (ushort*)alloc(128*512*2);
  ushort* hc = (ushort*)alloc((size_t)128*HP*2);
  ushort* xcb = (ushort*)alloc(128*512*2);

  auto cdiv = [](size_t a, size_t b){ return (unsigned)((a + b - 1)/b); };

  // weight conversion: fused QKV [1536x512] per layer (q-part scaled by QSF)
  convert_pad<<<cdiv((size_t)4*512*512,256),256,0,stream>>>(Wq, wqkvb,            512,512,512,512,4, QSF, 0, 512, (size_t)QKVS*512);
  convert_pad<<<cdiv((size_t)4*512*512,256),256,0,stream>>>(Wk, wqkvb + 512*512,  512,512,512,512,4, 1.f, 0, 512, (size_t)QKVS*512);
  convert_pad<<<cdiv((size_t)4*512*512,256),256,0,stream>>>(Wv, wqkvb + 1024*512, 512,512,512,512,4, 1.f, 0, 512, (size_t)QKVS*512);
  convert_pad<<<cdiv((size_t)4*512*512,256),256,0,stream>>>(Wo, wob, 512,512,512,512,4, 1.f, 0, 512, (size_t)512*512);
  convert_pad<<<cdiv((size_t)4*HP*512,256),256,0,stream>>>(l0_w, wl0a, DHID,512,HP,512,4, 1.f, 0,    DHID2, (size_t)HP*512);
  convert_pad<<<cdiv((size_t)4*HP*512,256),256,0,stream>>>(l0_w, wl0b, DHID,512,HP,512,4, 1.f, DHID, DHID2, (size_t)HP*512);
  convert_pad<<<cdiv((size_t)4*512*HP,256),256,0,stream>>>(l1_w, l1wp, 512,DHID,512,HP,4, 1.f, 0, 512, (size_t)512*HP);
  build_bias<<<cdiv(4*QKVS,256),256,0,stream>>>(bq, bk, bv, l0_b, fqkvb, l0ba, l0bb);

  embed_kernel<<<cdiv((size_t)NROWS*128,256),256,0,stream>>>(x_num, cls_w, x, xb);

  const int nwQKV = 12*513, nwF = 6*513, nwKV = 8*513;
  const int nRL = NROWS/64;   // 1026
  for (int i = 0; i < 3; ++i) {
    gemm_bt<0><<<nwQKV,256,0,stream>>>(xb, wqkvb+(size_t)i*QKVS*512, fqkvb+(size_t)i*QKVS, qkv, nullptr, 512, QKVS, 12, nwQKV);
    attn_fused<<<5120,256,0,stream>>>(qkv, ob);
    // WO gemm + residual + LN(n1[i]) -> x, xb
    gemm_res_ln<1><<<nRL,256,0,stream>>>(ob, wob+(size_t)i*262144, bo+i*512, x,
                                         n1_g+(size_t)i*512, n1_b+(size_t)i*512, xb, 512);
    gemm_ffn<<<nwF,256,0,stream>>>(xb, wl0a+(size_t)i*HP*512, wl0b+(size_t)i*HP*512,
                                   l0ba+(size_t)i*HP, l0bb+(size_t)i*HP, hbuf, 512, HP, 6, nwF);
    // L1 gemm + residual + LN(n0[i]) -> x, xb  (consumed by layer i+1 / layer 3)
    if (i < 2)
      gemm_res_ln<1><<<nRL,256,0,stream>>>(hbuf, l1wp+(size_t)i*512*HP, l1_b+i*512, x,
                                           n0_g+(size_t)i*512, n0_b+(size_t)i*512, xb, HP);
    else
      gemm_res_ln<0><<<nRL,256,0,stream>>>(hbuf, l1wp+(size_t)i*512*HP, l1_b+i*512, x,
                                           n0_g+(size_t)i*512, n0_b+(size_t)i*512, xb, HP);
  }

  // layer 3 (CLS query only) — xb already = LN_n0[2](x)
  gather_cls<<<128,64,0,stream>>>(xb, x, xq_cls, xcf);
  gemm_bt<0><<<4,256,0,stream>>>(xq_cls, wqkvb+(size_t)3*QKVS*512, fqkvb+(size_t)3*QKVS, qc, nullptr, 512, 512, 4, 4);
  gemm_bt<0><<<nwKV,256,0,stream>>>(xb, wqkvb+(size_t)3*QKVS*512 + 512*512, fqkvb+(size_t)3*QKVS + 512,
                                    qkv + 512, nullptr, 512, QKVS, 8, nwKV);
  attn_cls<<<1024,256,0,stream>>>(qc, 512, qkv, oc, 512);
  gemm_bt<1><<<4,256,0,stream>>>(oc, wob+(size_t)3*262144, bo+3*512, nullptr, xcf, 512, 512, 4, 4);
  ln_kernel<<<cdiv(128,4),256,0,stream>>>(xcf, n1_g+3*512, n1_b+3*512, xcb, 128);
  gemm_ffn<<<6,256,0,stream>>>(xcb, wl0a+(size_t)3*HP*512, wl0b+(size_t)3*HP*512,
                               l0ba+(size_t)3*HP, l0bb+(size_t)3*HP, hc, 512, HP, 6, 6);
  gemm_bt<1><<<4,256,0,stream>>>(hc, l1wp+(size_t)3*512*HP, l1_b+3*512, nullptr, xcf, HP, 512, 4, 4);
  head_kernel<<<128,64,0,stream>>>(xcf, ln_g, ln_b, head_w, head_b, out);
}

// Round 19
// 2336.811 us; speedup vs baseline: 1.1036x; 1.0095x over previous
//
#include <hip/hip_runtime.h>
#include <stdint.h>

typedef __attribute__((ext_vector_type(4))) float f32x4;
typedef __attribute__((ext_vector_type(8))) short short8;
typedef __attribute__((ext_vector_type(8))) _Float16 half8;

#define DMODEL 512
#define SEQ 513
#define BATCH 128
#define NROWS (BATCH*SEQ)   // 65664 = 513 * 128
#define DHID 682
#define DHID2 1364
#define HP 768
#define QKVS 1536
#define KVB 64
#define NKT8 8              // keys 0..511; key 512 folded into softmax init
#define QSF 0.1803368801111244f   // 0.125 * log2(e)

__device__ __forceinline__ float h2f(ushort u){ return (float)__builtin_bit_cast(_Float16, u); }
__device__ __forceinline__ ushort f2h(float f){ return __builtin_bit_cast(ushort, (_Float16)f); }
__device__ __forceinline__ uint pk2h(float a, float b){
  return __builtin_bit_cast(uint, __builtin_amdgcn_cvt_pkrtz(a, b));
}
__device__ __forceinline__ void gload16(const void* g, void* lds){
  __builtin_amdgcn_global_load_lds((const __attribute__((address_space(1))) void*)g,
                                   (__attribute__((address_space(3))) void*)lds, 16, 0, 0);
}
// bijective XCD-chunked flat-grid swizzle (m204)
__device__ __forceinline__ int xcd_wg(int orig, int nwg){
  const int q = nwg >> 3, r = nwg & 7;
  const int xcd = orig & 7, idx = orig >> 3;
  return (xcd < r) ? (xcd*(q+1) + idx) : (r*(q+1) + (xcd-r)*q + idx);
}

// ---------------------------------------------------------------------------
// GEMM: C[N x O] = A[N x K] @ W[O x K]^T (+bias). fp16 in, fp32 accum.
// 128x128 tile, BK=64, 4 waves, 32KB LDS, 3 blocks/CU, chunk-XOR swizzle.
// EPI=0: write fp16 Cb. EPI=1: Cf[idx] += acc + bias.
// ---------------------------------------------------------------------------
template<int EPI>
__global__ __launch_bounds__(256,3) void gemm_bt(
    const ushort* __restrict__ A, const ushort* __restrict__ W,
    const float* __restrict__ bias, ushort* __restrict__ Cb, float* __restrict__ Cf,
    int K, int ldc, int gx, int nwg)
{
  __shared__ char lds[32768];       // As @0, Ws @16384
  const int t = threadIdx.x, lane = t & 63, w = t >> 6;
  const int fr = lane & 15, g = lane >> 4;
  const int l7 = lane & 7, l8 = lane >> 3;
  const int wg = xcd_wg(blockIdx.x, nwg);
  const int row0 = (wg / gx) << 7;
  const int col0 = (wg % gx) << 7;
  const int wr = (w >> 1) << 6, wc = (w & 1) << 6;

  const int chunkoff = (l7 ^ l8) << 3;
  const ushort* Ag = A + (size_t)(row0 + w*8 + l8) * K + chunkoff;
  const ushort* Wg = W + (size_t)(col0 + w*8 + l8) * K + chunkoff;

  f32x4 acc[4][4] = {};

  for (int k0 = 0; k0 < K; k0 += 64) {
    __syncthreads();
#pragma unroll
    for (int p = 0; p < 4; ++p) {
      gload16(Ag + (size_t)(p*32)*K + k0, lds + p*4096 + w*1024);
      gload16(Wg + (size_t)(p*32)*K + k0, lds + 16384 + p*4096 + w*1024);
    }
    __syncthreads();
#pragma unroll
    for (int ks = 0; ks < 2; ++ks) {
      half8 af[4], wf[4];
#pragma unroll
      for (int m = 0; m < 4; ++m) {
        const int row = wr + m*16 + fr;
        af[m] = *(const half8*)(lds + row*128 + (((g + ks*4) ^ (fr & 7)) << 4));
      }
#pragma unroll
      for (int n = 0; n < 4; ++n) {
        const int row = wc + n*16 + fr;
        wf[n] = *(const half8*)(lds + 16384 + row*128 + (((g + ks*4) ^ (fr & 7)) << 4));
      }
#pragma unroll
      for (int m = 0; m < 4; ++m)
#pragma unroll
        for (int n = 0; n < 4; ++n)
          acc[m][n] = __builtin_amdgcn_mfma_f32_16x16x32_f16(af[m], wf[n], acc[m][n], 0, 0, 0);
    }
  }

  const int r0 = (lane >> 4) << 2;
#pragma unroll
  for (int m = 0; m < 4; ++m) {
    const int rg = row0 + wr + m*16 + r0;
#pragma unroll
    for (int n = 0; n < 4; ++n) {
      const int cg = col0 + wc + n*16 + fr;
      const float bi = bias[cg];
      if (EPI == 0) {
#pragma unroll
        for (int r = 0; r < 4; ++r)
          Cb[(size_t)(rg + r)*ldc + cg] = f2h(acc[m][n][r] + bi);
      } else {
#pragma unroll
        for (int r = 0; r < 4; ++r) {
          const size_t ix = (size_t)(rg + r)*ldc + cg;
          Cf[ix] += acc[m][n][r] + bi;
        }
      }
    }
  }
}

// ---------------------------------------------------------------------------
// Fused residual GEMM + LayerNorm, vectorized epilogue v4 (round-14 proven).
// XW=1: write full fp32 x. XW=0: write x only for CLS rows (row%513==0).
// ---------------------------------------------------------------------------
template<int XW>
__global__ __launch_bounds__(256,2) void gemm_res_ln(
    const ushort* __restrict__ A, const ushort* __restrict__ W,
    const float* __restrict__ bias, float* __restrict__ x,
    const float* __restrict__ gamma, const float* __restrict__ beta,
    ushort* __restrict__ xb, int K)
{
  __shared__ char lds[73728];        // K-loop: A [64][128B] @0, W [512][128B] @8192
                                     // epilogue: fb16 @0, redrow @66560, gb @67072
  const int t = threadIdx.x, lane = t & 63, w = t >> 6;
  const int fr = lane & 15, g = lane >> 4;
  const int l7 = lane & 7, l8 = lane >> 3;
  const int row0 = blockIdx.x << 6;

  const int chunkoff = (l7 ^ l8) << 3;
  const ushort* Ag = A + (size_t)(row0 + w*8 + l8) * K + chunkoff;
  const ushort* Wg = W + (size_t)(w*8 + l8) * K + chunkoff;

  f32x4 acc[4][8] = {};

  for (int k0 = 0; k0 < K; k0 += 64) {
    __syncthreads();
    gload16(Ag + k0,                 lds + w*1024);
    gload16(Ag + (size_t)32*K + k0,  lds + 4096 + w*1024);
#pragma unroll
    for (int p = 0; p < 16; ++p)
      gload16(Wg + (size_t)(p*32)*K + k0, lds + 8192 + p*4096 + w*1024);
    __syncthreads();
#pragma unroll
    for (int ks = 0; ks < 2; ++ks) {
      half8 af[4], wf[8];
#pragma unroll
      for (int m = 0; m < 4; ++m) {
        const int row = m*16 + fr;
        af[m] = *(const half8*)(lds + row*128 + (((g + ks*4) ^ (fr & 7)) << 4));
      }
#pragma unroll
      for (int n = 0; n < 8; ++n) {
        const int row = (w << 7) + n*16 + fr;
        wf[n] = *(const half8*)(lds + 8192 + row*128 + (((g + ks*4) ^ (fr & 7)) << 4));
      }
#pragma unroll
      for (int m = 0; m < 4; ++m)
#pragma unroll
        for (int n = 0; n < 8; ++n)
          acc[m][n] = __builtin_amdgcn_mfma_f32_16x16x32_f16(af[m], wf[n], acc[m][n], 0, 0, 0);
    }
  }

  // ---------------- epilogue v4 ----------------
  ushort* fb16   = (ushort*)lds;              // [64][520]
  float2* redrow = (float2*)(lds + 66560);    // [64]
  float*  gb     = (float*)(lds + 67072);     // gamma[512] | beta[512]

  __syncthreads();
#pragma unroll
  for (int n = 0; n < 8; ++n) {
    const int cg = (w << 7) + n*16 + fr;
    const float bi = bias[cg];
#pragma unroll
    for (int m = 0; m < 4; ++m)
#pragma unroll
      for (int r = 0; r < 4; ++r)
        fb16[(m*16 + g*4 + r)*520 + cg] = f2h(acc[m][n][r] + bi);
  }
  if (t < 128) *(f32x4*)&gb[t*4]            = *(const f32x4*)&gamma[t*4];
  else         *(f32x4*)&gb[512 + (t-128)*4] = *(const f32x4*)&beta[(t-128)*4];
  __syncthreads();

  const int q = t & 15;
  const int rbase = t >> 4;
#pragma unroll
  for (int rr = 0; rr < 4; ++rr) {
    const int row = rr*16 + rbase;
    const int grow = row0 + row;
    const bool wrx = XW || (grow % SEQ) == 0;
    const size_t xrow = (size_t)grow*DMODEL;
    float ps = 0.f, pss = 0.f;
#pragma unroll
    for (int j = 0; j < 8; ++j) {
      const int c = q*4 + j*64;
      const uint2 pk = *(const uint2*)&fb16[row*520 + c];
      f32x4 v;
      v[0] = h2f((ushort)(pk.x & 0xffffu)); v[1] = h2f((ushort)(pk.x >> 16));
      v[2] = h2f((ushort)(pk.y & 0xffffu)); v[3] = h2f((ushort)(pk.y >> 16));
      const f32x4 xo = *(const f32x4*)&x[xrow + c];
      v += xo;
      if (wrx) *(f32x4*)&x[xrow + c] = v;
      uint2 opk; opk.x = pk2h(v[0], v[1]); opk.y = pk2h(v[2], v[3]);
      *(uint2*)&fb16[row*520 + c] = opk;
      ps  += v[0]+v[1]+v[2]+v[3];
      pss += v[0]*v[0]+v[1]*v[1]+v[2]*v[2]+v[3]*v[3];
    }
#pragma unroll
    for (int mask = 1; mask <= 8; mask <<= 1) {
      ps  += __shfl_xor(ps,  mask);
      pss += __shfl_xor(pss, mask);
    }
    if (q == 0) redrow[row] = float2{ps, pss};
  }
  __syncthreads();
#pragma unroll
  for (int rr = 0; rr < 4; ++rr) {
    const int row = rr*16 + rbase;
    const float2 sr = redrow[row];
    const float mu = sr.x * (1.f/512.f);
    const float rstd = rsqrtf(sr.y*(1.f/512.f) - mu*mu + 1e-5f);
    const size_t xbrow = (size_t)(row0 + row)*DMODEL;
#pragma unroll
    for (int j = 0; j < 8; ++j) {
      const int c = q*4 + j*64;
      const uint2 pk = *(const uint2*)&fb16[row*520 + c];
      f32x4 v;
      v[0] = h2f((ushort)(pk.x & 0xffffu)); v[1] = h2f((ushort)(pk.x >> 16));
      v[2] = h2f((ushort)(pk.y & 0xffffu)); v[3] = h2f((ushort)(pk.y >> 16));
      const f32x4 ga = *(const f32x4*)&gb[c];
      const f32x4 be = *(const f32x4*)&gb[512 + c];
      f32x4 o_;
#pragma unroll
      for (int e = 0; e < 4; ++e) o_[e] = (v[e] - mu)*rstd*ga[e] + be[e];
      uint2 u; u.x = pk2h(o_[0], o_[1]); u.y = pk2h(o_[2], o_[3]);
      *(uint2*)&xb[xbrow + c] = u;
    }
  }
}

// ---------------------------------------------------------------------------
// Fused FFN-up + ReGLU: H[N x 768] = (A@Wa^T + ba) * relu(A@Wb^T + bb), fp16.
// BK=64 swizzled; 48KB LDS, 2 blocks/CU.
// ---------------------------------------------------------------------------
__global__ __launch_bounds__(256,2) void gemm_ffn(
    const ushort* __restrict__ A, const ushort* __restrict__ Wa, const ushort* __restrict__ Wb,
    const float* __restrict__ ba, const float* __restrict__ bb, ushort* __restrict__ H,
    int K, int ldc, int gx, int nwg)
{
  __shared__ char lds[49152];       // As @0, Was @16384, Wbs @32768
  const int t = threadIdx.x, lane = t & 63, w = t >> 6;
  const int fr = lane & 15, g = lane >> 4;
  const int l7 = lane & 7, l8 = lane >> 3;
  const int wg = xcd_wg(blockIdx.x, nwg);
  const int row0 = (wg / gx) << 7;
  const int col0 = (wg % gx) << 7;
  const int wr = (w >> 1) << 6, wc = (w & 1) << 6;

  const int chunkoff = (l7 ^ l8) << 3;
  const ushort* Ag  = A  + (size_t)(row0 + w*8 + l8) * K + chunkoff;
  const ushort* WaG = Wa + (size_t)(col0 + w*8 + l8) * K + chunkoff;
  const ushort* WbG = Wb + (size_t)(col0 + w*8 + l8) * K + chunkoff;

  f32x4 aa[4][4] = {}, ab[4][4] = {};

  for (int k0 = 0; k0 < K; k0 += 64) {
    __syncthreads();
#pragma unroll
    for (int p = 0; p < 4; ++p) {
      gload16(Ag  + (size_t)(p*32)*K + k0, lds + p*4096 + w*1024);
      gload16(WaG + (size_t)(p*32)*K + k0, lds + 16384 + p*4096 + w*1024);
      gload16(WbG + (size_t)(p*32)*K + k0, lds + 32768 + p*4096 + w*1024);
    }
    __syncthreads();
#pragma unroll
    for (int ks = 0; ks < 2; ++ks) {
      half8 af[4], wa[4], wb[4];
#pragma unroll
      for (int m = 0; m < 4; ++m) {
        const int row = wr + m*16 + fr;
        af[m] = *(const half8*)(lds + row*128 + (((g + ks*4) ^ (fr & 7)) << 4));
      }
#pragma unroll
      for (int n = 0; n < 4; ++n) {
        const int row = wc + n*16 + fr;
        const int off = row*128 + (((g + ks*4) ^ (fr & 7)) << 4);
        wa[n] = *(const half8*)(lds + 16384 + off);
        wb[n] = *(const half8*)(lds + 32768 + off);
      }
#pragma unroll
      for (int m = 0; m < 4; ++m)
#pragma unroll
        for (int n = 0; n < 4; ++n) {
          aa[m][n] = __builtin_amdgcn_mfma_f32_16x16x32_f16(af[m], wa[n], aa[m][n], 0, 0, 0);
          ab[m][n] = __builtin_amdgcn_mfma_f32_16x16x32_f16(af[m], wb[n], ab[m][n], 0, 0, 0);
        }
    }
  }

  const int r0 = (lane >> 4) << 2;
#pragma unroll
  for (int m = 0; m < 4; ++m) {
    const int rg = row0 + wr + m*16 + r0;
#pragma unroll
    for (int n = 0; n < 4; ++n) {
      const int cg = col0 + wc + n*16 + fr;
      const float bav = ba[cg], bbv = bb[cg];
#pragma unroll
      for (int r = 0; r < 4; ++r) {
        const float av = aa[m][n][r] + bav;
        const float bv = ab[m][n][r] + bbv;
        H[(size_t)(rg + r)*ldc + cg] = f2h(av * fmaxf(bv, 0.f));
      }
    }
  }
}

// ---------------------------------------------------------------------------
// Fused attention: 256 threads, 4 waves, 128 q-rows/block.
// blocks 0..4095 = flash path (8 unmasked K-tiles; key 512 folded into the
// online-softmax INIT state); blocks 4096..5119 = CLS-row path (q row 512).
// ---------------------------------------------------------------------------
__global__ __launch_bounds__(256,4) void attn_fused(
    const ushort* __restrict__ qkv, ushort* __restrict__ o)
{
  __shared__ char lds[40960];
  const int t = threadIdx.x;

  if (blockIdx.x >= 4096) {
    const int bh = blockIdx.x - 4096;
    const int b = bh >> 3, h = bh & 7;
    float* sc   = (float*)lds;
    float* qsh  = (float*)(lds + 2112);
    float* red  = (float*)(lds + 2368);
    float* osum = (float*)(lds + 2432);
    const ushort* k = qkv + 512;
    const ushort* v = qkv + 1024;
    const ushort* qb2 = qkv + (size_t)512*QKVS;
    if (t < 64) qsh[t] = h2f(qb2[(size_t)b*SEQ*QKVS + h*64 + t]);
    __syncthreads();
    for (int key = t; key < SEQ; key += 256) {
      const ushort* kr = k + ((size_t)b*SEQ + key)*QKVS + h*64;
      float s = 0.f;
#pragma unroll
      for (int dv = 0; dv < 8; ++dv) {
        const short8 kv = *(const short8*)(kr + dv*8);
#pragma unroll
        for (int j = 0; j < 8; ++j) s += qsh[dv*8 + j] * h2f((ushort)kv[j]);
      }
      sc[key] = s;
    }
    __syncthreads();
    float lm = -1e30f;
    for (int key = t; key < SEQ; key += 256) lm = fmaxf(lm, sc[key]);
#pragma unroll
    for (int mask=1; mask<64; mask<<=1) lm = fmaxf(lm, __shfl_xor(lm, mask));
    if ((t&63)==0) red[t>>6] = lm;
    __syncthreads();
    const float mx = fmaxf(fmaxf(red[0],red[1]), fmaxf(red[2],red[3]));
    float ls = 0.f;
    for (int key = t; key < SEQ; key += 256){ float pp = exp2f(sc[key]-mx); sc[key]=pp; ls += pp; }
#pragma unroll
    for (int mask=1; mask<64; mask<<=1) ls += __shfl_xor(ls, mask);
    if ((t&63)==0) red[4 + (t>>6)] = ls;
    __syncthreads();
    const float ssum = red[4]+red[5]+red[6]+red[7];
    const int d = t & 63, kc = t >> 6;
    float op = 0.f;
    for (int key = kc; key < SEQ; key += 4)
      op += sc[key] * h2f(v[((size_t)b*SEQ + key)*QKVS + h*64 + d]);
    osum[t] = op;
    __syncthreads();
    if (t < 64) {
      const float oo = (osum[t]+osum[64+t]+osum[128+t]+osum[192+t]) / ssum;
      o[((size_t)b*SEQ + 512)*DMODEL + h*64 + t] = f2h(oo);
    }
    return;
  }

  const int bid = blockIdx.x;
  const int sw = (bid & 7)*512 + (bid >> 3);
  const int qt = sw & 3;
  const int hb = sw >> 2;
  const int h = hb & 7, b = hb >> 3;
  const int lane = t & 63, w = t >> 6;
  const int fr = lane & 15, g = lane >> 4, gq4 = g << 2;
  const size_t rowB = (size_t)b * SEQ;
  const ushort* q = qkv;
  const ushort* k = qkv + 512;
  const ushort* v = qkv + 1024;

  char* const Ks  = lds;
  char* const Vs  = lds + 8192;
  char* const VTs = lds + 16384;
  char* const pb  = lds + 24576 + w*4096;

  const int qr0 = qt*128 + w*32;

  half8 qf[2][2];
#pragma unroll
  for (int nq = 0; nq < 2; ++nq) {
    const int qrow = qr0 + nq*16 + fr;
#pragma unroll
    for (int kk = 0; kk < 2; ++kk)
      qf[nq][kk] = *(const half8*)&q[(rowB + qrow)*QKVS + h*64 + kk*32 + g*8];
  }

  // ---- softmax init with key 512 (weight 1 at its own max) ----
  f32x4 accO[2][4];
  float mrun[2], lrun[2];
  {
    const ushort* k512 = k + (rowB + 512)*QKVS + h*64;
    const ushort* v512 = v + (rowB + 512)*QKVS + h*64;
    half8 kf512[2];
#pragma unroll
    for (int kk = 0; kk < 2; ++kk)
      kf512[kk] = *(const half8*)&k512[kk*32 + g*8];
#pragma unroll
    for (int nq = 0; nq < 2; ++nq) {
      float s = 0.f;
#pragma unroll
      for (int kk = 0; kk < 2; ++kk)
#pragma unroll
        for (int j = 0; j < 8; ++j)
          s += (float)qf[nq][kk][j] * (float)kf512[kk][j];
      s += __shfl_xor(s, 16);
      s += __shfl_xor(s, 32);
      mrun[nq] = s;          // per-lane valid for q-row nq*16 + fr
      lrun[nq] = 1.f;
    }
    float v0[4];
#pragma unroll
    for (int dn = 0; dn < 4; ++dn) v0[dn] = h2f(v512[dn*16 + fr]);
#pragma unroll
    for (int mq = 0; mq < 2; ++mq)
#pragma unroll
      for (int dn = 0; dn < 4; ++dn)
#pragma unroll
        for (int r = 0; r < 4; ++r) accO[mq][dn][r] = v0[dn];
  }

  const int l8 = lane >> 3, l7 = lane & 7;
  const int chunk = l7 ^ l8;
  auto STAGE = [&](int kt2) {
#pragma unroll
    for (int i = 0; i < 2; ++i) {
      const int row = i*32 + (w<<3) + l8;
      const int keyg = kt2*KVB + row;           // always < 512 here
      const size_t gsrc = (rowB + keyg)*QKVS + h*64 + chunk*8;
      gload16(k + gsrc, Ks + i*4096 + w*1024);
      gload16(v + gsrc, Vs + i*4096 + w*1024);
    }
  };

  const int db  = (lane & 7) | ((w & 1) << 3);
  const int kbq = l8 | ((w & 2) << 2);
  const int d0 = db << 2, key0 = kbq << 2;

  STAGE(0);

  for (int kt = 0; kt < NKT8; ++kt) {
    __syncthreads();

    f32x4 sc4[4][2] = {};
    __builtin_amdgcn_s_setprio(1);
#pragma unroll
    for (int kk = 0; kk < 2; ++kk) {
      half8 kf[4];
#pragma unroll
      for (int mk = 0; mk < 4; ++mk) {
        const int row = mk*16 + fr;
        kf[mk] = *(const half8*)(Ks + row*128 + ((kk*64 + g*16) ^ ((fr&7)<<4)));
      }
#pragma unroll
      for (int mk = 0; mk < 4; ++mk)
#pragma unroll
        for (int nq = 0; nq < 2; ++nq)
          sc4[mk][nq] = __builtin_amdgcn_mfma_f32_16x16x32_f16(kf[mk], qf[nq][kk], sc4[mk][nq], 0, 0, 0);
    }
    __builtin_amdgcn_s_setprio(0);

    {
      uint2 a[4];
#pragma unroll
      for (int i = 0; i < 4; ++i) {
        const int row = key0 + i;
        a[i] = *(const uint2*)(Vs + row*128 + ((d0*2) ^ ((row&7)<<4)));
      }
      uint2 bb[4];
      bb[0].x = (a[0].x & 0xffffu) | (a[1].x << 16);
      bb[0].y = (a[2].x & 0xffffu) | (a[3].x << 16);
      bb[1].x = (a[0].x >> 16) | (a[1].x & 0xffff0000u);
      bb[1].y = (a[2].x >> 16) | (a[3].x & 0xffff0000u);
      bb[2].x = (a[0].y & 0xffffu) | (a[1].y << 16);
      bb[2].y = (a[2].y & 0xffffu) | (a[3].y << 16);
      bb[3].x = (a[0].y >> 16) | (a[1].y & 0xffff0000u);
      bb[3].y = (a[2].y >> 16) | (a[3].y & 0xffff0000u);
#pragma unroll
      for (int j = 0; j < 4; ++j) {
        const int drow = d0 + j;
        *(uint2*)(VTs + drow*128 + ((key0*2) ^ ((drow&7)<<4))) = bb[j];
      }
    }

    __syncthreads();

    if (kt+1 < NKT8) STAGE(kt+1);

    float al2[2];
    bool resc[2];
#pragma unroll
    for (int nq = 0; nq < 2; ++nq) {
      // tree max over 16 values (depth 4; enables v_max3 fusion)
      float m0 = fmaxf(fmaxf(sc4[0][nq][0], sc4[0][nq][1]), fmaxf(sc4[0][nq][2], sc4[0][nq][3]));
      float m1 = fmaxf(fmaxf(sc4[1][nq][0], sc4[1][nq][1]), fmaxf(sc4[1][nq][2], sc4[1][nq][3]));
      float m2 = fmaxf(fmaxf(sc4[2][nq][0], sc4[2][nq][1]), fmaxf(sc4[2][nq][2], sc4[2][nq][3]));
      float m3 = fmaxf(fmaxf(sc4[3][nq][0], sc4[3][nq][1]), fmaxf(sc4[3][nq][2], sc4[3][nq][3]));
      float tm = fmaxf(fmaxf(m0, m1), fmaxf(m2, m3));
      tm = fmaxf(tm, __shfl_xor(tm, 16));
      tm = fmaxf(tm, __shfl_xor(tm, 32));
      float mref;
      if (__all(tm - mrun[nq] <= 8.f)) {
        mref = mrun[nq];
        al2[nq] = 1.f; resc[nq] = false;
      } else {
        const float mnew = fmaxf(mrun[nq], tm);
        al2[nq] = exp2f(mrun[nq] - mnew);
        mrun[nq] = mnew;
        mref = mnew;
        resc[nq] = true;
      }
#pragma unroll
      for (int mk = 0; mk < 4; ++mk)
#pragma unroll
        for (int r = 0; r < 4; ++r)
          sc4[mk][nq][r] = exp2f(sc4[mk][nq][r] - mref);
      // tree sum over 16 values
      float r0s = (sc4[0][nq][0] + sc4[0][nq][1]) + (sc4[0][nq][2] + sc4[0][nq][3]);
      float r1s = (sc4[1][nq][0] + sc4[1][nq][1]) + (sc4[1][nq][2] + sc4[1][nq][3]);
      float r2s = (sc4[2][nq][0] + sc4[2][nq][1]) + (sc4[2][nq][2] + sc4[2][nq][3]);
      float r3s = (sc4[3][nq][0] + sc4[3][nq][1]) + (sc4[3][nq][2] + sc4[3][nq][3]);
      float rs = (r0s + r1s) + (r2s + r3s);
      rs += __shfl_xor(rs, 16);
      rs += __shfl_xor(rs, 32);
      lrun[nq] = resc[nq] ? (lrun[nq]*al2[nq] + rs) : (lrun[nq] + rs);
      char* prow = pb + (nq*16 + fr)*128;
#pragma unroll
      for (int mk = 0; mk < 4; ++mk) {
        uint2 pk;
        pk.x = pk2h(sc4[mk][nq][0], sc4[mk][nq][1]);
        pk.y = pk2h(sc4[mk][nq][2], sc4[mk][nq][3]);
        *(uint2*)(prow + ((mk*32 + gq4*2) ^ ((fr&7)<<4))) = pk;
      }
    }

#pragma unroll
    for (int mq = 0; mq < 2; ++mq) {
      if (resc[mq]) {
#pragma unroll
        for (int r = 0; r < 4; ++r) {
          const float alr = __shfl(al2[mq], (lane & 48) | (gq4 + r));
#pragma unroll
          for (int dn = 0; dn < 4; ++dn) accO[mq][dn][r] *= alr;
        }
      }
    }

    asm volatile("" ::: "memory");

    __builtin_amdgcn_s_setprio(1);
#pragma unroll
    for (int kk2 = 0; kk2 < 2; ++kk2) {
      half8 pf[2];
#pragma unroll
      for (int mq = 0; mq < 2; ++mq)
        pf[mq] = *(const half8*)(pb + (mq*16 + fr)*128 + ((kk2*64 + g*16) ^ ((fr&7)<<4)));
      half8 vf[4];
#pragma unroll
      for (int dn = 0; dn < 4; ++dn) {
        const int row = dn*16 + fr;
        vf[dn] = *(const half8*)(VTs + row*128 + ((kk2*64 + g*16) ^ ((fr&7)<<4)));
      }
#pragma unroll
      for (int mq = 0; mq < 2; ++mq)
#pragma unroll
        for (int dn = 0; dn < 4; ++dn)
          accO[mq][dn] = __builtin_amdgcn_mfma_f32_16x16x32_f16(pf[mq], vf[dn], accO[mq][dn], 0, 0, 0);
    }
    __builtin_amdgcn_s_setprio(0);
  }

#pragma unroll
  for (int mq = 0; mq < 2; ++mq)
#pragma unroll
    for (int r = 0; r < 4; ++r) {
      const int qrow = qr0 + mq*16 + gq4 + r;
      const float ls = __shfl(lrun[mq], (lane & 48) | (gq4 + r));
      const float inv = 1.f / ls;
#pragma unroll
      for (int dn = 0; dn < 4; ++dn)
        o[(rowB + qrow)*DMODEL + h*64 + dn*16 + fr] = f2h(accO[mq][dn][r] * inv);
    }
}

// ---------------------------------------------------------------------------
// Standalone single-q attention (layer-3 decode; q/out stride 512).
// ---------------------------------------------------------------------------
__global__ __launch_bounds__(256) void attn_cls(
    const ushort* __restrict__ qbase, size_t qstride,
    const ushort* __restrict__ qkv,
    ushort* __restrict__ obase, size_t ostride)
{
  const int bh = blockIdx.x;
  const int b = bh >> 3, h = bh & 7;
  const int t = threadIdx.x;
  __shared__ float sc[SEQ];
  __shared__ float qsh[64];
  __shared__ float red[8];
  __shared__ float osum[256];
  const ushort* k = qkv + 512;
  const ushort* v = qkv + 1024;
  if (t < 64) qsh[t] = h2f(qbase[(size_t)b*qstride + h*64 + t]);
  __syncthreads();
  for (int key = t; key < SEQ; key += 256) {
    const ushort* kr = k + ((size_t)b*SEQ + key)*QKVS + h*64;
    float s = 0.f;
#pragma unroll
    for (int dv = 0; dv < 8; ++dv) {
      const short8 kv = *(const short8*)(kr + dv*8);
#pragma unroll
      for (int j = 0; j < 8; ++j) s += qsh[dv*8 + j] * h2f((ushort)kv[j]);
    }
    sc[key] = s;
  }
  __syncthreads();
  float lm = -1e30f;
  for (int key = t; key < SEQ; key += 256) lm = fmaxf(lm, sc[key]);
#pragma unroll
  for (int mask=1; mask<64; mask<<=1) lm = fmaxf(lm, __shfl_xor(lm, mask));
  if ((t&63)==0) red[t>>6] = lm;
  __syncthreads();
  const float mx = fmaxf(fmaxf(red[0],red[1]), fmaxf(red[2],red[3]));
  float ls = 0.f;
  for (int key = t; key < SEQ; key += 256){ float pp = exp2f(sc[key]-mx); sc[key]=pp; ls += pp; }
#pragma unroll
  for (int mask=1; mask<64; mask<<=1) ls += __shfl_xor(ls, mask);
  if ((t&63)==0) red[4 + (t>>6)] = ls;
  __syncthreads();
  const float ssum = red[4]+red[5]+red[6]+red[7];
  const int d = t & 63, kc = t >> 6;
  float op = 0.f;
  for (int key = kc; key < SEQ; key += 4)
    op += sc[key] * h2f(v[((size_t)b*SEQ + key)*QKVS + h*64 + d]);
  osum[t] = op;
  __syncthreads();
  if (t < 64) {
    const float oo = (osum[t]+osum[64+t]+osum[128+t]+osum[192+t]) / ssum;
    obase[(size_t)b*ostride + h*64 + t] = f2h(oo);
  }
}

// ---------------------------------------------------------------------------
__global__ __launch_bounds__(256) void ln_kernel(
    const float* __restrict__ x, const float* __restrict__ gamma, const float* __restrict__ beta,
    ushort* __restrict__ out, int nrows)
{
  const int row = blockIdx.x*4 + (threadIdx.x >> 6);
  const int lane = threadIdx.x & 63;
  if (row >= nrows) return;
  const float* xr = x + (size_t)row*DMODEL;
  float4 a = *(const float4*)(xr + lane*8);
  float4 b = *(const float4*)(xr + lane*8 + 4);
  float s  = a.x+a.y+a.z+a.w+b.x+b.y+b.z+b.w;
  float ss = a.x*a.x+a.y*a.y+a.z*a.z+a.w*a.w+b.x*b.x+b.y*b.y+b.z*b.z+b.w*b.w;
#pragma unroll
  for (int mask=1; mask<64; mask<<=1){ s += __shfl_xor(s,mask); ss += __shfl_xor(ss,mask); }
  const float mu = s*(1.f/512.f);
  const float rstd = rsqrtf(ss*(1.f/512.f) - mu*mu + 1e-5f);
  float vals[8] = {a.x,a.y,a.z,a.w,b.x,b.y,b.z,b.w};
  short8 pk;
#pragma unroll
  for (int j=0;j<8;++j){
    const int c = lane*8 + j;
    pk[j] = (short)f2h((vals[j]-mu)*rstd*gamma[c] + beta[c]);
  }
  *(short8*)(out + (size_t)row*DMODEL + lane*8) = pk;
}

// ---------------------------------------------------------------------------
__global__ void embed_kernel(const float* __restrict__ x_num, const float* __restrict__ cls_w,
                             float* __restrict__ x, ushort* __restrict__ xb)
{
  const size_t i = (size_t)blockIdx.x*256 + threadIdx.x;
  if (i >= (size_t)NROWS*128) return;
  const int row = (int)(i >> 7);
  const int c4 = ((int)(i & 127)) << 2;
  const int b = row / SEQ;
  const int s = row - b*SEQ;
  float4 val;
  if (s == 0) val = *(const float4*)(cls_w + c4);
  else        val = *(const float4*)(x_num + ((size_t)b*512 + (s-1))*512 + c4);
  *(float4*)(x + (size_t)row*DMODEL + c4) = val;
  ushort4 pk;
  pk.x = f2h(val.x); pk.y = f2h(val.y); pk.z = f2h(val.z); pk.w = f2h(val.w);
  *(ushort4*)(xb + (size_t)row*DMODEL + c4) = pk;
}

// ---------------------------------------------------------------------------
__global__ void convert_pad(const float* __restrict__ in, ushort* __restrict__ out,
                            int R, int C, int RP, int CP, int layers, float scale,
                            int r0, int srcRL, size_t ostride)
{
  const size_t i = (size_t)blockIdx.x*256 + threadIdx.x;
  const size_t per = (size_t)RP*CP;
  if (i >= per*layers) return;
  const int l = (int)(i / per);
  const int rem = (int)(i - (size_t)l*per);
  const int r = rem / CP;
  const int c = rem - r*CP;
  ushort val = 0;
  if (r < R && c < C) val = f2h(in[((size_t)l*srcRL + r0 + r)*C + c] * scale);
  out[(size_t)l*ostride + (size_t)r*CP + c] = val;
}

__global__ void build_bias(const float* __restrict__ bq, const float* __restrict__ bk,
                           const float* __restrict__ bv, const float* __restrict__ l0b,
                           float* __restrict__ fqkv, float* __restrict__ fa, float* __restrict__ fb)
{
  const int i = blockIdx.x*256 + threadIdx.x;
  if (i < 4*1536) {
    const int l = i / 1536, j = i - l*1536;
    float val;
    if (j < 512)       val = bq[l*512 + j] * QSF;
    else if (j < 1024) val = bk[l*512 + j - 512];
    else               val = bv[l*512 + j - 1024];
    fqkv[i] = val;
  }
  if (i < 4*HP) {
    const int l = i / HP, j = i - l*HP;
    fa[i] = (j < DHID) ? l0b[l*DHID2 + j] : 0.f;
    fb[i] = (j < DHID) ? l0b[l*DHID2 + DHID + j] : 0.f;
  }
}

__global__ void gather_cls(const ushort* __restrict__ xb, const float* __restrict__ x,
                           ushort* __restrict__ xq, float* __restrict__ xc)
{
  const int b = blockIdx.x, lane = threadIdx.x;
  const size_t src = (size_t)b*SEQ*DMODEL;
  *(short8*)(xq + b*DMODEL + lane*8) = *(const short8*)(xb + src + lane*8);
  *(float4*)(xc + b*DMODEL + lane*8)     = *(const float4*)(x + src + lane*8);
  *(float4*)(xc + b*DMODEL + lane*8 + 4) = *(const float4*)(x + src + lane*8 + 4);
}

__global__ void head_kernel(const float* __restrict__ xc, const float* __restrict__ g,
                            const float* __restrict__ be, const float* __restrict__ hw,
                            const float* __restrict__ hb, float* __restrict__ out)
{
  const int row = blockIdx.x;
  const int lane = threadIdx.x;
  const float* xr = xc + (size_t)row*DMODEL;
  float4 a = *(const float4*)(xr + lane*8);
  float4 b = *(const float4*)(xr + lane*8 + 4);
  float s  = a.x+a.y+a.z+a.w+b.x+b.y+b.z+b.w;
  float ss = a.x*a.x+a.y*a.y+a.z*a.z+a.w*a.w+b.x*b.x+b.y*b.y+b.z*b.z+b.w*b.w;
#pragma unroll
  for (int mask=1; mask<64; mask<<=1){ s += __shfl_xor(s,mask); ss += __shfl_xor(ss,mask); }
  const float mu = s*(1.f/512.f);
  const float rstd = rsqrtf(ss*(1.f/512.f) - mu*mu + 1e-5f);
  float vals[8] = {a.x,a.y,a.z,a.w,b.x,b.y,b.z,b.w};
  float acc = 0.f;
#pragma unroll
  for (int j=0;j<8;++j){
    const int c = lane*8 + j;
    float tv = (vals[j]-mu)*rstd*g[c] + be[c];
    acc += fmaxf(tv, 0.f) * hw[c];
  }
#pragma unroll
  for (int mask=1; mask<64; mask<<=1) acc += __shfl_xor(acc, mask);
  if (lane==0) out[row] = acc + hb[0];
}

// ---------------------------------------------------------------------------
extern "C" void kernel_launch(void* const* d_in, const int* in_sizes, int n_in,
                              void* d_out, int out_size, void* d_ws, size_t ws_size,
                              hipStream_t stream)
{
  const float* x_num = (const float*)d_in[0];
  const float* cls_w = (const float*)d_in[1];
  const float* Wq = (const float*)d_in[2];
  const float* bq = (const float*)d_in[3];
  const float* Wk = (const float*)d_in[4];
  const float* bk = (const float*)d_in[5];
  const float* Wv = (const float*)d_in[6];
  const float* bv = (const float*)d_in[7];
  const float* Wo = (const float*)d_in[8];
  const float* bo = (const float*)d_in[9];
  const float* l0_w = (const float*)d_in[10];
  const float* l0_b = (const float*)d_in[11];
  const float* l1_w = (const float*)d_in[12];
  const float* l1_b = (const float*)d_in[13];
  const float* n0_g = (const float*)d_in[14];
  const float* n0_b = (const float*)d_in[15];
  const float* n1_g = (const float*)d_in[16];
  const float* n1_b = (const float*)d_in[17];
  const float* ln_g = (const float*)d_in[18];
  const float* ln_b = (const float*)d_in[19];
  const float* head_w = (const float*)d_in[20];
  const float* head_b = (const float*)d_in[21];
  float* out = (float*)d_out;

  char* p = (char*)d_ws;
  auto alloc = [&](size_t bytes){ char* r = p; p += (bytes + 255) & ~(size_t)255; return r; };

  float* x  = (float*)alloc((size_t)NROWS*DMODEL*4);          // residual fp32
  char* U   = alloc((size_t)NROWS*DMODEL*2);                  // xb / attn-out
  ushort* xb = (ushort*)U;
  ushort* ob = (ushort*)U;
  char* QKVG = alloc((size_t)NROWS*QKVS*2);                   // qkv; also h [NROWS][768]
  ushort* qkv = (ushort*)QKVG;
  ushort* hbuf = (ushort*)QKVG;
  ushort* wqkvb = (ushort*)alloc((size_t)4*QKVS*512*2);
  ushort* wob  = (ushort*)alloc((size_t)4*512*512*2);
  ushort* wl0a = (ushort*)alloc((size_t)4*HP*512*2);
  ushort* wl0b = (ushort*)alloc((size_t)4*HP*512*2);
  ushort* l1wp = (ushort*)alloc((size_t)4*512*HP*2);
  float*  fqkvb = (float*)alloc((size_t)4*QKVS*4);
  float*  l0ba = (float*)alloc((size_t)4*HP*4);
  float*  l0bb = (float*)alloc((size_t)4*HP*4);
  ushort* xq_cls = (ushort*)alloc(128*512*2);
  float*  xcf = (float*)alloc(128*512*4);
  ushort* qc = (ushort*)alloc(128*512*2);
  ushort* oc = (ushort*)alloc(128*512*2);
  ushort* hc = (ushort*)alloc((size_t)128*HP*2);
  ushort* xcb = (ushort*)alloc(128*512*2);

  auto cdiv = [](size_t a, size_t b){ return (unsigned)((a + b - 1)/b); };

  // weight conversion: fused QKV [1536x512] per layer (q-part scaled by QSF)
  convert_pad<<<cdiv((size_t)4*512*512,256),256,0,stream>>>(Wq, wqkvb,            512,512,512,512,4, QSF, 0, 512, (size_t)QKVS*512);
  convert_pad<<<cdiv((size_t)4*512*512,256),256,0,stream>>>(Wk, wqkvb + 512*512,  512,512,512,512,4, 1.f, 0, 512, (size_t)QKVS*512);
  convert_pad<<<cdiv((size_t)4*512*512,256),256,0,stream>>>(Wv, wqkvb + 1024*512, 512,512,512,512,4, 1.f, 0, 512, (size_t)QKVS*512);
  convert_pad<<<cdiv((size_t)4*512*512,256),256,0,stream>>>(Wo, wob, 512,512,512,512,4, 1.f, 0, 512, (size_t)512*512);
  convert_pad<<<cdiv((size_t)4*HP*512,256),256,0,stream>>>(l0_w, wl0a, DHID,512,HP,512,4, 1.f, 0,    DHID2, (size_t)HP*512);
  convert_pad<<<cdiv((size_t)4*HP*512,256),256,0,stream>>>(l0_w, wl0b, DHID,512,HP,512,4, 1.f, DHID, DHID2, (size_t)HP*512);
  convert_pad<<<cdiv((size_t)4*512*HP,256),256,0,stream>>>(l1_w, l1wp, 512,DHID,512,HP,4, 1.f, 0, 512, (size_t)512*HP);
  build_bias<<<cdiv(4*QKVS,256),256,0,stream>>>(bq, bk, bv, l0_b, fqkvb, l0ba, l0bb);

  embed_kernel<<<cdiv((size_t)NROWS*128,256),256,0,stream>>>(x_num, cls_w, x, xb);

  const int nwQKV = 12*513, nwF = 6*513, nwKV = 8*513;
  const int nRL = NROWS/64;   // 1026
  for (int i = 0; i < 3; ++i) {
    gemm_bt<0><<<nwQKV,256,0,stream>>>(xb, wqkvb+(size_t)i*QKVS*512, fqkvb+(size_t)i*QKVS, qkv, nullptr, 512, QKVS, 12, nwQKV);
    attn_fused<<<5120,256,0,stream>>>(qkv, ob);
    // WO gemm + residual + LN(n1[i]) -> x, xb
    gemm_res_ln<1><<<nRL,256,0,stream>>>(ob, wob+(size_t)i*262144, bo+i*512, x,
                                         n1_g+(size_t)i*512, n1_b+(size_t)i*512, xb, 512);
    gemm_ffn<<<nwF,256,0,stream>>>(xb, wl0a+(size_t)i*HP*512, wl0b+(size_t)i*HP*512,
                                   l0ba+(size_t)i*HP, l0bb+(size_t)i*HP, hbuf, 512, HP, 6, nwF);
    // L1 gemm + residual + LN(n0[i]) -> x, xb  (consumed by layer i+1 / layer 3)
    if (i < 2)
      gemm_res_ln<1><<<nRL,256,0,stream>>>(hbuf, l1wp+(size_t)i*512*HP, l1_b+i*512, x,
                                           n0_g+(size_t)i*512, n0_b+(size_t)i*512, xb, HP);
    else
      gemm_res_ln<0><<<nRL,256,0,stream>>>(hbuf, l1wp+(size_t)i*512*HP, l1_b+i*512, x,
                                           n0_g+(size_t)i*512, n0_b+(size_t)i*512, xb, HP);
  }

  // layer 3 (CLS query only) — xb already = LN_n0[2](x)
  gather_cls<<<128,64,0,stream>>>(xb, x, xq_cls, xcf);
  gemm_bt<0><<<4,256,0,stream>>>(xq_cls, wqkvb+(size_t)3*QKVS*512, fqkvb+(size_t)3*QKVS, qc, nullptr, 512, 512, 4, 4);
  gemm_bt<0><<<nwKV,256,0,stream>>>(xb, wqkvb+(size_t)3*QKVS*512 + 512*512, fqkvb+(size_t)3*QKVS + 512,
                                    qkv + 512, nullptr, 512, QKVS, 8, nwKV);
  attn_cls<<<1024,256,0,stream>>>(qc, 512, qkv, oc, 512);
  gemm_bt<1><<<4,256,0,stream>>>(oc, wob+(size_t)3*262144, bo+3*512, nullptr, xcf, 512, 512, 4, 4);
  ln_kernel<<<cdiv(128,4),256,0,stream>>>(xcf, n1_g+3*512, n1_b+3*512, xcb, 128);
  gemm_ffn<<<6,256,0,stream>>>(xcb, wl0a+(size_t)3*HP*512, wl0b+(size_t)3*HP*512,
                               l0ba+(size_t)3*HP, l0bb+(size_t)3*HP, hc, 512, HP, 6, 6);
  gemm_bt<1><<<4,256,0,stream>>>(hc, l1wp+(size_t)3*512*HP, l1_b+3*512, nullptr, xcf, HP, 512, 4, 4);
  head_kernel<<<128,64,0,stream>>>(xcf, ln_g, ln_b, head_w, head_b, out);
}

// Round 20
// 2318.430 us; speedup vs baseline: 1.1124x; 1.0079x over previous
//
#include <hip/hip_runtime.h>
#include <stdint.h>

typedef __attribute__((ext_vector_type(4))) float f32x4;
typedef __attribute__((ext_vector_type(8))) short short8;
typedef __attribute__((ext_vector_type(8))) _Float16 half8;

#define DMODEL 512
#define SEQ 513
#define BATCH 128
#define NROWS (BATCH*SEQ)   // 65664 = 513 * 128
#define DHID 682
#define DHID2 1364
#define HP 768
#define KTRIM 704           // ceil(682/64)*64 : K-loop bound for FFN-down
#define QKVS 1536
#define KVB 64
#define NKT8 8              // keys 0..511; key 512 folded into softmax init
#define QSF 0.1803368801111244f   // 0.125 * log2(e)

__device__ __forceinline__ float h2f(ushort u){ return (float)__builtin_bit_cast(_Float16, u); }
__device__ __forceinline__ ushort f2h(float f){ return __builtin_bit_cast(ushort, (_Float16)f); }
__device__ __forceinline__ uint pk2h(float a, float b){
  return __builtin_bit_cast(uint, __builtin_amdgcn_cvt_pkrtz(a, b));
}
__device__ __forceinline__ void gload16(const void* g, void* lds){
  __builtin_amdgcn_global_load_lds((const __attribute__((address_space(1))) void*)g,
                                   (__attribute__((address_space(3))) void*)lds, 16, 0, 0);
}
// bijective XCD-chunked flat-grid swizzle (m204)
__device__ __forceinline__ int xcd_wg(int orig, int nwg){
  const int q = nwg >> 3, r = nwg & 7;
  const int xcd = orig & 7, idx = orig >> 3;
  return (xcd < r) ? (xcd*(q+1) + idx) : (r*(q+1) + (xcd-r)*q + idx);
}

// ---------------------------------------------------------------------------
// GEMM: C[N x O] = A[N x K] @ W[O x K]^T (+bias). fp16 in, fp32 accum.
// 128x128 tile, BK=64, 4 waves, 32KB LDS, 3 blocks/CU, chunk-XOR swizzle.
// EPI=0: write fp16 Cb. EPI=1: Cf[idx] += acc + bias.
// ---------------------------------------------------------------------------
template<int EPI>
__global__ __launch_bounds__(256,3) void gemm_bt(
    const ushort* __restrict__ A, const ushort* __restrict__ W,
    const float* __restrict__ bias, ushort* __restrict__ Cb, float* __restrict__ Cf,
    int K, int ldc, int gx, int nwg)
{
  __shared__ char lds[32768];       // As @0, Ws @16384
  const int t = threadIdx.x, lane = t & 63, w = t >> 6;
  const int fr = lane & 15, g = lane >> 4;
  const int l7 = lane & 7, l8 = lane >> 3;
  const int wg = xcd_wg(blockIdx.x, nwg);
  const int row0 = (wg / gx) << 7;
  const int col0 = (wg % gx) << 7;
  const int wr = (w >> 1) << 6, wc = (w & 1) << 6;

  const int chunkoff = (l7 ^ l8) << 3;
  const ushort* Ag = A + (size_t)(row0 + w*8 + l8) * K + chunkoff;
  const ushort* Wg = W + (size_t)(col0 + w*8 + l8) * K + chunkoff;

  f32x4 acc[4][4] = {};

  for (int k0 = 0; k0 < K; k0 += 64) {
    __syncthreads();
#pragma unroll
    for (int p = 0; p < 4; ++p) {
      gload16(Ag + (size_t)(p*32)*K + k0, lds + p*4096 + w*1024);
      gload16(Wg + (size_t)(p*32)*K + k0, lds + 16384 + p*4096 + w*1024);
    }
    __syncthreads();
#pragma unroll
    for (int ks = 0; ks < 2; ++ks) {
      half8 af[4], wf[4];
#pragma unroll
      for (int m = 0; m < 4; ++m) {
        const int row = wr + m*16 + fr;
        af[m] = *(const half8*)(lds + row*128 + (((g + ks*4) ^ (fr & 7)) << 4));
      }
#pragma unroll
      for (int n = 0; n < 4; ++n) {
        const int row = wc + n*16 + fr;
        wf[n] = *(const half8*)(lds + 16384 + row*128 + (((g + ks*4) ^ (fr & 7)) << 4));
      }
#pragma unroll
      for (int m = 0; m < 4; ++m)
#pragma unroll
        for (int n = 0; n < 4; ++n)
          acc[m][n] = __builtin_amdgcn_mfma_f32_16x16x32_f16(af[m], wf[n], acc[m][n], 0, 0, 0);
    }
  }

  const int r0 = (lane >> 4) << 2;
#pragma unroll
  for (int m = 0; m < 4; ++m) {
    const int rg = row0 + wr + m*16 + r0;
#pragma unroll
    for (int n = 0; n < 4; ++n) {
      const int cg = col0 + wc + n*16 + fr;
      const float bi = bias[cg];
      if (EPI == 0) {
#pragma unroll
        for (int r = 0; r < 4; ++r)
          Cb[(size_t)(rg + r)*ldc + cg] = f2h(acc[m][n][r] + bi);
      } else {
#pragma unroll
        for (int r = 0; r < 4; ++r) {
          const size_t ix = (size_t)(rg + r)*ldc + cg;
          Cf[ix] += acc[m][n][r] + bi;
        }
      }
    }
  }
}

// ---------------------------------------------------------------------------
// Fused residual GEMM + LayerNorm, vectorized epilogue v4 (round-14 proven).
// XW=1: write full fp32 x. XW=0: write x only for CLS rows (row%513==0).
// K = loop bound (multiple of 64); lda = row stride of A and W (K <= lda).
// ---------------------------------------------------------------------------
template<int XW>
__global__ __launch_bounds__(256,2) void gemm_res_ln(
    const ushort* __restrict__ A, const ushort* __restrict__ W,
    const float* __restrict__ bias, float* __restrict__ x,
    const float* __restrict__ gamma, const float* __restrict__ beta,
    ushort* __restrict__ xb, int K, int lda)
{
  __shared__ char lds[73728];        // K-loop: A [64][128B] @0, W [512][128B] @8192
                                     // epilogue: fb16 @0, redrow @66560, gb @67072
  const int t = threadIdx.x, lane = t & 63, w = t >> 6;
  const int fr = lane & 15, g = lane >> 4;
  const int l7 = lane & 7, l8 = lane >> 3;
  const int row0 = blockIdx.x << 6;

  const int chunkoff = (l7 ^ l8) << 3;
  const ushort* Ag = A + (size_t)(row0 + w*8 + l8) * lda + chunkoff;
  const ushort* Wg = W + (size_t)(w*8 + l8) * lda + chunkoff;

  f32x4 acc[4][8] = {};

  for (int k0 = 0; k0 < K; k0 += 64) {
    __syncthreads();
    gload16(Ag + k0,                   lds + w*1024);
    gload16(Ag + (size_t)32*lda + k0,  lds + 4096 + w*1024);
#pragma unroll
    for (int p = 0; p < 16; ++p)
      gload16(Wg + (size_t)(p*32)*lda + k0, lds + 8192 + p*4096 + w*1024);
    __syncthreads();
#pragma unroll
    for (int ks = 0; ks < 2; ++ks) {
      half8 af[4], wf[8];
#pragma unroll
      for (int m = 0; m < 4; ++m) {
        const int row = m*16 + fr;
        af[m] = *(const half8*)(lds + row*128 + (((g + ks*4) ^ (fr & 7)) << 4));
      }
#pragma unroll
      for (int n = 0; n < 8; ++n) {
        const int row = (w << 7) + n*16 + fr;
        wf[n] = *(const half8*)(lds + 8192 + row*128 + (((g + ks*4) ^ (fr & 7)) << 4));
      }
#pragma unroll
      for (int m = 0; m < 4; ++m)
#pragma unroll
        for (int n = 0; n < 8; ++n)
          acc[m][n] = __builtin_amdgcn_mfma_f32_16x16x32_f16(af[m], wf[n], acc[m][n], 0, 0, 0);
    }
  }

  // ---------------- epilogue v4 ----------------
  ushort* fb16   = (ushort*)lds;              // [64][520]
  float2* redrow = (float2*)(lds + 66560);    // [64]
  float*  gb     = (float*)(lds + 67072);     // gamma[512] | beta[512]

  __syncthreads();
#pragma unroll
  for (int n = 0; n < 8; ++n) {
    const int cg = (w << 7) + n*16 + fr;
    const float bi = bias[cg];
#pragma unroll
    for (int m = 0; m < 4; ++m)
#pragma unroll
      for (int r = 0; r < 4; ++r)
        fb16[(m*16 + g*4 + r)*520 + cg] = f2h(acc[m][n][r] + bi);
  }
  if (t < 128) *(f32x4*)&gb[t*4]            = *(const f32x4*)&gamma[t*4];
  else         *(f32x4*)&gb[512 + (t-128)*4] = *(const f32x4*)&beta[(t-128)*4];
  __syncthreads();

  const int q = t & 15;
  const int rbase = t >> 4;
#pragma unroll
  for (int rr = 0; rr < 4; ++rr) {
    const int row = rr*16 + rbase;
    const int grow = row0 + row;
    const bool wrx = XW || (grow % SEQ) == 0;
    const size_t xrow = (size_t)grow*DMODEL;
    float ps = 0.f, pss = 0.f;
#pragma unroll
    for (int j = 0; j < 8; ++j) {
      const int c = q*4 + j*64;
      const uint2 pk = *(const uint2*)&fb16[row*520 + c];
      f32x4 v;
      v[0] = h2f((ushort)(pk.x & 0xffffu)); v[1] = h2f((ushort)(pk.x >> 16));
      v[2] = h2f((ushort)(pk.y & 0xffffu)); v[3] = h2f((ushort)(pk.y >> 16));
      const f32x4 xo = *(const f32x4*)&x[xrow + c];
      v += xo;
      if (wrx) *(f32x4*)&x[xrow + c] = v;
      uint2 opk; opk.x = pk2h(v[0], v[1]); opk.y = pk2h(v[2], v[3]);
      *(uint2*)&fb16[row*520 + c] = opk;
      ps  += v[0]+v[1]+v[2]+v[3];
      pss += v[0]*v[0]+v[1]*v[1]+v[2]*v[2]+v[3]*v[3];
    }
#pragma unroll
    for (int mask = 1; mask <= 8; mask <<= 1) {
      ps  += __shfl_xor(ps,  mask);
      pss += __shfl_xor(pss, mask);
    }
    if (q == 0) redrow[row] = float2{ps, pss};
  }
  __syncthreads();
#pragma unroll
  for (int rr = 0; rr < 4; ++rr) {
    const int row = rr*16 + rbase;
    const float2 sr = redrow[row];
    const float mu = sr.x * (1.f/512.f);
    const float rstd = rsqrtf(sr.y*(1.f/512.f) - mu*mu + 1e-5f);
    const size_t xbrow = (size_t)(row0 + row)*DMODEL;
#pragma unroll
    for (int j = 0; j < 8; ++j) {
      const int c = q*4 + j*64;
      const uint2 pk = *(const uint2*)&fb16[row*520 + c];
      f32x4 v;
      v[0] = h2f((ushort)(pk.x & 0xffffu)); v[1] = h2f((ushort)(pk.x >> 16));
      v[2] = h2f((ushort)(pk.y & 0xffffu)); v[3] = h2f((ushort)(pk.y >> 16));
      const f32x4 ga = *(const f32x4*)&gb[c];
      const f32x4 be = *(const f32x4*)&gb[512 + c];
      f32x4 o_;
#pragma unroll
      for (int e = 0; e < 4; ++e) o_[e] = (v[e] - mu)*rstd*ga[e] + be[e];
      uint2 u; u.x = pk2h(o_[0], o_[1]); u.y = pk2h(o_[2], o_[3]);
      *(uint2*)&xb[xbrow + c] = u;
    }
  }
}

// ---------------------------------------------------------------------------
// Fused FFN-up + ReGLU: H[N x 768] = (A@Wa^T + ba) * relu(A@Wb^T + bb), fp16.
// BK=64 swizzled; 48KB LDS, 2 blocks/CU.
// ---------------------------------------------------------------------------
__global__ __launch_bounds__(256,2) void gemm_ffn(
    const ushort* __restrict__ A, const ushort* __restrict__ Wa, const ushort* __restrict__ Wb,
    const float* __restrict__ ba, const float* __restrict__ bb, ushort* __restrict__ H,
    int K, int ldc, int gx, int nwg)
{
  __shared__ char lds[49152];       // As @0, Was @16384, Wbs @32768
  const int t = threadIdx.x, lane = t & 63, w = t >> 6;
  const int fr = lane & 15, g = lane >> 4;
  const int l7 = lane & 7, l8 = lane >> 3;
  const int wg = xcd_wg(blockIdx.x, nwg);
  const int row0 = (wg / gx) << 7;
  const int col0 = (wg % gx) << 7;
  const int wr = (w >> 1) << 6, wc = (w & 1) << 6;

  const int chunkoff = (l7 ^ l8) << 3;
  const ushort* Ag  = A  + (size_t)(row0 + w*8 + l8) * K + chunkoff;
  const ushort* WaG = Wa + (size_t)(col0 + w*8 + l8) * K + chunkoff;
  const ushort* WbG = Wb + (size_t)(col0 + w*8 + l8) * K + chunkoff;

  f32x4 aa[4][4] = {}, ab[4][4] = {};

  for (int k0 = 0; k0 < K; k0 += 64) {
    __syncthreads();
#pragma unroll
    for (int p = 0; p < 4; ++p) {
      gload16(Ag  + (size_t)(p*32)*K + k0, lds + p*4096 + w*1024);
      gload16(WaG + (size_t)(p*32)*K + k0, lds + 16384 + p*4096 + w*1024);
      gload16(WbG + (size_t)(p*32)*K + k0, lds + 32768 + p*4096 + w*1024);
    }
    __syncthreads();
#pragma unroll
    for (int ks = 0; ks < 2; ++ks) {
      half8 af[4], wa[4], wb[4];
#pragma unroll
      for (int m = 0; m < 4; ++m) {
        const int row = wr + m*16 + fr;
        af[m] = *(const half8*)(lds + row*128 + (((g + ks*4) ^ (fr & 7)) << 4));
      }
#pragma unroll
      for (int n = 0; n < 4; ++n) {
        const int row = wc + n*16 + fr;
        const int off = row*128 + (((g + ks*4) ^ (fr & 7)) << 4);
        wa[n] = *(const half8*)(lds + 16384 + off);
        wb[n] = *(const half8*)(lds + 32768 + off);
      }
#pragma unroll
      for (int m = 0; m < 4; ++m)
#pragma unroll
        for (int n = 0; n < 4; ++n) {
          aa[m][n] = __builtin_amdgcn_mfma_f32_16x16x32_f16(af[m], wa[n], aa[m][n], 0, 0, 0);
          ab[m][n] = __builtin_amdgcn_mfma_f32_16x16x32_f16(af[m], wb[n], ab[m][n], 0, 0, 0);
        }
    }
  }

  const int r0 = (lane >> 4) << 2;
#pragma unroll
  for (int m = 0; m < 4; ++m) {
    const int rg = row0 + wr + m*16 + r0;
#pragma unroll
    for (int n = 0; n < 4; ++n) {
      const int cg = col0 + wc + n*16 + fr;
      const float bav = ba[cg], bbv = bb[cg];
#pragma unroll
      for (int r = 0; r < 4; ++r) {
        const float av = aa[m][n][r] + bav;
        const float bv = ab[m][n][r] + bbv;
        H[(size_t)(rg + r)*ldc + cg] = f2h(av * fmaxf(bv, 0.f));
      }
    }
  }
}

// ---------------------------------------------------------------------------
// Fused attention: 256 threads, 4 waves, 128 q-rows/block.
// blocks 0..4095 = flash path (8 unmasked K-tiles; key 512 folded into the
// online-softmax INIT state); blocks 4096..5119 = CLS-row path (q row 512).
// ---------------------------------------------------------------------------
__global__ __launch_bounds__(256,4) void attn_fused(
    const ushort* __restrict__ qkv, ushort* __restrict__ o)
{
  __shared__ char lds[40960];
  const int t = threadIdx.x;

  if (blockIdx.x >= 4096) {
    const int bh = blockIdx.x - 4096;
    const int b = bh >> 3, h = bh & 7;
    float* sc   = (float*)lds;
    float* qsh  = (float*)(lds + 2112);
    float* red  = (float*)(lds + 2368);
    float* osum = (float*)(lds + 2432);
    const ushort* k = qkv + 512;
    const ushort* v = qkv + 1024;
    const ushort* qb2 = qkv + (size_t)512*QKVS;
    if (t < 64) qsh[t] = h2f(qb2[(size_t)b*SEQ*QKVS + h*64 + t]);
    __syncthreads();
    for (int key = t; key < SEQ; key += 256) {
      const ushort* kr = k + ((size_t)b*SEQ + key)*QKVS + h*64;
      float s = 0.f;
#pragma unroll
      for (int dv = 0; dv < 8; ++dv) {
        const short8 kv = *(const short8*)(kr + dv*8);
#pragma unroll
        for (int j = 0; j < 8; ++j) s += qsh[dv*8 + j] * h2f((ushort)kv[j]);
      }
      sc[key] = s;
    }
    __syncthreads();
    float lm = -1e30f;
    for (int key = t; key < SEQ; key += 256) lm = fmaxf(lm, sc[key]);
#pragma unroll
    for (int mask=1; mask<64; mask<<=1) lm = fmaxf(lm, __shfl_xor(lm, mask));
    if ((t&63)==0) red[t>>6] = lm;
    __syncthreads();
    const float mx = fmaxf(fmaxf(red[0],red[1]), fmaxf(red[2],red[3]));
    float ls = 0.f;
    for (int key = t; key < SEQ; key += 256){ float pp = exp2f(sc[key]-mx); sc[key]=pp; ls += pp; }
#pragma unroll
    for (int mask=1; mask<64; mask<<=1) ls += __shfl_xor(ls, mask);
    if ((t&63)==0) red[4 + (t>>6)] = ls;
    __syncthreads();
    const float ssum = red[4]+red[5]+red[6]+red[7];
    const int d = t & 63, kc = t >> 6;
    float op = 0.f;
    for (int key = kc; key < SEQ; key += 4)
      op += sc[key] * h2f(v[((size_t)b*SEQ + key)*QKVS + h*64 + d]);
    osum[t] = op;
    __syncthreads();
    if (t < 64) {
      const float oo = (osum[t]+osum[64+t]+osum[128+t]+osum[192+t]) / ssum;
      o[((size_t)b*SEQ + 512)*DMODEL + h*64 + t] = f2h(oo);
    }
    return;
  }

  const int bid = blockIdx.x;
  const int sw = (bid & 7)*512 + (bid >> 3);
  const int qt = sw & 3;
  const int hb = sw >> 2;
  const int h = hb & 7, b = hb >> 3;
  const int lane = t & 63, w = t >> 6;
  const int fr = lane & 15, g = lane >> 4, gq4 = g << 2;
  const size_t rowB = (size_t)b * SEQ;
  const ushort* q = qkv;
  const ushort* k = qkv + 512;
  const ushort* v = qkv + 1024;

  char* const Ks  = lds;
  char* const Vs  = lds + 8192;
  char* const VTs = lds + 16384;
  char* const pb  = lds + 24576 + w*4096;

  const int qr0 = qt*128 + w*32;

  half8 qf[2][2];
#pragma unroll
  for (int nq = 0; nq < 2; ++nq) {
    const int qrow = qr0 + nq*16 + fr;
#pragma unroll
    for (int kk = 0; kk < 2; ++kk)
      qf[nq][kk] = *(const half8*)&q[(rowB + qrow)*QKVS + h*64 + kk*32 + g*8];
  }

  // ---- softmax init with key 512 (weight 1 at its own max) ----
  f32x4 accO[2][4];
  float mrun[2], lrun[2];
  {
    const ushort* k512 = k + (rowB + 512)*QKVS + h*64;
    const ushort* v512 = v + (rowB + 512)*QKVS + h*64;
    half8 kf512[2];
#pragma unroll
    for (int kk = 0; kk < 2; ++kk)
      kf512[kk] = *(const half8*)&k512[kk*32 + g*8];
#pragma unroll
    for (int nq = 0; nq < 2; ++nq) {
      float s = 0.f;
#pragma unroll
      for (int kk = 0; kk < 2; ++kk)
#pragma unroll
        for (int j = 0; j < 8; ++j)
          s += (float)qf[nq][kk][j] * (float)kf512[kk][j];
      s += __shfl_xor(s, 16);
      s += __shfl_xor(s, 32);
      mrun[nq] = s;          // per-lane valid for q-row nq*16 + fr
      lrun[nq] = 1.f;
    }
    float v0[4];
#pragma unroll
    for (int dn = 0; dn < 4; ++dn) v0[dn] = h2f(v512[dn*16 + fr]);
#pragma unroll
    for (int mq = 0; mq < 2; ++mq)
#pragma unroll
      for (int dn = 0; dn < 4; ++dn)
#pragma unroll
        for (int r = 0; r < 4; ++r) accO[mq][dn][r] = v0[dn];
  }

  const int l8 = lane >> 3, l7 = lane & 7;
  const int chunk = l7 ^ l8;
  auto STAGE = [&](int kt2) {
#pragma unroll
    for (int i = 0; i < 2; ++i) {
      const int row = i*32 + (w<<3) + l8;
      const int keyg = kt2*KVB + row;           // always < 512 here
      const size_t gsrc = (rowB + keyg)*QKVS + h*64 + chunk*8;
      gload16(k + gsrc, Ks + i*4096 + w*1024);
      gload16(v + gsrc, Vs + i*4096 + w*1024);
    }
  };

  const int db  = (lane & 7) | ((w & 1) << 3);
  const int kbq = l8 | ((w & 2) << 2);
  const int d0 = db << 2, key0 = kbq << 2;

  STAGE(0);

  for (int kt = 0; kt < NKT8; ++kt) {
    __syncthreads();

    f32x4 sc4[4][2] = {};
    __builtin_amdgcn_s_setprio(1);
#pragma unroll
    for (int kk = 0; kk < 2; ++kk) {
      half8 kf[4];
#pragma unroll
      for (int mk = 0; mk < 4; ++mk) {
        const int row = mk*16 + fr;
        kf[mk] = *(const half8*)(Ks + row*128 + ((kk*64 + g*16) ^ ((fr&7)<<4)));
      }
#pragma unroll
      for (int mk = 0; mk < 4; ++mk)
#pragma unroll
        for (int nq = 0; nq < 2; ++nq)
          sc4[mk][nq] = __builtin_amdgcn_mfma_f32_16x16x32_f16(kf[mk], qf[nq][kk], sc4[mk][nq], 0, 0, 0);
    }
    __builtin_amdgcn_s_setprio(0);

    {
      uint2 a[4];
#pragma unroll
      for (int i = 0; i < 4; ++i) {
        const int row = key0 + i;
        a[i] = *(const uint2*)(Vs + row*128 + ((d0*2) ^ ((row&7)<<4)));
      }
      uint2 bb[4];
      bb[0].x = (a[0].x & 0xffffu) | (a[1].x << 16);
      bb[0].y = (a[2].x & 0xffffu) | (a[3].x << 16);
      bb[1].x = (a[0].x >> 16) | (a[1].x & 0xffff0000u);
      bb[1].y = (a[2].x >> 16) | (a[3].x & 0xffff0000u);
      bb[2].x = (a[0].y & 0xffffu) | (a[1].y << 16);
      bb[2].y = (a[2].y & 0xffffu) | (a[3].y << 16);
      bb[3].x = (a[0].y >> 16) | (a[1].y & 0xffff0000u);
      bb[3].y = (a[2].y >> 16) | (a[3].y & 0xffff0000u);
#pragma unroll
      for (int j = 0; j < 4; ++j) {
        const int drow = d0 + j;
        *(uint2*)(VTs + drow*128 + ((key0*2) ^ ((drow&7)<<4))) = bb[j];
      }
    }

    __syncthreads();

    if (kt+1 < NKT8) STAGE(kt+1);

    float al2[2];
    bool resc[2];
#pragma unroll
    for (int nq = 0; nq < 2; ++nq) {
      // tree max over 16 values (depth 4; enables v_max3 fusion)
      float m0 = fmaxf(fmaxf(sc4[0][nq][0], sc4[0][nq][1]), fmaxf(sc4[0][nq][2], sc4[0][nq][3]));
      float m1 = fmaxf(fmaxf(sc4[1][nq][0], sc4[1][nq][1]), fmaxf(sc4[1][nq][2], sc4[1][nq][3]));
      float m2 = fmaxf(fmaxf(sc4[2][nq][0], sc4[2][nq][1]), fmaxf(sc4[2][nq][2], sc4[2][nq][3]));
      float m3 = fmaxf(fmaxf(sc4[3][nq][0], sc4[3][nq][1]), fmaxf(sc4[3][nq][2], sc4[3][nq][3]));
      float tm = fmaxf(fmaxf(m0, m1), fmaxf(m2, m3));
      tm = fmaxf(tm, __shfl_xor(tm, 16));
      tm = fmaxf(tm, __shfl_xor(tm, 32));
      float mref;
      if (__all(tm - mrun[nq] <= 8.f)) {
        mref = mrun[nq];
        al2[nq] = 1.f; resc[nq] = false;
      } else {
        const float mnew = fmaxf(mrun[nq], tm);
        al2[nq] = exp2f(mrun[nq] - mnew);
        mrun[nq] = mnew;
        mref = mnew;
        resc[nq] = true;
      }
#pragma unroll
      for (int mk = 0; mk < 4; ++mk)
#pragma unroll
        for (int r = 0; r < 4; ++r)
          sc4[mk][nq][r] = exp2f(sc4[mk][nq][r] - mref);
      // tree sum over 16 values
      float r0s = (sc4[0][nq][0] + sc4[0][nq][1]) + (sc4[0][nq][2] + sc4[0][nq][3]);
      float r1s = (sc4[1][nq][0] + sc4[1][nq][1]) + (sc4[1][nq][2] + sc4[1][nq][3]);
      float r2s = (sc4[2][nq][0] + sc4[2][nq][1]) + (sc4[2][nq][2] + sc4[2][nq][3]);
      float r3s = (sc4[3][nq][0] + sc4[3][nq][1]) + (sc4[3][nq][2] + sc4[3][nq][3]);
      float rs = (r0s + r1s) + (r2s + r3s);
      rs += __shfl_xor(rs, 16);
      rs += __shfl_xor(rs, 32);
      lrun[nq] = resc[nq] ? (lrun[nq]*al2[nq] + rs) : (lrun[nq] + rs);
      char* prow = pb + (nq*16 + fr)*128;
#pragma unroll
      for (int mk = 0; mk < 4; ++mk) {
        uint2 pk;
        pk.x = pk2h(sc4[mk][nq][0], sc4[mk][nq][1]);
        pk.y = pk2h(sc4[mk][nq][2], sc4[mk][nq][3]);
        *(uint2*)(prow + ((mk*32 + gq4*2) ^ ((fr&7)<<4))) = pk;
      }
    }

#pragma unroll
    for (int mq = 0; mq < 2; ++mq) {
      if (resc[mq]) {
#pragma unroll
        for (int r = 0; r < 4; ++r) {
          const float alr = __shfl(al2[mq], (lane & 48) | (gq4 + r));
#pragma unroll
          for (int dn = 0; dn < 4; ++dn) accO[mq][dn][r] *= alr;
        }
      }
    }

    asm volatile("" ::: "memory");

    __builtin_amdgcn_s_setprio(1);
#pragma unroll
    for (int kk2 = 0; kk2 < 2; ++kk2) {
      half8 pf[2];
#pragma unroll
      for (int mq = 0; mq < 2; ++mq)
        pf[mq] = *(const half8*)(pb + (mq*16 + fr)*128 + ((kk2*64 + g*16) ^ ((fr&7)<<4)));
      half8 vf[4];
#pragma unroll
      for (int dn = 0; dn < 4; ++dn) {
        const int row = dn*16 + fr;
        vf[dn] = *(const half8*)(VTs + row*128 + ((kk2*64 + g*16) ^ ((fr&7)<<4)));
      }
#pragma unroll
      for (int mq = 0; mq < 2; ++mq)
#pragma unroll
        for (int dn = 0; dn < 4; ++dn)
          accO[mq][dn] = __builtin_amdgcn_mfma_f32_16x16x32_f16(pf[mq], vf[dn], accO[mq][dn], 0, 0, 0);
    }
    __builtin_amdgcn_s_setprio(0);
  }

#pragma unroll
  for (int mq = 0; mq < 2; ++mq)
#pragma unroll
    for (int r = 0; r < 4; ++r) {
      const int qrow = qr0 + mq*16 + gq4 + r;
      const float ls = __shfl(lrun[mq], (lane & 48) | (gq4 + r));
      const float inv = 1.f / ls;
#pragma unroll
      for (int dn = 0; dn < 4; ++dn)
        o[(rowB + qrow)*DMODEL + h*64 + dn*16 + fr] = f2h(accO[mq][dn][r] * inv);
    }
}

// ---------------------------------------------------------------------------
// Standalone single-q attention (layer-3 decode; q/out stride 512).
// ---------------------------------------------------------------------------
__global__ __launch_bounds__(256) void attn_cls(
    const ushort* __restrict__ qbase, size_t qstride,
    const ushort* __restrict__ qkv,
    ushort* __restrict__ obase, size_t ostride)
{
  const int bh = blockIdx.x;
  const int b = bh >> 3, h = bh & 7;
  const int t = threadIdx.x;
  __shared__ float sc[SEQ];
  __shared__ float qsh[64];
  __shared__ float red[8];
  __shared__ float osum[256];
  const ushort* k = qkv + 512;
  const ushort* v = qkv + 1024;
  if (t < 64) qsh[t] = h2f(qbase[(size_t)b*qstride + h*64 + t]);
  __syncthreads();
  for (int key = t; key < SEQ; key += 256) {
    const ushort* kr = k + ((size_t)b*SEQ + key)*QKVS + h*64;
    float s = 0.f;
#pragma unroll
    for (int dv = 0; dv < 8; ++dv) {
      const short8 kv = *(const short8*)(kr + dv*8);
#pragma unroll
      for (int j = 0; j < 8; ++j) s += qsh[dv*8 + j] * h2f((ushort)kv[j]);
    }
    sc[key] = s;
  }
  __syncthreads();
  float lm = -1e30f;
  for (int key = t; key < SEQ; key += 256) lm = fmaxf(lm, sc[key]);
#pragma unroll
  for (int mask=1; mask<64; mask<<=1) lm = fmaxf(lm, __shfl_xor(lm, mask));
  if ((t&63)==0) red[t>>6] = lm;
  __syncthreads();
  const float mx = fmaxf(fmaxf(red[0],red[1]), fmaxf(red[2],red[3]));
  float ls = 0.f;
  for (int key = t; key < SEQ; key += 256){ float pp = exp2f(sc[key]-mx); sc[key]=pp; ls += pp; }
#pragma unroll
  for (int mask=1; mask<64; mask<<=1) ls += __shfl_xor(ls, mask);
  if ((t&63)==0) red[4 + (t>>6)] = ls;
  __syncthreads();
  const float ssum = red[4]+red[5]+red[6]+red[7];
  const int d = t & 63, kc = t >> 6;
  float op = 0.f;
  for (int key = kc; key < SEQ; key += 4)
    op += sc[key] * h2f(v[((size_t)b*SEQ + key)*QKVS + h*64 + d]);
  osum[t] = op;
  __syncthreads();
  if (t < 64) {
    const float oo = (osum[t]+osum[64+t]+osum[128+t]+osum[192+t]) / ssum;
    obase[(size_t)b*ostride + h*64 + t] = f2h(oo);
  }
}

// ---------------------------------------------------------------------------
__global__ __launch_bounds__(256) void ln_kernel(
    const float* __restrict__ x, const float* __restrict__ gamma, const float* __restrict__ beta,
    ushort* __restrict__ out, int nrows)
{
  const int row = blockIdx.x*4 + (threadIdx.x >> 6);
  const int lane = threadIdx.x & 63;
  if (row >= nrows) return;
  const float* xr = x + (size_t)row*DMODEL;
  float4 a = *(const float4*)(xr + lane*8);
  float4 b = *(const float4*)(xr + lane*8 + 4);
  float s  = a.x+a.y+a.z+a.w+b.x+b.y+b.z+b.w;
  float ss = a.x*a.x+a.y*a.y+a.z*a.z+a.w*a.w+b.x*b.x+b.y*b.y+b.z*b.z+b.w*b.w;
#pragma unroll
  for (int mask=1; mask<64; mask<<=1){ s += __shfl_xor(s,mask); ss += __shfl_xor(ss,mask); }
  const float mu = s*(1.f/512.f);
  const float rstd = rsqrtf(ss*(1.f/512.f) - mu*mu + 1e-5f);
  float vals[8] = {a.x,a.y,a.z,a.w,b.x,b.y,b.z,b.w};
  short8 pk;
#pragma unroll
  for (int j=0;j<8;++j){
    const int c = lane*8 + j;
    pk[j] = (short)f2h((vals[j]-mu)*rstd*gamma[c] + beta[c]);
  }
  *(short8*)(out + (size_t)row*DMODEL + lane*8) = pk;
}

// ---------------------------------------------------------------------------
__global__ void embed_kernel(const float* __restrict__ x_num, const float* __restrict__ cls_w,
                             float* __restrict__ x, ushort* __restrict__ xb)
{
  const size_t i = (size_t)blockIdx.x*256 + threadIdx.x;
  if (i >= (size_t)NROWS*128) return;
  const int row = (int)(i >> 7);
  const int c4 = ((int)(i & 127)) << 2;
  const int b = row / SEQ;
  const int s = row - b*SEQ;
  float4 val;
  if (s == 0) val = *(const float4*)(cls_w + c4);
  else        val = *(const float4*)(x_num + ((size_t)b*512 + (s-1))*512 + c4);
  *(float4*)(x + (size_t)row*DMODEL + c4) = val;
  ushort4 pk;
  pk.x = f2h(val.x); pk.y = f2h(val.y); pk.z = f2h(val.z); pk.w = f2h(val.w);
  *(ushort4*)(xb + (size_t)row*DMODEL + c4) = pk;
}

// ---------------------------------------------------------------------------
__global__ void convert_pad(const float* __restrict__ in, ushort* __restrict__ out,
                            int R, int C, int RP, int CP, int layers, float scale,
                            int r0, int srcRL, size_t ostride)
{
  const size_t i = (size_t)blockIdx.x*256 + threadIdx.x;
  const size_t per = (size_t)RP*CP;
  if (i >= per*layers) return;
  const int l = (int)(i / per);
  const int rem = (int)(i - (size_t)l*per);
  const int r = rem / CP;
  const int c = rem - r*CP;
  ushort val = 0;
  if (r < R && c < C) val = f2h(in[((size_t)l*srcRL + r0 + r)*C + c] * scale);
  out[(size_t)l*ostride + (size_t)r*CP + c] = val;
}

__global__ void build_bias(const float* __restrict__ bq, const float* __restrict__ bk,
                           const float* __restrict__ bv, const float* __restrict__ l0b,
                           float* __restrict__ fqkv, float* __restrict__ fa, float* __restrict__ fb)
{
  const int i = blockIdx.x*256 + threadIdx.x;
  if (i < 4*1536) {
    const int l = i / 1536, j = i - l*1536;
    float val;
    if (j < 512)       val = bq[l*512 + j] * QSF;
    else if (j < 1024) val = bk[l*512 + j - 512];
    else               val = bv[l*512 + j - 1024];
    fqkv[i] = val;
  }
  if (i < 4*HP) {
    const int l = i / HP, j = i - l*HP;
    fa[i] = (j < DHID) ? l0b[l*DHID2 + j] : 0.f;
    fb[i] = (j < DHID) ? l0b[l*DHID2 + DHID + j] : 0.f;
  }
}

__global__ void gather_cls(const ushort* __restrict__ xb, const float* __restrict__ x,
                           ushort* __restrict__ xq, float* __restrict__ xc)
{
  const int b = blockIdx.x, lane = threadIdx.x;
  const size_t src = (size_t)b*SEQ*DMODEL;
  *(short8*)(xq + b*DMODEL + lane*8) = *(const short8*)(xb + src + lane*8);
  *(float4*)(xc + b*DMODEL + lane*8)     = *(const float4*)(x + src + lane*8);
  *(float4*)(xc + b*DMODEL + lane*8 + 4) = *(const float4*)(x + src + lane*8 + 4);
}

__global__ void head_kernel(const float* __restrict__ xc, const float* __restrict__ g,
                            const float* __restrict__ be, const float* __restrict__ hw,
                            const float* __restrict__ hb, float* __restrict__ out)
{
  const int row = blockIdx.x;
  const int lane = threadIdx.x;
  const float* xr = xc + (size_t)row*DMODEL;
  float4 a = *(const float4*)(xr + lane*8);
  float4 b = *(const float4*)(xr + lane*8 + 4);
  float s  = a.x+a.y+a.z+a.w+b.x+b.y+b.z+b.w;
  float ss = a.x*a.x+a.y*a.y+a.z*a.z+a.w*a.w+b.x*b.x+b.y*b.y+b.z*b.z+b.w*b.w;
#pragma unroll
  for (int mask=1; mask<64; mask<<=1){ s += __shfl_xor(s,mask); ss += __shfl_xor(ss,mask); }
  const float mu = s*(1.f/512.f);
  const float rstd = rsqrtf(ss*(1.f/512.f) - mu*mu + 1e-5f);
  float vals[8] = {a.x,a.y,a.z,a.w,b.x,b.y,b.z,b.w};
  float acc = 0.f;
#pragma unroll
  for (int j=0;j<8;++j){
    const int c = lane*8 + j;
    float tv = (vals[j]-mu)*rstd*g[c] + be[c];
    acc += fmaxf(tv, 0.f) * hw[c];
  }
#pragma unroll
  for (int mask=1; mask<64; mask<<=1) acc += __shfl_xor(acc, mask);
  if (lane==0) out[row] = acc + hb[0];
}

// ---------------------------------------------------------------------------
extern "C" void kernel_launch(void* const* d_in, const int* in_sizes, int n_in,
                              void* d_out, int out_size, void* d_ws, size_t ws_size,
                              hipStream_t stream)
{
  const float* x_num = (const float*)d_in[0];
  const float* cls_w = (const float*)d_in[1];
  const float* Wq = (const float*)d_in[2];
  const float* bq = (const float*)d_in[3];
  const float* Wk = (const float*)d_in[4];
  const float* bk = (const float*)d_in[5];
  const float* Wv = (const float*)d_in[6];
  const float* bv = (const float*)d_in[7];
  const float* Wo = (const float*)d_in[8];
  const float* bo = (const float*)d_in[9];
  const float* l0_w = (const float*)d_in[10];
  const float* l0_b = (const float*)d_in[11];
  const float* l1_w = (const float*)d_in[12];
  const float* l1_b = (const float*)d_in[13];
  const float* n0_g = (const float*)d_in[14];
  const float* n0_b = (const float*)d_in[15];
  const float* n1_g = (const float*)d_in[16];
  const float* n1_b = (const float*)d_in[17];
  const float* ln_g = (const float*)d_in[18];
  const float* ln_b = (const float*)d_in[19];
  const float* head_w = (const float*)d_in[20];
  const float* head_b = (const float*)d_in[21];
  float* out = (float*)d_out;

  char* p = (char*)d_ws;
  auto alloc = [&](size_t bytes){ char* r = p; p += (bytes + 255) & ~(size_t)255; return r; };

  float* x  = (float*)alloc((size_t)NROWS*DMODEL*4);          // residual fp32
  char* U   = alloc((size_t)NROWS*DMODEL*2);                  // xb / attn-out
  ushort* xb = (ushort*)U;
  ushort* ob = (ushort*)U;
  char* QKVG = alloc((size_t)NROWS*QKVS*2);                   // qkv; also h [NROWS][768]
  ushort* qkv = (ushort*)QKVG;
  ushort* hbuf = (ushort*)QKVG;
  ushort* wqkvb = (ushort*)alloc((size_t)4*QKVS*512*2);
  ushort* wob  = (ushort*)alloc((size_t)4*512*512*2);
  ushort* wl0a = (ushort*)alloc((size_t)4*HP*512*2);
  ushort* wl0b = (ushort*)alloc((size_t)4*HP*512*2);
  ushort* l1wp = (ushort*)alloc((size_t)4*512*HP*2);
  float*  fqkvb = (float*)alloc((size_t)4*QKVS*4);
  float*  l0ba = (float*)alloc((size_t)4*HP*4);
  float*  l0bb = (float*)alloc((size_t)4*HP*4);
  ushort* xq_cls = (ushort*)alloc(128*512*2);
  float*  xcf = (float*)alloc(128*512*4);
  ushort* qc = (ushort*)alloc(128*512*2);
  ushort* oc = (ushort*)alloc(128*512*2);
  ushort* hc = (ushort*)alloc((size_t)128*HP*2);
  ushort* xcb = (ushort*)alloc(128*512*2);

  auto cdiv = [](size_t a, size_t b){ return (unsigned)((a + b - 1)/b); };

  // weight conversion: fused QKV [1536x512] per layer (q-part scaled by QSF)
  convert_pad<<<cdiv((size_t)4*512*512,256),256,0,stream>>>(Wq, wqkvb,            512,512,512,512,4, QSF, 0, 512, (size_t)QKVS*512);
  convert_pad<<<cdiv((size_t)4*512*512,256),256,0,stream>>>(Wk, wqkvb + 512*512,  512,512,512,512,4, 1.f, 0, 512, (size_t)QKVS*512);
  convert_pad<<<cdiv((size_t)4*512*512,256),256,0,stream>>>(Wv, wqkvb + 1024*512, 512,512,512,512,4, 1.f, 0, 512, (size_t)QKVS*512);
  convert_pad<<<cdiv((size_t)4*512*512,256),256,0,stream>>>(Wo, wob, 512,512,512,512,4, 1.f, 0, 512, (size_t)512*512);
  convert_pad<<<cdiv((size_t)4*HP*512,256),256,0,stream>>>(l0_w, wl0a, DHID,512,HP,512,4, 1.f, 0,    DHID2, (size_t)HP*512);
  convert_pad<<<cdiv((size_t)4*HP*512,256),256,0,stream>>>(l0_w, wl0b, DHID,512,HP,512,4, 1.f, DHID, DHID2, (size_t)HP*512);
  convert_pad<<<cdiv((size_t)4*512*HP,256),256,0,stream>>>(l1_w, l1wp, 512,DHID,512,HP,4, 1.f, 0, 512, (size_t)512*HP);
  build_bias<<<cdiv(4*QKVS,256),256,0,stream>>>(bq, bk, bv, l0_b, fqkvb, l0ba, l0bb);

  embed_kernel<<<cdiv((size_t)NROWS*128,256),256,0,stream>>>(x_num, cls_w, x, xb);

  const int nwQKV = 12*513, nwF = 6*513, nwKV = 8*513;
  const int nRL = NROWS/64;   // 1026
  for (int i = 0; i < 3; ++i) {
    gemm_bt<0><<<nwQKV,256,0,stream>>>(xb, wqkvb+(size_t)i*QKVS*512, fqkvb+(size_t)i*QKVS, qkv, nullptr, 512, QKVS, 12, nwQKV);
    attn_fused<<<5120,256,0,stream>>>(qkv, ob);
    // WO gemm + residual + LN(n1[i]) -> x, xb
    gemm_res_ln<1><<<nRL,256,0,stream>>>(ob, wob+(size_t)i*262144, bo+i*512, x,
                                         n1_g+(size_t)i*512, n1_b+(size_t)i*512, xb, 512, 512);
    gemm_ffn<<<nwF,256,0,stream>>>(xb, wl0a+(size_t)i*HP*512, wl0b+(size_t)i*HP*512,
                                   l0ba+(size_t)i*HP, l0bb+(size_t)i*HP, hbuf, 512, HP, 6, nwF);
    // L1 gemm + residual + LN(n0[i]) -> x, xb  (K trimmed to 704: cols 682..767 of hbuf are zero)
    if (i < 2)
      gemm_res_ln<1><<<nRL,256,0,stream>>>(hbuf, l1wp+(size_t)i*512*HP, l1_b+i*512, x,
                                           n0_g+(size_t)i*512, n0_b+(size_t)i*512, xb, KTRIM, HP);
    else
      gemm_res_ln<0><<<nRL,256,0,stream>>>(hbuf, l1wp+(size_t)i*512*HP, l1_b+i*512, x,
                                           n0_g+(size_t)i*512, n0_b+(size_t)i*512, xb, KTRIM, HP);
  }

  // layer 3 (CLS query only) — xb already = LN_n0[2](x)
  gather_cls<<<128,64,0,stream>>>(xb, x, xq_cls, xcf);
  gemm_bt<0><<<4,256,0,stream>>>(xq_cls, wqkvb+(size_t)3*QKVS*512, fqkvb+(size_t)3*QKVS, qc, nullptr, 512, 512, 4, 4);
  gemm_bt<0><<<nwKV,256,0,stream>>>(xb, wqkvb+(size_t)3*QKVS*512 + 512*512, fqkvb+(size_t)3*QKVS + 512,
                                    qkv + 512, nullptr, 512, QKVS, 8, nwKV);
  attn_cls<<<1024,256,0,stream>>>(qc, 512, qkv, oc, 512);
  gemm_bt<1><<<4,256,0,stream>>>(oc, wob+(size_t)3*262144, bo+3*512, nullptr, xcf, 512, 512, 4, 4);
  ln_kernel<<<cdiv(128,4),256,0,stream>>>(xcf, n1_g+3*512, n1_b+3*512, xcb, 128);
  gemm_ffn<<<6,256,0,stream>>>(xcb, wl0a+(size_t)3*HP*512, wl0b+(size_t)3*HP*512,
                               l0ba+(size_t)3*HP, l0bb+(size_t)3*HP, hc, 512, HP, 6, 6);
  gemm_bt<1><<<4,256,0,stream>>>(hc, l1wp+(size_t)3*512*HP, l1_b+3*512, nullptr, xcf, HP, 512, 4, 4);
  head_kernel<<<128,64,0,stream>>>(xcf, ln_g, ln_b, head_w, head_b, out);
}